// Round 3
// baseline (1023.401 us; speedup 1.0000x reference)
//
#include <hip/hip_runtime.h>
#include <math.h>

// ---------------------------------------------------------------------------
// VQ-VAE forward, fp32 (round 3).
//  - round-2 B-tile fix kept
//  - hipMemsetAsync replaced by k_init (graph-capture safety)
//  - M-guards (A-row clamp, C/stats guards) -> supports M=135 GEMMs
//  - W_in folded into conv_e1 weights (BN shift-invariance kills b_in):
//    removes the 30720x135x512 input GEMM and 63 MB h0 buffer; -15.7 GFLOP.
// Layout: activations time-major (slice, B=1024, C=512). BN stats accumulated
// in producer GEMM (atomics), scale/shift applied fused at consumer A-load.
// ---------------------------------------------------------------------------

#define TM 64
#define TN 64
#define BK 32
#define LSTR 68   // LDS row stride in floats (pad 64 -> 68, keeps 16B align)

__global__ __launch_bounds__(256)
void k_gemm(const float* __restrict__ Abase,
            const float* __restrict__ Wt,
            float* __restrict__ Cout,
            const float* __restrict__ bias,
            const float* __restrict__ bnS, const float* __restrict__ bnB,
            float* __restrict__ stats,                     // [ch]=sum, [512+ch]=sumsq, or null
            unsigned long long* __restrict__ amin,         // argmin mode if non-null
            const float* __restrict__ codesq,
            float* __restrict__ operm,                     // permuted final write
            int Mslice, int K, int N,
            int n_terms, int enc_mode, int decK)
{
    __shared__ __align__(16) float As[BK][LSTR];
    __shared__ __align__(16) float Bs[BK][LSTR];
    __shared__ float colsum[TN];
    __shared__ float colsq[TN];

    const int tid = threadIdx.x;
    const int z  = blockIdx.z;
    const int n0 = blockIdx.x * TN;
    const int m0 = blockIdx.y * TM;
    const int ty = tid >> 4;          // 0..15 -> rows 4*ty..4*ty+3
    const int tx = tid & 15;          // 0..15 -> cols 4*tx..4*tx+3

    if (stats != nullptr && tid < TN) { colsum[tid] = 0.f; colsq[tid] = 0.f; }

    float acc[4][4];
#pragma unroll
    for (int i = 0; i < 4; ++i)
#pragma unroll
        for (int j = 0; j < 4; ++j) acc[i][j] = 0.f;

    const int arow = tid >> 2;          // 0..63
    const int ac4  = (tid & 3) << 2;    // 0,4,8,12
    const int brow = tid >> 3;          // 0..31
    const int bc4  = (tid & 7) << 2;    // 0..28 (plus +32 twin)

    // clamp A row so partial-M tiles read valid memory (C writes are guarded)
    int mrow = m0 + arow;
    if (mrow > Mslice - 1) mrow = Mslice - 1;

    const bool alignedK = ((K & 31) == 0);
    const bool alignedN = ((N & 3) == 0);

    for (int term = 0; term < n_terms; ++term) {
        int a_slice, wk;
        if (enc_mode) { a_slice = z * n_terms + term; wk = term; }
        else          { a_slice = z / decK;           wk = z % decK; }
        const float* Ap = Abase + (size_t)a_slice * (size_t)Mslice * (size_t)K;
        const float* Wp = Wt    + (size_t)wk * (size_t)K * (size_t)N;
        const float* Arow_p = Ap + (size_t)mrow * (size_t)K;

        for (int k0 = 0; k0 < K; k0 += BK) {
            __syncthreads();
            // ---------------- stage A (transposed into [kk][m]) ----------------
            if (alignedK) {
                float4 a0 = *(const float4*)(Arow_p + k0 + ac4);
                float4 a1 = *(const float4*)(Arow_p + k0 + ac4 + 16);
                if (bnS != nullptr) {
                    float4 s0 = *(const float4*)(bnS + k0 + ac4);
                    float4 c0 = *(const float4*)(bnB + k0 + ac4);
                    float4 s1 = *(const float4*)(bnS + k0 + ac4 + 16);
                    float4 c1 = *(const float4*)(bnB + k0 + ac4 + 16);
                    a0.x = fmaxf(fmaf(a0.x, s0.x, c0.x), 0.f);
                    a0.y = fmaxf(fmaf(a0.y, s0.y, c0.y), 0.f);
                    a0.z = fmaxf(fmaf(a0.z, s0.z, c0.z), 0.f);
                    a0.w = fmaxf(fmaf(a0.w, s0.w, c0.w), 0.f);
                    a1.x = fmaxf(fmaf(a1.x, s1.x, c1.x), 0.f);
                    a1.y = fmaxf(fmaf(a1.y, s1.y, c1.y), 0.f);
                    a1.z = fmaxf(fmaf(a1.z, s1.z, c1.z), 0.f);
                    a1.w = fmaxf(fmaf(a1.w, s1.w, c1.w), 0.f);
                }
                As[ac4+0][arow] = a0.x;  As[ac4+1][arow] = a0.y;
                As[ac4+2][arow] = a0.z;  As[ac4+3][arow] = a0.w;
                As[ac4+16][arow] = a1.x; As[ac4+17][arow] = a1.y;
                As[ac4+18][arow] = a1.z; As[ac4+19][arow] = a1.w;
            } else {
                // guarded scalar path (K=135); bnS never set on this path here
#pragma unroll
                for (int j = 0; j < 4; ++j) {
                    int k = k0 + ac4 + j;
                    As[ac4+j][arow] = (k < K) ? Arow_p[k] : 0.f;
                    int k2 = k + 16;
                    As[ac4+16+j][arow] = (k2 < K) ? Arow_p[k2] : 0.f;
                }
            }
            // ---------------- stage B ([kk][n], full 64 cols) ----------------
            {
                int kB = k0 + brow;
                if (alignedN) {
                    float4 b0 = make_float4(0.f, 0.f, 0.f, 0.f);
                    float4 b1 = make_float4(0.f, 0.f, 0.f, 0.f);
                    if (kB < K) {
                        const float* wrow = Wp + (size_t)kB * N + n0;
                        b0 = *(const float4*)(wrow + bc4);
                        b1 = *(const float4*)(wrow + bc4 + 32);
                    }
                    *(float4*)&Bs[brow][bc4]      = b0;
                    *(float4*)&Bs[brow][bc4 + 32] = b1;
                } else {
#pragma unroll
                    for (int j = 0; j < 4; ++j) {
                        int n  = n0 + bc4 + j;
                        int n2 = n + 32;
                        Bs[brow][bc4+j]    = (kB < K && n  < N) ? Wp[(size_t)kB * N + n]  : 0.f;
                        Bs[brow][bc4+32+j] = (kB < K && n2 < N) ? Wp[(size_t)kB * N + n2] : 0.f;
                    }
                }
            }
            __syncthreads();
            // ---------------- compute ----------------
#pragma unroll
            for (int kk = 0; kk < BK; ++kk) {
                float4 av = *(const float4*)&As[kk][ty << 2];
                float4 bv = *(const float4*)&Bs[kk][tx << 2];
                acc[0][0] = fmaf(av.x, bv.x, acc[0][0]);
                acc[0][1] = fmaf(av.x, bv.y, acc[0][1]);
                acc[0][2] = fmaf(av.x, bv.z, acc[0][2]);
                acc[0][3] = fmaf(av.x, bv.w, acc[0][3]);
                acc[1][0] = fmaf(av.y, bv.x, acc[1][0]);
                acc[1][1] = fmaf(av.y, bv.y, acc[1][1]);
                acc[1][2] = fmaf(av.y, bv.z, acc[1][2]);
                acc[1][3] = fmaf(av.y, bv.w, acc[1][3]);
                acc[2][0] = fmaf(av.z, bv.x, acc[2][0]);
                acc[2][1] = fmaf(av.z, bv.y, acc[2][1]);
                acc[2][2] = fmaf(av.z, bv.z, acc[2][2]);
                acc[2][3] = fmaf(av.z, bv.w, acc[2][3]);
                acc[3][0] = fmaf(av.w, bv.x, acc[3][0]);
                acc[3][1] = fmaf(av.w, bv.y, acc[3][1]);
                acc[3][2] = fmaf(av.w, bv.z, acc[3][2]);
                acc[3][3] = fmaf(av.w, bv.w, acc[3][3]);
            }
        }
    }

    // ---------------- epilogue: VQ argmin ----------------
    if (amin != nullptr) {
        float4 cq = *(const float4*)(codesq + n0 + (tx << 2));
#pragma unroll
        for (int i = 0; i < 4; ++i) {
            int m = m0 + (ty << 2) + i;
            if (m >= Mslice) continue;
            float d0 = cq.x - 2.f * acc[i][0];
            float d1 = cq.y - 2.f * acc[i][1];
            float d2 = cq.z - 2.f * acc[i][2];
            float d3 = cq.w - 2.f * acc[i][3];
            float best = d0; int bj = 0;
            if (d1 < best) { best = d1; bj = 1; }
            if (d2 < best) { best = d2; bj = 2; }
            if (d3 < best) { best = d3; bj = 3; }
            unsigned u = __float_as_uint(best);
            u = (u & 0x80000000u) ? ~u : (u | 0x80000000u);   // order-preserving map
            unsigned long long key =
                ((unsigned long long)u << 32) | (unsigned)(n0 + (tx << 2) + bj);
            atomicMin(&amin[m], key);                          // ties -> lowest idx
        }
        return;
    }

    // ---------------- epilogue: write C ----------------
#pragma unroll
    for (int i = 0; i < 4; ++i) {
        int m = m0 + (ty << 2) + i;
        if (m >= Mslice) continue;
        float vv[4] = { acc[i][0], acc[i][1], acc[i][2], acc[i][3] };
        if (operm != nullptr) {
            int t = m >> 10, b = m & 1023;
#pragma unroll
            for (int j = 0; j < 4; ++j) {
                int n = n0 + (tx << 2) + j;
                if (n < N) {
                    float val = vv[j];
                    if (bias != nullptr) val += bias[n];
                    operm[(size_t)b * (30 * 135) + (size_t)t * 135 + n] = val;
                }
            }
        } else {
            float4 v = make_float4(vv[0], vv[1], vv[2], vv[3]);
            if (bias != nullptr) {
                float4 bb = *(const float4*)(bias + n0 + (tx << 2));
                v.x += bb.x; v.y += bb.y; v.z += bb.z; v.w += bb.w;
            }
            *(float4*)&Cout[((size_t)z * Mslice + m) * N + n0 + (tx << 2)] = v;
        }
    }

    // ---------------- epilogue: BN stats ----------------
    if (stats != nullptr) {
#pragma unroll
        for (int j = 0; j < 4; ++j) {
            float s = 0.f, q = 0.f;
#pragma unroll
            for (int i = 0; i < 4; ++i) {
                int m = m0 + (ty << 2) + i;
                if (m < Mslice) { float x = acc[i][j]; s += x; q += x * x; }
            }
            atomicAdd(&colsum[(tx << 2) + j], s);
            atomicAdd(&colsq [(tx << 2) + j], q);
        }
        __syncthreads();
        if (tid < TN) {
            atomicAdd(&stats[n0 + tid],       colsum[tid]);
            atomicAdd(&stats[512 + n0 + tid], colsq[tid]);
        }
    }
}

__global__ void k_init(float* __restrict__ zbase, unsigned long long* __restrict__ amin)
{
    int t = blockIdx.x * 256 + threadIdx.x;
    if (t < 6720) zbase[t] = 0.f;               // stats(6144) + loss(64) + hist(512)
    if (t < 1024) amin[t] = ~0ULL;
}

// repack conv weights to [k][i*512+o]; swap_oi=1 for encoder (O,I,K) / codebook
__global__ void k_repack(const float* __restrict__ w, float* __restrict__ wt,
                         int Kc, int swap_oi, int total)
{
    int idx = blockIdx.x * 256 + threadIdx.x;
    if (idx >= total) return;
    int k = idx >> 18;            // / 262144
    int rem = idx & 262143;
    int i = rem >> 9, o = rem & 511;
    int src = swap_oi ? (((o << 9) + i) * Kc + k) : (((i << 9) + o) * Kc + k);
    wt[idx] = w[src];
}

__global__ void k_codesq(const float* __restrict__ cb, float* __restrict__ outq)
{
    int c = blockIdx.x; int l = threadIdx.x;
    float s = 0.f;
    for (int i = l; i < 512; i += 64) { float v = cb[c * 512 + i]; s += v * v; }
    for (int off = 32; off; off >>= 1) s += __shfl_down(s, off, 64);
    if (l == 0) outq[c] = s;
}

__global__ void k_bn_fin(const float* __restrict__ stats,
                         const float* __restrict__ g, const float* __restrict__ b,
                         float* __restrict__ sc, float* __restrict__ sh, float inv_n)
{
    int c = blockIdx.x * blockDim.x + threadIdx.x;
    if (c >= 512) return;
    float m = stats[c] * inv_n;
    float v = stats[512 + c] * inv_n - m * m;
    float a = (float)((double)g[c] / sqrt((double)v + 1e-5));
    sc[c] = a;
    sh[c] = b[c] - m * a;
}

__global__ void k_vq_gather(const unsigned long long* __restrict__ amin,
                            const float* __restrict__ codebook,
                            const float* __restrict__ e3pre,
                            const float* __restrict__ sc, const float* __restrict__ sh,
                            float* __restrict__ quant, float* __restrict__ loss,
                            unsigned int* __restrict__ hist)
{
    int b = blockIdx.x; int t = threadIdx.x;   // 256 threads
    unsigned int idx = (unsigned int)(amin[b] & 0xFFFFFFFFull) & 511u;
    float part = 0.f;
    for (int i = t; i < 512; i += 256) {
        float q = codebook[(size_t)idx * 512 + i];
        quant[(size_t)b * 512 + i] = q;
        float x = e3pre[(size_t)b * 512 + i];
        float f = fmaxf(fmaf(x, sc[i], sh[i]), 0.f);
        float d = q - f;
        part += d * d;
    }
    for (int off = 32; off; off >>= 1) part += __shfl_down(part, off, 64);
    __shared__ float red[4];
    if ((t & 63) == 0) red[t >> 6] = part;
    __syncthreads();
    if (t == 0) {
        atomicAdd(loss, red[0] + red[1] + red[2] + red[3]);
        atomicAdd(&hist[idx], 1u);
    }
}

__global__ void k_scalars(const unsigned int* __restrict__ hist,
                          const float* __restrict__ loss, float* __restrict__ out)
{
    int t = threadIdx.x;   // 512
    float p = (float)hist[t] * (1.0f / 1024.0f);
    float e = p * logf(p + 1e-10f);
    for (int off = 32; off; off >>= 1) e += __shfl_down(e, off, 64);
    __shared__ float red[8];
    if ((t & 63) == 0) red[t >> 6] = e;
    __syncthreads();
    if (t == 0) {
        float s = 0.f;
        for (int i = 0; i < 8; ++i) s += red[i];
        out[4147200] = 1.25f * loss[0] * (1.0f / 524288.0f);
        out[4147201] = expf(-s);
    }
}

extern "C" void kernel_launch(void* const* d_in, const int* in_sizes, int n_in,
                              void* d_out, int out_size, void* d_ws, size_t ws_size,
                              hipStream_t stream)
{
    const float* in_seqs = (const float*)d_in[0];
    const float* W_in  = (const float*)d_in[1];
    // d_in[2] = b_in: dropped (BN shift-invariance)
    const float* w_e1  = (const float*)d_in[3];
    const float* g_e1  = (const float*)d_in[4];
    const float* be1   = (const float*)d_in[5];
    const float* w_e2  = (const float*)d_in[6];
    const float* g_e2  = (const float*)d_in[7];
    const float* be2   = (const float*)d_in[8];
    const float* w_e3  = (const float*)d_in[9];
    const float* g_e3  = (const float*)d_in[10];
    const float* be3   = (const float*)d_in[11];
    const float* codebook = (const float*)d_in[12];
    const float* W_q   = (const float*)d_in[13];
    const float* b_q   = (const float*)d_in[14];
    const float* w_d1  = (const float*)d_in[15];
    const float* g_d1  = (const float*)d_in[16];
    const float* bd1   = (const float*)d_in[17];
    const float* w_d2  = (const float*)d_in[18];
    const float* g_d2  = (const float*)d_in[19];
    const float* bd2   = (const float*)d_in[20];
    const float* w_d3  = (const float*)d_in[21];
    const float* g_d3  = (const float*)d_in[22];
    const float* bd3   = (const float*)d_in[23];
    const float* W_out = (const float*)d_in[24];
    const float* b_out = (const float*)d_in[25];
    float* out = (float*)d_out;

    // ---- workspace layout: control buffers first, then weights, then acts ----
    float* W = (float*)d_ws;
    unsigned long long* amin = (unsigned long long*)W;     // 1024 u64 = 2048 f
    float* stats  = W + 2048;                              // 6144
    float* lossp  = W + 8192;                              // 64
    unsigned int* hist = (unsigned int*)(W + 8256);        // 512
    float* scsh   = W + 8768;                              // 6144
    float* codesq = W + 14912;                             // 512
    float* wt_e1 = W + 15424;                              // 5*262144
    float* wt_e2 = wt_e1 + 5 * 262144;
    float* wt_e3 = wt_e2 + 3 * 262144;
    float* wt_d1 = wt_e3 + 2 * 262144;
    float* wt_d2 = wt_d1 + 2 * 262144;
    float* wt_d3 = wt_d2 + 3 * 262144;
    float* codeT = wt_d3 + 5 * 262144;                     // 262144
    float* weff  = codeT + 262144;                         // 5*135*512 = 345600
    const size_t SLICE = 1024u * 512u;
    float* e1    = weff + 345600;                          // 6 slices (reused as d2)
    float* e2    = e1 + 6 * SLICE;                         // 2 slices (reused as d1)
    float* e3    = e2 + 2 * SLICE;                         // 1
    float* quant = e3 + SLICE;                             // 1
    float* d0v   = quant + SLICE;                          // 1
    float* d3v   = d0v + SLICE;                            // 30 slices

    float* st_e1 = stats + 0 * 1024; float* sc_e1 = scsh + 0 * 1024; float* sh_e1 = sc_e1 + 512;
    float* st_e2 = stats + 1 * 1024; float* sc_e2 = scsh + 1 * 1024; float* sh_e2 = sc_e2 + 512;
    float* st_e3 = stats + 2 * 1024; float* sc_e3 = scsh + 2 * 1024; float* sh_e3 = sc_e3 + 512;
    float* st_d1 = stats + 3 * 1024; float* sc_d1 = scsh + 3 * 1024; float* sh_d1 = sc_d1 + 512;
    float* st_d2 = stats + 4 * 1024; float* sc_d2 = scsh + 4 * 1024; float* sh_d2 = sc_d2 + 512;
    float* st_d3 = stats + 5 * 1024; float* sc_d3 = scsh + 5 * 1024; float* sh_d3 = sc_d3 + 512;

    float* d1v = e2;   // e2 dead after conv_e3
    float* d2v = e1;   // e1 dead after conv_e2

    dim3 blk(256);
    k_init<<<dim3(32), blk, 0, stream>>>(stats, amin);

    // weight repacks
    k_repack<<<dim3(5 * 1024), blk, 0, stream>>>(w_e1, wt_e1, 5, 1, 5 * 262144);
    k_repack<<<dim3(3 * 1024), blk, 0, stream>>>(w_e2, wt_e2, 3, 1, 3 * 262144);
    k_repack<<<dim3(2 * 1024), blk, 0, stream>>>(w_e3, wt_e3, 2, 1, 2 * 262144);
    k_repack<<<dim3(2 * 1024), blk, 0, stream>>>(w_d1, wt_d1, 2, 0, 2 * 262144);
    k_repack<<<dim3(3 * 1024), blk, 0, stream>>>(w_d2, wt_d2, 3, 0, 3 * 262144);
    k_repack<<<dim3(5 * 1024), blk, 0, stream>>>(w_d3, wt_d3, 5, 0, 5 * 262144);
    k_repack<<<dim3(1024),     blk, 0, stream>>>(codebook, codeT, 1, 1, 262144);
    k_codesq<<<dim3(512), dim3(64), 0, stream>>>(codebook, codesq);

    // weff[k] = W_in (135x512) @ wt_e1[k] (512x512); dec mode keeps A fixed
    k_gemm<<<dim3(8, 3, 5), blk, 0, stream>>>(W_in, wt_e1, weff, nullptr,
        nullptr, nullptr, nullptr, nullptr, nullptr, nullptr, 135, 512, 512, 1, 0, 5);

    // encoder: e1 = conv(x, weff) (fused input projection), K=135
    k_gemm<<<dim3(8, 16, 6), blk, 0, stream>>>(in_seqs, weff, e1, nullptr,
        nullptr, nullptr, st_e1, nullptr, nullptr, nullptr, 1024, 135, 512, 5, 1, 1);
    k_bn_fin<<<dim3(2), blk, 0, stream>>>(st_e1, g_e1, be1, sc_e1, sh_e1, 1.f / 6144.f);

    k_gemm<<<dim3(8, 16, 2), blk, 0, stream>>>(e1, wt_e2, e2, nullptr,
        sc_e1, sh_e1, st_e2, nullptr, nullptr, nullptr, 1024, 512, 512, 3, 1, 1);
    k_bn_fin<<<dim3(2), blk, 0, stream>>>(st_e2, g_e2, be2, sc_e2, sh_e2, 1.f / 2048.f);

    k_gemm<<<dim3(8, 16, 1), blk, 0, stream>>>(e2, wt_e3, e3, nullptr,
        sc_e2, sh_e2, st_e3, nullptr, nullptr, nullptr, 1024, 512, 512, 2, 1, 1);
    k_bn_fin<<<dim3(2), blk, 0, stream>>>(st_e3, g_e3, be3, sc_e3, sh_e3, 1.f / 1024.f);

    // VQ: dist GEMM + argmin epilogue (A-load applies bn_e3+relu -> flat)
    k_gemm<<<dim3(8, 16, 1), blk, 0, stream>>>(e3, codeT, nullptr, nullptr,
        sc_e3, sh_e3, nullptr, amin, codesq, nullptr, 1024, 512, 512, 1, 1, 1);
    k_vq_gather<<<dim3(1024), blk, 0, stream>>>(amin, codebook, e3, sc_e3, sh_e3,
                                                quant, lossp, hist);

    // d0 = quantized @ W_q + b_q
    k_gemm<<<dim3(8, 16, 1), blk, 0, stream>>>(quant, W_q, d0v, b_q,
        nullptr, nullptr, nullptr, nullptr, nullptr, nullptr, 1024, 512, 512, 1, 1, 1);

    // decoder
    k_gemm<<<dim3(8, 16, 2), blk, 0, stream>>>(d0v, wt_d1, d1v, nullptr,
        nullptr, nullptr, st_d1, nullptr, nullptr, nullptr, 1024, 512, 512, 1, 0, 2);
    k_bn_fin<<<dim3(2), blk, 0, stream>>>(st_d1, g_d1, bd1, sc_d1, sh_d1, 1.f / 2048.f);

    k_gemm<<<dim3(8, 16, 6), blk, 0, stream>>>(d1v, wt_d2, d2v, nullptr,
        sc_d1, sh_d1, st_d2, nullptr, nullptr, nullptr, 1024, 512, 512, 1, 0, 3);
    k_bn_fin<<<dim3(2), blk, 0, stream>>>(st_d2, g_d2, bd2, sc_d2, sh_d2, 1.f / 6144.f);

    k_gemm<<<dim3(8, 16, 30), blk, 0, stream>>>(d2v, wt_d3, d3v, nullptr,
        sc_d2, sh_d2, st_d3, nullptr, nullptr, nullptr, 1024, 512, 512, 1, 0, 5);
    k_bn_fin<<<dim3(2), blk, 0, stream>>>(st_d3, g_d3, bd3, sc_d3, sh_d3, 1.f / 30720.f);

    // recon = bnrelu(d3) @ W_out + b_out, written (b, t, p)-permuted
    k_gemm<<<dim3(3, 480, 1), blk, 0, stream>>>(d3v, W_out, nullptr, b_out,
        sc_d3, sh_d3, nullptr, nullptr, nullptr, out, 30720, 512, 135, 1, 1, 1);

    // vq_loss + perplexity
    k_scalars<<<dim3(1), dim3(512), 0, stream>>>(hist, lossp, out);
}

// Round 4
// 809.596 us; speedup vs baseline: 1.2641x; 1.2641x over previous
//
#include <hip/hip_runtime.h>
#include <math.h>

// ---------------------------------------------------------------------------
// VQ-VAE forward (round 4).
//  - Encoder + VQ argmin: unchanged fp32 k_gemm (argmin stays bit-identical
//    to the passing round; removes the only discrete hazard).
//  - Decoder side (W_q, d1, d2, d3, out-proj = 25.2/34.4 GFLOP): new bf16
//    MFMA kernel k_mfma (128x128 block tile, 4 waves of 64x64 via
//    mfma_f32_16x16x32_bf16, fp32 accumulate).
//  - bf16 weight repacks overlay the dead wt_e1/wt_e2 fp32 region (launched
//    after the e2 GEMM) so the workspace footprint matches round 3.
// ---------------------------------------------------------------------------

#define TM 64
#define TN 64
#define BK 32
#define LSTR 68   // fp32 kernel LDS row stride

typedef __attribute__((ext_vector_type(8))) short bf16x8;
typedef __attribute__((ext_vector_type(4))) float f32x4;

__device__ __forceinline__ unsigned pk_bf16(float a, float b) {
    unsigned ua = __float_as_uint(a), ub = __float_as_uint(b);
    ua += 0x7fffu + ((ua >> 16) & 1u);          // RNE
    ub += 0x7fffu + ((ub >> 16) & 1u);
    return (ua >> 16) | (ub & 0xffff0000u);
}

// ======================= fp32 GEMM (encoder + VQ) ==========================
__global__ __launch_bounds__(256)
void k_gemm(const float* __restrict__ Abase,
            const float* __restrict__ Wt,
            float* __restrict__ Cout,
            const float* __restrict__ bias,
            const float* __restrict__ bnS, const float* __restrict__ bnB,
            float* __restrict__ stats,
            unsigned long long* __restrict__ amin,
            const float* __restrict__ codesq,
            float* __restrict__ operm,
            int Mslice, int K, int N,
            int n_terms, int enc_mode, int decK)
{
    __shared__ __align__(16) float As[BK][LSTR];
    __shared__ __align__(16) float Bs[BK][LSTR];
    __shared__ float colsum[TN];
    __shared__ float colsq[TN];

    const int tid = threadIdx.x;
    const int z  = blockIdx.z;
    const int n0 = blockIdx.x * TN;
    const int m0 = blockIdx.y * TM;
    const int ty = tid >> 4;
    const int tx = tid & 15;

    if (stats != nullptr && tid < TN) { colsum[tid] = 0.f; colsq[tid] = 0.f; }

    float acc[4][4];
#pragma unroll
    for (int i = 0; i < 4; ++i)
#pragma unroll
        for (int j = 0; j < 4; ++j) acc[i][j] = 0.f;

    const int arow = tid >> 2;
    const int ac4  = (tid & 3) << 2;
    const int brow = tid >> 3;
    const int bc4  = (tid & 7) << 2;

    int mrow = m0 + arow;
    if (mrow > Mslice - 1) mrow = Mslice - 1;

    const bool alignedK = ((K & 31) == 0);
    const bool alignedN = ((N & 3) == 0);

    for (int term = 0; term < n_terms; ++term) {
        int a_slice, wk;
        if (enc_mode) { a_slice = z * n_terms + term; wk = term; }
        else          { a_slice = z / decK;           wk = z % decK; }
        const float* Ap = Abase + (size_t)a_slice * (size_t)Mslice * (size_t)K;
        const float* Wp = Wt    + (size_t)wk * (size_t)K * (size_t)N;
        const float* Arow_p = Ap + (size_t)mrow * (size_t)K;

        for (int k0 = 0; k0 < K; k0 += BK) {
            __syncthreads();
            if (alignedK) {
                float4 a0 = *(const float4*)(Arow_p + k0 + ac4);
                float4 a1 = *(const float4*)(Arow_p + k0 + ac4 + 16);
                if (bnS != nullptr) {
                    float4 s0 = *(const float4*)(bnS + k0 + ac4);
                    float4 c0 = *(const float4*)(bnB + k0 + ac4);
                    float4 s1 = *(const float4*)(bnS + k0 + ac4 + 16);
                    float4 c1 = *(const float4*)(bnB + k0 + ac4 + 16);
                    a0.x = fmaxf(fmaf(a0.x, s0.x, c0.x), 0.f);
                    a0.y = fmaxf(fmaf(a0.y, s0.y, c0.y), 0.f);
                    a0.z = fmaxf(fmaf(a0.z, s0.z, c0.z), 0.f);
                    a0.w = fmaxf(fmaf(a0.w, s0.w, c0.w), 0.f);
                    a1.x = fmaxf(fmaf(a1.x, s1.x, c1.x), 0.f);
                    a1.y = fmaxf(fmaf(a1.y, s1.y, c1.y), 0.f);
                    a1.z = fmaxf(fmaf(a1.z, s1.z, c1.z), 0.f);
                    a1.w = fmaxf(fmaf(a1.w, s1.w, c1.w), 0.f);
                }
                As[ac4+0][arow] = a0.x;  As[ac4+1][arow] = a0.y;
                As[ac4+2][arow] = a0.z;  As[ac4+3][arow] = a0.w;
                As[ac4+16][arow] = a1.x; As[ac4+17][arow] = a1.y;
                As[ac4+18][arow] = a1.z; As[ac4+19][arow] = a1.w;
            } else {
#pragma unroll
                for (int j = 0; j < 4; ++j) {
                    int k = k0 + ac4 + j;
                    As[ac4+j][arow] = (k < K) ? Arow_p[k] : 0.f;
                    int k2 = k + 16;
                    As[ac4+16+j][arow] = (k2 < K) ? Arow_p[k2] : 0.f;
                }
            }
            {
                int kB = k0 + brow;
                if (alignedN) {
                    float4 b0 = make_float4(0.f, 0.f, 0.f, 0.f);
                    float4 b1 = make_float4(0.f, 0.f, 0.f, 0.f);
                    if (kB < K) {
                        const float* wrow = Wp + (size_t)kB * N + n0;
                        b0 = *(const float4*)(wrow + bc4);
                        b1 = *(const float4*)(wrow + bc4 + 32);
                    }
                    *(float4*)&Bs[brow][bc4]      = b0;
                    *(float4*)&Bs[brow][bc4 + 32] = b1;
                } else {
#pragma unroll
                    for (int j = 0; j < 4; ++j) {
                        int n  = n0 + bc4 + j;
                        int n2 = n + 32;
                        Bs[brow][bc4+j]    = (kB < K && n  < N) ? Wp[(size_t)kB * N + n]  : 0.f;
                        Bs[brow][bc4+32+j] = (kB < K && n2 < N) ? Wp[(size_t)kB * N + n2] : 0.f;
                    }
                }
            }
            __syncthreads();
#pragma unroll
            for (int kk = 0; kk < BK; ++kk) {
                float4 av = *(const float4*)&As[kk][ty << 2];
                float4 bv = *(const float4*)&Bs[kk][tx << 2];
                acc[0][0] = fmaf(av.x, bv.x, acc[0][0]);
                acc[0][1] = fmaf(av.x, bv.y, acc[0][1]);
                acc[0][2] = fmaf(av.x, bv.z, acc[0][2]);
                acc[0][3] = fmaf(av.x, bv.w, acc[0][3]);
                acc[1][0] = fmaf(av.y, bv.x, acc[1][0]);
                acc[1][1] = fmaf(av.y, bv.y, acc[1][1]);
                acc[1][2] = fmaf(av.y, bv.z, acc[1][2]);
                acc[1][3] = fmaf(av.y, bv.w, acc[1][3]);
                acc[2][0] = fmaf(av.z, bv.x, acc[2][0]);
                acc[2][1] = fmaf(av.z, bv.y, acc[2][1]);
                acc[2][2] = fmaf(av.z, bv.z, acc[2][2]);
                acc[2][3] = fmaf(av.z, bv.w, acc[2][3]);
                acc[3][0] = fmaf(av.w, bv.x, acc[3][0]);
                acc[3][1] = fmaf(av.w, bv.y, acc[3][1]);
                acc[3][2] = fmaf(av.w, bv.z, acc[3][2]);
                acc[3][3] = fmaf(av.w, bv.w, acc[3][3]);
            }
        }
    }

    if (amin != nullptr) {
        float4 cq = *(const float4*)(codesq + n0 + (tx << 2));
#pragma unroll
        for (int i = 0; i < 4; ++i) {
            int m = m0 + (ty << 2) + i;
            if (m >= Mslice) continue;
            float d0 = cq.x - 2.f * acc[i][0];
            float d1 = cq.y - 2.f * acc[i][1];
            float d2 = cq.z - 2.f * acc[i][2];
            float d3 = cq.w - 2.f * acc[i][3];
            float best = d0; int bj = 0;
            if (d1 < best) { best = d1; bj = 1; }
            if (d2 < best) { best = d2; bj = 2; }
            if (d3 < best) { best = d3; bj = 3; }
            unsigned u = __float_as_uint(best);
            u = (u & 0x80000000u) ? ~u : (u | 0x80000000u);
            unsigned long long key =
                ((unsigned long long)u << 32) | (unsigned)(n0 + (tx << 2) + bj);
            atomicMin(&amin[m], key);
        }
        return;
    }

#pragma unroll
    for (int i = 0; i < 4; ++i) {
        int m = m0 + (ty << 2) + i;
        if (m >= Mslice) continue;
        float vv[4] = { acc[i][0], acc[i][1], acc[i][2], acc[i][3] };
        if (operm != nullptr) {
            int t = m >> 10, b = m & 1023;
#pragma unroll
            for (int j = 0; j < 4; ++j) {
                int n = n0 + (tx << 2) + j;
                if (n < N) {
                    float val = vv[j];
                    if (bias != nullptr) val += bias[n];
                    operm[(size_t)b * (30 * 135) + (size_t)t * 135 + n] = val;
                }
            }
        } else {
            float4 v = make_float4(vv[0], vv[1], vv[2], vv[3]);
            if (bias != nullptr) {
                float4 bb = *(const float4*)(bias + n0 + (tx << 2));
                v.x += bb.x; v.y += bb.y; v.z += bb.z; v.w += bb.w;
            }
            *(float4*)&Cout[((size_t)z * Mslice + m) * N + n0 + (tx << 2)] = v;
        }
    }

    if (stats != nullptr) {
#pragma unroll
        for (int j = 0; j < 4; ++j) {
            float s = 0.f, q = 0.f;
#pragma unroll
            for (int i = 0; i < 4; ++i) {
                int m = m0 + (ty << 2) + i;
                if (m < Mslice) { float x = acc[i][j]; s += x; q += x * x; }
            }
            atomicAdd(&colsum[(tx << 2) + j], s);
            atomicAdd(&colsq [(tx << 2) + j], q);
        }
        __syncthreads();
        if (tid < TN) {
            atomicAdd(&stats[n0 + tid],       colsum[tid]);
            atomicAdd(&stats[512 + n0 + tid], colsq[tid]);
        }
    }
}

// ======================= bf16 MFMA GEMM (decoder) ==========================
// C[z][m][n] = sum_k bnrelu(A[z/decK][m][k]) * Bt[z%decK][n][k]
// Block tile 128x128, 4 waves (2x2) of 64x64, mfma_f32_16x16x32_bf16.
#define ASTR 72   // LDS row stride in bf16 elems (144B: odd*16B -> <=2-way banks)

__global__ __launch_bounds__(256)
void k_mfma(const float* __restrict__ Abase, const unsigned short* __restrict__ Bt,
            float* __restrict__ Cout, const float* __restrict__ bias,
            const float* __restrict__ bnS, const float* __restrict__ bnB,
            float* __restrict__ stats, float* __restrict__ operm,
            int Mslice, int K, int N, int decK)
{
    __shared__ __align__(16) unsigned short As[128 * ASTR];
    __shared__ __align__(16) unsigned short Bs[128 * ASTR];
    __shared__ float colsum[128], colsq[128];

    const int tid  = threadIdx.x;
    const int lane = tid & 63;
    const int wave = tid >> 6;
    const int wm = (wave >> 1) << 6;
    const int wn = (wave & 1) << 6;
    const int z  = blockIdx.z;
    const int n0 = blockIdx.x << 7;
    const int m0 = blockIdx.y << 7;

    if (stats != nullptr && tid < 128) { colsum[tid] = 0.f; colsq[tid] = 0.f; }

    const int a_slice = z / decK, wk = z - a_slice * decK;
    const float* Ap = Abase + (size_t)a_slice * (size_t)Mslice * (size_t)K;
    const unsigned short* Bp = Bt + (size_t)wk * (size_t)N * (size_t)K;

    const int sr = tid >> 1;           // staging row 0..127
    const int sk = (tid & 1) << 5;     // k half: 0 or 32

    const float* Arow = Ap + (size_t)(m0 + sr) * K + sk;
    const unsigned short* Brow = Bp + (size_t)(n0 + sr) * K + sk;
    const bool bvalid = (n0 + sr) < N;

    f32x4 acc[4][4];
#pragma unroll
    for (int i = 0; i < 4; ++i)
#pragma unroll
        for (int j = 0; j < 4; ++j) acc[i][j] = (f32x4){0.f, 0.f, 0.f, 0.f};

    const int lidx = lane & 15;
    const int lq   = lane >> 4;

    for (int k0 = 0; k0 < K; k0 += 64) {
        __syncthreads();
        // ---- stage A: fp32 -> (bn+relu) -> bf16, 32 elems/thread ----
        {
            unsigned up[16];
#pragma unroll
            for (int i = 0; i < 8; ++i) {
                float4 f = *(const float4*)(Arow + k0 + (i << 2));
                if (bnS != nullptr) {
                    float4 s = *(const float4*)(bnS + k0 + sk + (i << 2));
                    float4 c = *(const float4*)(bnB + k0 + sk + (i << 2));
                    f.x = fmaxf(fmaf(f.x, s.x, c.x), 0.f);
                    f.y = fmaxf(fmaf(f.y, s.y, c.y), 0.f);
                    f.z = fmaxf(fmaf(f.z, s.z, c.z), 0.f);
                    f.w = fmaxf(fmaf(f.w, s.w, c.w), 0.f);
                }
                up[2*i]   = pk_bf16(f.x, f.y);
                up[2*i+1] = pk_bf16(f.z, f.w);
            }
            uint4* dst = (uint4*)&As[sr * ASTR + sk];
#pragma unroll
            for (int i = 0; i < 4; ++i)
                dst[i] = make_uint4(up[4*i], up[4*i+1], up[4*i+2], up[4*i+3]);
        }
        // ---- stage B: bf16 copy, 32 elems/thread ----
        {
            uint4* dst = (uint4*)&Bs[sr * ASTR + sk];
            if (bvalid) {
#pragma unroll
                for (int i = 0; i < 4; ++i)
                    dst[i] = *(const uint4*)(Brow + k0 + (i << 3));
            } else {
#pragma unroll
                for (int i = 0; i < 4; ++i)
                    dst[i] = make_uint4(0u, 0u, 0u, 0u);
            }
        }
        __syncthreads();
        // ---- 2 MFMA K-steps of 32 ----
#pragma unroll
        for (int ks = 0; ks < 2; ++ks) {
            const int kb = (ks << 5) + (lq << 3);
            bf16x8 af[4], bfv[4];
#pragma unroll
            for (int t = 0; t < 4; ++t)
                af[t] = *(const bf16x8*)&As[(wm + (t << 4) + lidx) * ASTR + kb];
#pragma unroll
            for (int t = 0; t < 4; ++t)
                bfv[t] = *(const bf16x8*)&Bs[(wn + (t << 4) + lidx) * ASTR + kb];
#pragma unroll
            for (int mt = 0; mt < 4; ++mt)
#pragma unroll
                for (int nt = 0; nt < 4; ++nt)
                    acc[mt][nt] = __builtin_amdgcn_mfma_f32_16x16x32_bf16(
                        af[mt], bfv[nt], acc[mt][nt], 0, 0, 0);
        }
    }

    // ---- epilogue: C/D layout col=lane&15, row=(lane>>4)*4+reg ----
    const int rbase = lq << 2;
#pragma unroll
    for (int nt = 0; nt < 4; ++nt) {
        const int col = n0 + wn + (nt << 4) + lidx;
        float s = 0.f, q = 0.f;
#pragma unroll
        for (int mt = 0; mt < 4; ++mt) {
#pragma unroll
            for (int r = 0; r < 4; ++r) {
                float x = acc[mt][nt][r];
                s += x; q += x * x;
                const int row = m0 + wm + (mt << 4) + rbase + r;
                if (operm != nullptr) {
                    if (col < N) {
                        const int t = row >> 10, b = row & 1023;
                        operm[(size_t)b * 4050 + t * 135 + col] = x + bias[col];
                    }
                } else {
                    float v = x;
                    if (bias != nullptr) v += bias[col];
                    Cout[((size_t)z * Mslice + row) * (size_t)N + col] = v;
                }
            }
        }
        if (stats != nullptr) {
            s += __shfl_xor(s, 16, 64); s += __shfl_xor(s, 32, 64);
            q += __shfl_xor(q, 16, 64); q += __shfl_xor(q, 32, 64);
            if (lq == 0) {
                atomicAdd(&colsum[wn + (nt << 4) + lidx], s);
                atomicAdd(&colsq [wn + (nt << 4) + lidx], q);
            }
        }
    }
    if (stats != nullptr) {
        __syncthreads();
        if (tid < 128) {
            const int c = n0 + tid;
            if (c < N) {
                atomicAdd(&stats[c],       colsum[tid]);
                atomicAdd(&stats[512 + c], colsq[tid]);
            }
        }
    }
}

// ============================ small kernels ================================
__global__ void k_init(float* __restrict__ zbase, unsigned long long* __restrict__ amin)
{
    int t = blockIdx.x * 256 + threadIdx.x;
    if (t < 6720) zbase[t] = 0.f;               // stats + loss + hist
    if (t < 1024) amin[t] = ~0ULL;
}

// fp32 repack to [k][i*512+o]; swap_oi=1 for encoder (O,I,K) / codebook
__global__ void k_repack(const float* __restrict__ w, float* __restrict__ wt,
                         int Kc, int swap_oi, int total)
{
    int idx = blockIdx.x * 256 + threadIdx.x;
    if (idx >= total) return;
    int k = idx >> 18;
    int rem = idx & 262143;
    int i = rem >> 9, o = rem & 511;
    int src = swap_oi ? (((o << 9) + i) * Kc + k) : (((i << 9) + o) * Kc + k);
    wt[idx] = w[src];
}

// bf16 repack to [k][o][i]; src is (I,O,Kc) i.e. src = (i*O+o)*Kc + k
__global__ void k_repack_bf(const float* __restrict__ w, unsigned short* __restrict__ wt,
                            int Kc, int I, int O, int total)
{
    int idx = blockIdx.x * 256 + threadIdx.x;
    if (idx >= total) return;
    int i = idx % I;
    int o = (idx / I) % O;
    int k = idx / (I * O);
    float v = w[((size_t)i * O + o) * Kc + k];
    unsigned u = __float_as_uint(v);
    u += 0x7fffu + ((u >> 16) & 1u);
    wt[idx] = (unsigned short)(u >> 16);
}

__global__ void k_codesq(const float* __restrict__ cb, float* __restrict__ outq)
{
    int c = blockIdx.x; int l = threadIdx.x;
    float s = 0.f;
    for (int i = l; i < 512; i += 64) { float v = cb[c * 512 + i]; s += v * v; }
    for (int off = 32; off; off >>= 1) s += __shfl_down(s, off, 64);
    if (l == 0) outq[c] = s;
}

__global__ void k_bn_fin(const float* __restrict__ stats,
                         const float* __restrict__ g, const float* __restrict__ b,
                         float* __restrict__ sc, float* __restrict__ sh, float inv_n)
{
    int c = blockIdx.x * blockDim.x + threadIdx.x;
    if (c >= 512) return;
    float m = stats[c] * inv_n;
    float v = stats[512 + c] * inv_n - m * m;
    float a = (float)((double)g[c] / sqrt((double)v + 1e-5));
    sc[c] = a;
    sh[c] = b[c] - m * a;
}

__global__ void k_vq_gather(const unsigned long long* __restrict__ amin,
                            const float* __restrict__ codebook,
                            const float* __restrict__ e3pre,
                            const float* __restrict__ sc, const float* __restrict__ sh,
                            float* __restrict__ quant, float* __restrict__ loss,
                            unsigned int* __restrict__ hist)
{
    int b = blockIdx.x; int t = threadIdx.x;   // 256 threads
    unsigned int idx = (unsigned int)(amin[b] & 0xFFFFFFFFull) & 511u;
    float part = 0.f;
    for (int i = t; i < 512; i += 256) {
        float q = codebook[(size_t)idx * 512 + i];
        quant[(size_t)b * 512 + i] = q;
        float x = e3pre[(size_t)b * 512 + i];
        float f = fmaxf(fmaf(x, sc[i], sh[i]), 0.f);
        float d = q - f;
        part += d * d;
    }
    for (int off = 32; off; off >>= 1) part += __shfl_down(part, off, 64);
    __shared__ float red[4];
    if ((t & 63) == 0) red[t >> 6] = part;
    __syncthreads();
    if (t == 0) {
        atomicAdd(loss, red[0] + red[1] + red[2] + red[3]);
        atomicAdd(&hist[idx], 1u);
    }
}

__global__ void k_scalars(const unsigned int* __restrict__ hist,
                          const float* __restrict__ loss, float* __restrict__ out)
{
    int t = threadIdx.x;   // 512
    float p = (float)hist[t] * (1.0f / 1024.0f);
    float e = p * logf(p + 1e-10f);
    for (int off = 32; off; off >>= 1) e += __shfl_down(e, off, 64);
    __shared__ float red[8];
    if ((t & 63) == 0) red[t >> 6] = e;
    __syncthreads();
    if (t == 0) {
        float s = 0.f;
        for (int i = 0; i < 8; ++i) s += red[i];
        out[4147200] = 1.25f * loss[0] * (1.0f / 524288.0f);
        out[4147201] = expf(-s);
    }
}

extern "C" void kernel_launch(void* const* d_in, const int* in_sizes, int n_in,
                              void* d_out, int out_size, void* d_ws, size_t ws_size,
                              hipStream_t stream)
{
    const float* in_seqs = (const float*)d_in[0];
    const float* W_in  = (const float*)d_in[1];
    // d_in[2] = b_in: dropped (BN shift-invariance)
    const float* w_e1  = (const float*)d_in[3];
    const float* g_e1  = (const float*)d_in[4];
    const float* be1   = (const float*)d_in[5];
    const float* w_e2  = (const float*)d_in[6];
    const float* g_e2  = (const float*)d_in[7];
    const float* be2   = (const float*)d_in[8];
    const float* w_e3  = (const float*)d_in[9];
    const float* g_e3  = (const float*)d_in[10];
    const float* be3   = (const float*)d_in[11];
    const float* codebook = (const float*)d_in[12];
    const float* W_q   = (const float*)d_in[13];
    const float* b_q   = (const float*)d_in[14];
    const float* w_d1  = (const float*)d_in[15];
    const float* g_d1  = (const float*)d_in[16];
    const float* bd1   = (const float*)d_in[17];
    const float* w_d2  = (const float*)d_in[18];
    const float* g_d2  = (const float*)d_in[19];
    const float* bd2   = (const float*)d_in[20];
    const float* w_d3  = (const float*)d_in[21];
    const float* g_d3  = (const float*)d_in[22];
    const float* bd3   = (const float*)d_in[23];
    const float* W_out = (const float*)d_in[24];
    const float* b_out = (const float*)d_in[25];
    float* out = (float*)d_out;

    // ---- workspace layout (floats) ----
    float* W = (float*)d_ws;
    unsigned long long* amin = (unsigned long long*)W;     // 1024 u64 = 2048 f
    float* stats  = W + 2048;                              // 6144
    float* lossp  = W + 8192;                              // 64
    unsigned int* hist = (unsigned int*)(W + 8256);        // 512
    float* scsh   = W + 8768;                              // 6144
    float* codesq = W + 14912;                             // 512
    float* wt_e1 = W + 15424;                              // 5*262144 (fp32)
    float* wt_e2 = wt_e1 + 5 * 262144;                     // 3*262144
    float* wt_e3 = wt_e2 + 3 * 262144;                     // 2*262144
    float* codeT = wt_e3 + 2 * 262144;                     // 262144
    float* weff  = codeT + 262144;                         // 5*135*512 = 345600
    const size_t SLICE = 1024u * 512u;
    float* e1    = weff + 345600;                          // 6 slices (reused as d2)
    float* e2    = e1 + 6 * SLICE;                         // 2 slices (reused as d1)
    float* e3    = e2 + 2 * SLICE;                         // 1
    float* quant = e3 + SLICE;                             // 1
    float* d0v   = quant + SLICE;                          // 1
    float* d3v   = d0v + SLICE;                            // 30 slices

    // bf16 weights overlay the wt_e1/wt_e2 region (dead after weff / e2 GEMMs)
    unsigned short* bfb   = (unsigned short*)wt_e1;
    unsigned short* wqb   = bfb;                 // 262144 sh  (in wt_e1)
    unsigned short* wd1b  = bfb + 262144;        // 524288 sh  (in wt_e1)
    unsigned short* wd2b  = bfb + 786432;        // 786432 sh  (in wt_e1)
    unsigned short* wd3b  = bfb + 1572864;       // 1310720 sh (crosses into wt_e2)
    unsigned short* woutb = bfb + 2883584;       // 69120 sh   (in wt_e2)

    float* st_e1 = stats + 0 * 1024; float* sc_e1 = scsh + 0 * 1024; float* sh_e1 = sc_e1 + 512;
    float* st_e2 = stats + 1 * 1024; float* sc_e2 = scsh + 1 * 1024; float* sh_e2 = sc_e2 + 512;
    float* st_e3 = stats + 2 * 1024; float* sc_e3 = scsh + 2 * 1024; float* sh_e3 = sc_e3 + 512;
    float* st_d1 = stats + 3 * 1024; float* sc_d1 = scsh + 3 * 1024; float* sh_d1 = sc_d1 + 512;
    float* st_d2 = stats + 4 * 1024; float* sc_d2 = scsh + 4 * 1024; float* sh_d2 = sc_d2 + 512;
    float* st_d3 = stats + 5 * 1024; float* sc_d3 = scsh + 5 * 1024; float* sh_d3 = sc_d3 + 512;

    float* d1v = e2;   // e2 dead after conv_e3
    float* d2v = e1;   // e1 dead after conv_e2

    dim3 blk(256);
    k_init<<<dim3(32), blk, 0, stream>>>(stats, amin);

    // encoder weight repacks (fp32) + codebook
    k_repack<<<dim3(5 * 1024), blk, 0, stream>>>(w_e1, wt_e1, 5, 1, 5 * 262144);
    k_repack<<<dim3(3 * 1024), blk, 0, stream>>>(w_e2, wt_e2, 3, 1, 3 * 262144);
    k_repack<<<dim3(2 * 1024), blk, 0, stream>>>(w_e3, wt_e3, 2, 1, 2 * 262144);
    k_repack<<<dim3(1024),     blk, 0, stream>>>(codebook, codeT, 1, 1, 262144);
    k_codesq<<<dim3(512), dim3(64), 0, stream>>>(codebook, codesq);

    // weff[k] = W_in (135x512) @ wt_e1[k]
    k_gemm<<<dim3(8, 3, 5), blk, 0, stream>>>(W_in, wt_e1, weff, nullptr,
        nullptr, nullptr, nullptr, nullptr, nullptr, nullptr, 135, 512, 512, 1, 0, 5);

    // e1 = conv(x, weff) (input projection folded), K=135, 5 terms
    k_gemm<<<dim3(8, 16, 6), blk, 0, stream>>>(in_seqs, weff, e1, nullptr,
        nullptr, nullptr, st_e1, nullptr, nullptr, nullptr, 1024, 135, 512, 5, 1, 1);
    k_bn_fin<<<dim3(2), blk, 0, stream>>>(st_e1, g_e1, be1, sc_e1, sh_e1, 1.f / 6144.f);

    k_gemm<<<dim3(8, 16, 2), blk, 0, stream>>>(e1, wt_e2, e2, nullptr,
        sc_e1, sh_e1, st_e2, nullptr, nullptr, nullptr, 1024, 512, 512, 3, 1, 1);
    k_bn_fin<<<dim3(2), blk, 0, stream>>>(st_e2, g_e2, be2, sc_e2, sh_e2, 1.f / 2048.f);

    // bf16 decoder-weight repacks (wt_e1/wt_e2 regions are dead now)
    k_repack_bf<<<dim3(1024),     blk, 0, stream>>>(W_q,   wqb,   1, 512, 512, 262144);
    k_repack_bf<<<dim3(2 * 1024), blk, 0, stream>>>(w_d1,  wd1b,  2, 512, 512, 524288);
    k_repack_bf<<<dim3(3 * 1024), blk, 0, stream>>>(w_d2,  wd2b,  3, 512, 512, 786432);
    k_repack_bf<<<dim3(5 * 1024), blk, 0, stream>>>(w_d3,  wd3b,  5, 512, 512, 1310720);
    k_repack_bf<<<dim3(270),      blk, 0, stream>>>(W_out, woutb, 1, 512, 135, 69120);

    k_gemm<<<dim3(8, 16, 1), blk, 0, stream>>>(e2, wt_e3, e3, nullptr,
        sc_e2, sh_e2, st_e3, nullptr, nullptr, nullptr, 1024, 512, 512, 2, 1, 1);
    k_bn_fin<<<dim3(2), blk, 0, stream>>>(st_e3, g_e3, be3, sc_e3, sh_e3, 1.f / 1024.f);

    // VQ: dist GEMM + argmin (fp32, bit-identical to round 3)
    k_gemm<<<dim3(8, 16, 1), blk, 0, stream>>>(e3, codeT, nullptr, nullptr,
        sc_e3, sh_e3, nullptr, amin, codesq, nullptr, 1024, 512, 512, 1, 1, 1);
    k_vq_gather<<<dim3(1024), blk, 0, stream>>>(amin, codebook, e3, sc_e3, sh_e3,
                                                quant, lossp, hist);

    // ---- decoder side: bf16 MFMA ----
    // d0 = quant @ W_q + b_q
    k_mfma<<<dim3(4, 8, 1), blk, 0, stream>>>(quant, wqb, d0v, b_q,
        nullptr, nullptr, nullptr, nullptr, 1024, 512, 512, 1);

    k_mfma<<<dim3(4, 8, 2), blk, 0, stream>>>(d0v, wd1b, d1v, nullptr,
        nullptr, nullptr, st_d1, nullptr, 1024, 512, 512, 2);
    k_bn_fin<<<dim3(2), blk, 0, stream>>>(st_d1, g_d1, bd1, sc_d1, sh_d1, 1.f / 2048.f);

    k_mfma<<<dim3(4, 8, 6), blk, 0, stream>>>(d1v, wd2b, d2v, nullptr,
        sc_d1, sh_d1, st_d2, nullptr, 1024, 512, 512, 3);
    k_bn_fin<<<dim3(2), blk, 0, stream>>>(st_d2, g_d2, bd2, sc_d2, sh_d2, 1.f / 6144.f);

    k_mfma<<<dim3(4, 8, 30), blk, 0, stream>>>(d2v, wd3b, d3v, nullptr,
        sc_d2, sh_d2, st_d3, nullptr, 1024, 512, 512, 5);
    k_bn_fin<<<dim3(2), blk, 0, stream>>>(st_d3, g_d3, bd3, sc_d3, sh_d3, 1.f / 30720.f);

    // recon = bnrelu(d3) @ W_out + b_out, (b,t,p)-permuted write
    k_mfma<<<dim3(2, 240, 1), blk, 0, stream>>>(d3v, woutb, nullptr, b_out,
        sc_d3, sh_d3, nullptr, out, 30720, 512, 135, 1);

    k_scalars<<<dim3(1), dim3(512), 0, stream>>>(hist, lossp, out);
}

// Round 5
// 748.265 us; speedup vs baseline: 1.3677x; 1.0820x over previous
//
#include <hip/hip_runtime.h>
#include <math.h>

// ---------------------------------------------------------------------------
// VQ-VAE forward (round 5).
//  - Encoder convs e1/e2/e3: split-bf16 MFMA (hi+lo decomposition, 3 MFMA
//    passes -> fp32-class accuracy, ~830 TF ceiling). VQ dist+argmin stays
//    pure fp32 (bit-identical to rounds 3/4).
//  - Decoder: single-bf16 MFMA (unchanged from round 4).
//  - Workspace: split-enc weights overlay the d3v region (dead until the
//    decoder); decoder bf16 weights overlay dead wt_e1+weff. Total ~94 MB,
//    below round 4's ~99 MB.
// ---------------------------------------------------------------------------

#define TM 64
#define TN 64
#define BK 32
#define LSTR 68   // fp32 kernel LDS row stride

typedef __attribute__((ext_vector_type(8))) short bf16x8;
typedef __attribute__((ext_vector_type(4))) float f32x4;

__device__ __forceinline__ unsigned pk_bf16(float a, float b) {
    unsigned ua = __float_as_uint(a), ub = __float_as_uint(b);
    ua += 0x7fffu + ((ua >> 16) & 1u);          // RNE
    ub += 0x7fffu + ((ub >> 16) & 1u);
    return (ua >> 16) | (ub & 0xffff0000u);
}
__device__ __forceinline__ unsigned short bfh(float x) {
    unsigned u = __float_as_uint(x);
    u += 0x7fffu + ((u >> 16) & 1u);
    return (unsigned short)(u >> 16);
}
__device__ __forceinline__ float bf2f(unsigned short h) {
    return __uint_as_float(((unsigned)h) << 16);
}

// ======================= fp32 GEMM (weff + VQ dist) ========================
__global__ __launch_bounds__(256)
void k_gemm(const float* __restrict__ Abase,
            const float* __restrict__ Wt,
            float* __restrict__ Cout,
            const float* __restrict__ bias,
            const float* __restrict__ bnS, const float* __restrict__ bnB,
            float* __restrict__ stats,
            unsigned long long* __restrict__ amin,
            const float* __restrict__ codesq,
            float* __restrict__ operm,
            int Mslice, int K, int N,
            int n_terms, int enc_mode, int decK)
{
    __shared__ __align__(16) float As[BK][LSTR];
    __shared__ __align__(16) float Bs[BK][LSTR];
    __shared__ float colsum[TN];
    __shared__ float colsq[TN];

    const int tid = threadIdx.x;
    const int z  = blockIdx.z;
    const int n0 = blockIdx.x * TN;
    const int m0 = blockIdx.y * TM;
    const int ty = tid >> 4;
    const int tx = tid & 15;

    if (stats != nullptr && tid < TN) { colsum[tid] = 0.f; colsq[tid] = 0.f; }

    float acc[4][4];
#pragma unroll
    for (int i = 0; i < 4; ++i)
#pragma unroll
        for (int j = 0; j < 4; ++j) acc[i][j] = 0.f;

    const int arow = tid >> 2;
    const int ac4  = (tid & 3) << 2;
    const int brow = tid >> 3;
    const int bc4  = (tid & 7) << 2;

    int mrow = m0 + arow;
    if (mrow > Mslice - 1) mrow = Mslice - 1;

    const bool alignedK = ((K & 31) == 0);
    const bool alignedN = ((N & 3) == 0);

    for (int term = 0; term < n_terms; ++term) {
        int a_slice, wk;
        if (enc_mode) { a_slice = z * n_terms + term; wk = term; }
        else          { a_slice = z / decK;           wk = z % decK; }
        const float* Ap = Abase + (size_t)a_slice * (size_t)Mslice * (size_t)K;
        const float* Wp = Wt    + (size_t)wk * (size_t)K * (size_t)N;
        const float* Arow_p = Ap + (size_t)mrow * (size_t)K;

        for (int k0 = 0; k0 < K; k0 += BK) {
            __syncthreads();
            if (alignedK) {
                float4 a0 = *(const float4*)(Arow_p + k0 + ac4);
                float4 a1 = *(const float4*)(Arow_p + k0 + ac4 + 16);
                if (bnS != nullptr) {
                    float4 s0 = *(const float4*)(bnS + k0 + ac4);
                    float4 c0 = *(const float4*)(bnB + k0 + ac4);
                    float4 s1 = *(const float4*)(bnS + k0 + ac4 + 16);
                    float4 c1 = *(const float4*)(bnB + k0 + ac4 + 16);
                    a0.x = fmaxf(fmaf(a0.x, s0.x, c0.x), 0.f);
                    a0.y = fmaxf(fmaf(a0.y, s0.y, c0.y), 0.f);
                    a0.z = fmaxf(fmaf(a0.z, s0.z, c0.z), 0.f);
                    a0.w = fmaxf(fmaf(a0.w, s0.w, c0.w), 0.f);
                    a1.x = fmaxf(fmaf(a1.x, s1.x, c1.x), 0.f);
                    a1.y = fmaxf(fmaf(a1.y, s1.y, c1.y), 0.f);
                    a1.z = fmaxf(fmaf(a1.z, s1.z, c1.z), 0.f);
                    a1.w = fmaxf(fmaf(a1.w, s1.w, c1.w), 0.f);
                }
                As[ac4+0][arow] = a0.x;  As[ac4+1][arow] = a0.y;
                As[ac4+2][arow] = a0.z;  As[ac4+3][arow] = a0.w;
                As[ac4+16][arow] = a1.x; As[ac4+17][arow] = a1.y;
                As[ac4+18][arow] = a1.z; As[ac4+19][arow] = a1.w;
            } else {
#pragma unroll
                for (int j = 0; j < 4; ++j) {
                    int k = k0 + ac4 + j;
                    As[ac4+j][arow] = (k < K) ? Arow_p[k] : 0.f;
                    int k2 = k + 16;
                    As[ac4+16+j][arow] = (k2 < K) ? Arow_p[k2] : 0.f;
                }
            }
            {
                int kB = k0 + brow;
                if (alignedN) {
                    float4 b0 = make_float4(0.f, 0.f, 0.f, 0.f);
                    float4 b1 = make_float4(0.f, 0.f, 0.f, 0.f);
                    if (kB < K) {
                        const float* wrow = Wp + (size_t)kB * N + n0;
                        b0 = *(const float4*)(wrow + bc4);
                        b1 = *(const float4*)(wrow + bc4 + 32);
                    }
                    *(float4*)&Bs[brow][bc4]      = b0;
                    *(float4*)&Bs[brow][bc4 + 32] = b1;
                } else {
#pragma unroll
                    for (int j = 0; j < 4; ++j) {
                        int n  = n0 + bc4 + j;
                        int n2 = n + 32;
                        Bs[brow][bc4+j]    = (kB < K && n  < N) ? Wp[(size_t)kB * N + n]  : 0.f;
                        Bs[brow][bc4+32+j] = (kB < K && n2 < N) ? Wp[(size_t)kB * N + n2] : 0.f;
                    }
                }
            }
            __syncthreads();
#pragma unroll
            for (int kk = 0; kk < BK; ++kk) {
                float4 av = *(const float4*)&As[kk][ty << 2];
                float4 bv = *(const float4*)&Bs[kk][tx << 2];
                acc[0][0] = fmaf(av.x, bv.x, acc[0][0]);
                acc[0][1] = fmaf(av.x, bv.y, acc[0][1]);
                acc[0][2] = fmaf(av.x, bv.z, acc[0][2]);
                acc[0][3] = fmaf(av.x, bv.w, acc[0][3]);
                acc[1][0] = fmaf(av.y, bv.x, acc[1][0]);
                acc[1][1] = fmaf(av.y, bv.y, acc[1][1]);
                acc[1][2] = fmaf(av.y, bv.z, acc[1][2]);
                acc[1][3] = fmaf(av.y, bv.w, acc[1][3]);
                acc[2][0] = fmaf(av.z, bv.x, acc[2][0]);
                acc[2][1] = fmaf(av.z, bv.y, acc[2][1]);
                acc[2][2] = fmaf(av.z, bv.z, acc[2][2]);
                acc[2][3] = fmaf(av.z, bv.w, acc[2][3]);
                acc[3][0] = fmaf(av.w, bv.x, acc[3][0]);
                acc[3][1] = fmaf(av.w, bv.y, acc[3][1]);
                acc[3][2] = fmaf(av.w, bv.z, acc[3][2]);
                acc[3][3] = fmaf(av.w, bv.w, acc[3][3]);
            }
        }
    }

    if (amin != nullptr) {
        float4 cq = *(const float4*)(codesq + n0 + (tx << 2));
#pragma unroll
        for (int i = 0; i < 4; ++i) {
            int m = m0 + (ty << 2) + i;
            if (m >= Mslice) continue;
            float d0 = cq.x - 2.f * acc[i][0];
            float d1 = cq.y - 2.f * acc[i][1];
            float d2 = cq.z - 2.f * acc[i][2];
            float d3 = cq.w - 2.f * acc[i][3];
            float best = d0; int bj = 0;
            if (d1 < best) { best = d1; bj = 1; }
            if (d2 < best) { best = d2; bj = 2; }
            if (d3 < best) { best = d3; bj = 3; }
            unsigned u = __float_as_uint(best);
            u = (u & 0x80000000u) ? ~u : (u | 0x80000000u);
            unsigned long long key =
                ((unsigned long long)u << 32) | (unsigned)(n0 + (tx << 2) + bj);
            atomicMin(&amin[m], key);
        }
        return;
    }

#pragma unroll
    for (int i = 0; i < 4; ++i) {
        int m = m0 + (ty << 2) + i;
        if (m >= Mslice) continue;
        float4 v = make_float4(acc[i][0], acc[i][1], acc[i][2], acc[i][3]);
        if (bias != nullptr) {
            float4 bb = *(const float4*)(bias + n0 + (tx << 2));
            v.x += bb.x; v.y += bb.y; v.z += bb.z; v.w += bb.w;
        }
        *(float4*)&Cout[((size_t)z * Mslice + m) * N + n0 + (tx << 2)] = v;
    }

    if (stats != nullptr) {
#pragma unroll
        for (int j = 0; j < 4; ++j) {
            float s = 0.f, q = 0.f;
#pragma unroll
            for (int i = 0; i < 4; ++i) {
                int m = m0 + (ty << 2) + i;
                if (m < Mslice) { float x = acc[i][j]; s += x; q += x * x; }
            }
            atomicAdd(&colsum[(tx << 2) + j], s);
            atomicAdd(&colsq [(tx << 2) + j], q);
        }
        __syncthreads();
        if (tid < TN) {
            atomicAdd(&stats[n0 + tid],       colsum[tid]);
            atomicAdd(&stats[512 + n0 + tid], colsq[tid]);
        }
    }
}

// ======================= bf16 MFMA GEMM (decoder) ==========================
#define ASTR 72

__global__ __launch_bounds__(256)
void k_mfma(const float* __restrict__ Abase, const unsigned short* __restrict__ Bt,
            float* __restrict__ Cout, const float* __restrict__ bias,
            const float* __restrict__ bnS, const float* __restrict__ bnB,
            float* __restrict__ stats, float* __restrict__ operm,
            int Mslice, int K, int N, int decK)
{
    __shared__ __align__(16) unsigned short As[128 * ASTR];
    __shared__ __align__(16) unsigned short Bs[128 * ASTR];
    __shared__ float colsum[128], colsq[128];

    const int tid  = threadIdx.x;
    const int lane = tid & 63;
    const int wave = tid >> 6;
    const int wm = (wave >> 1) << 6;
    const int wn = (wave & 1) << 6;
    const int z  = blockIdx.z;
    const int n0 = blockIdx.x << 7;
    const int m0 = blockIdx.y << 7;

    if (stats != nullptr && tid < 128) { colsum[tid] = 0.f; colsq[tid] = 0.f; }

    const int a_slice = z / decK, wk = z - a_slice * decK;
    const float* Ap = Abase + (size_t)a_slice * (size_t)Mslice * (size_t)K;
    const unsigned short* Bp = Bt + (size_t)wk * (size_t)N * (size_t)K;

    const int sr = tid >> 1;
    const int sk = (tid & 1) << 5;

    const float* Arow = Ap + (size_t)(m0 + sr) * K + sk;
    const unsigned short* Brow = Bp + (size_t)(n0 + sr) * K + sk;
    const bool bvalid = (n0 + sr) < N;

    f32x4 acc[4][4];
#pragma unroll
    for (int i = 0; i < 4; ++i)
#pragma unroll
        for (int j = 0; j < 4; ++j) acc[i][j] = (f32x4){0.f, 0.f, 0.f, 0.f};

    const int lidx = lane & 15;
    const int lq   = lane >> 4;

    for (int k0 = 0; k0 < K; k0 += 64) {
        __syncthreads();
        {
            unsigned up[16];
#pragma unroll
            for (int i = 0; i < 8; ++i) {
                float4 f = *(const float4*)(Arow + k0 + (i << 2));
                if (bnS != nullptr) {
                    float4 s = *(const float4*)(bnS + k0 + sk + (i << 2));
                    float4 c = *(const float4*)(bnB + k0 + sk + (i << 2));
                    f.x = fmaxf(fmaf(f.x, s.x, c.x), 0.f);
                    f.y = fmaxf(fmaf(f.y, s.y, c.y), 0.f);
                    f.z = fmaxf(fmaf(f.z, s.z, c.z), 0.f);
                    f.w = fmaxf(fmaf(f.w, s.w, c.w), 0.f);
                }
                up[2*i]   = pk_bf16(f.x, f.y);
                up[2*i+1] = pk_bf16(f.z, f.w);
            }
            uint4* dst = (uint4*)&As[sr * ASTR + sk];
#pragma unroll
            for (int i = 0; i < 4; ++i)
                dst[i] = make_uint4(up[4*i], up[4*i+1], up[4*i+2], up[4*i+3]);
        }
        {
            uint4* dst = (uint4*)&Bs[sr * ASTR + sk];
            if (bvalid) {
#pragma unroll
                for (int i = 0; i < 4; ++i)
                    dst[i] = *(const uint4*)(Brow + k0 + (i << 3));
            } else {
#pragma unroll
                for (int i = 0; i < 4; ++i)
                    dst[i] = make_uint4(0u, 0u, 0u, 0u);
            }
        }
        __syncthreads();
#pragma unroll
        for (int ks = 0; ks < 2; ++ks) {
            const int kb = (ks << 5) + (lq << 3);
            bf16x8 af[4], bfv[4];
#pragma unroll
            for (int t = 0; t < 4; ++t)
                af[t] = *(const bf16x8*)&As[(wm + (t << 4) + lidx) * ASTR + kb];
#pragma unroll
            for (int t = 0; t < 4; ++t)
                bfv[t] = *(const bf16x8*)&Bs[(wn + (t << 4) + lidx) * ASTR + kb];
#pragma unroll
            for (int mt = 0; mt < 4; ++mt)
#pragma unroll
                for (int nt = 0; nt < 4; ++nt)
                    acc[mt][nt] = __builtin_amdgcn_mfma_f32_16x16x32_bf16(
                        af[mt], bfv[nt], acc[mt][nt], 0, 0, 0);
        }
    }

    const int rbase = lq << 2;
#pragma unroll
    for (int nt = 0; nt < 4; ++nt) {
        const int col = n0 + wn + (nt << 4) + lidx;
        float s = 0.f, q = 0.f;
#pragma unroll
        for (int mt = 0; mt < 4; ++mt) {
#pragma unroll
            for (int r = 0; r < 4; ++r) {
                float x = acc[mt][nt][r];
                s += x; q += x * x;
                const int row = m0 + wm + (mt << 4) + rbase + r;
                if (operm != nullptr) {
                    if (col < N) {
                        const int t = row >> 10, b = row & 1023;
                        operm[(size_t)b * 4050 + t * 135 + col] = x + bias[col];
                    }
                } else {
                    float v = x;
                    if (bias != nullptr) v += bias[col];
                    Cout[((size_t)z * Mslice + row) * (size_t)N + col] = v;
                }
            }
        }
        if (stats != nullptr) {
            s += __shfl_xor(s, 16, 64); s += __shfl_xor(s, 32, 64);
            q += __shfl_xor(q, 16, 64); q += __shfl_xor(q, 32, 64);
            if (lq == 0) {
                atomicAdd(&colsum[wn + (nt << 4) + lidx], s);
                atomicAdd(&colsq [wn + (nt << 4) + lidx], q);
            }
        }
    }
    if (stats != nullptr) {
        __syncthreads();
        if (tid < 128) {
            const int c = n0 + tid;
            if (c < N) {
                atomicAdd(&stats[c],       colsum[tid]);
                atomicAdd(&stats[512 + c], colsq[tid]);
            }
        }
    }
}

// ================= split-bf16 MFMA GEMM (encoder convs) ====================
// C = sum_term bnrelu(A[z*n_terms+term]) @ W[term]^T with hi/lo bf16 weights.
// K-chunk 32, LDS 4 tiles of 128x40 bf16 (42 KB). 3 MFMA passes per pair.
#define SSTR 40

__global__ __launch_bounds__(256)
void k_mfma_sp(const float* __restrict__ Abase,
               const unsigned short* __restrict__ Whi,
               const unsigned short* __restrict__ Wlo,
               float* __restrict__ Cout,
               const float* __restrict__ bnS, const float* __restrict__ bnB,
               float* __restrict__ stats,
               int Mslice, int Kterm, int Kp, int N, int n_terms)
{
    __shared__ __align__(16) unsigned short Ah[128 * SSTR];
    __shared__ __align__(16) unsigned short Al[128 * SSTR];
    __shared__ __align__(16) unsigned short Bh[128 * SSTR];
    __shared__ __align__(16) unsigned short Bl[128 * SSTR];
    __shared__ float colsum[128], colsq[128];

    const int tid  = threadIdx.x;
    const int lane = tid & 63;
    const int wave = tid >> 6;
    const int wm = (wave >> 1) << 6;
    const int wn = (wave & 1) << 6;
    const int z  = blockIdx.z;
    const int n0 = blockIdx.x << 7;
    const int m0 = blockIdx.y << 7;

    if (stats != nullptr && tid < 128) { colsum[tid] = 0.f; colsq[tid] = 0.f; }

    const int sr = tid >> 1;           // 0..127
    const int sk = (tid & 1) << 4;     // 0 or 16

    f32x4 acc[4][4];
#pragma unroll
    for (int i = 0; i < 4; ++i)
#pragma unroll
        for (int j = 0; j < 4; ++j) acc[i][j] = (f32x4){0.f, 0.f, 0.f, 0.f};

    const int lidx = lane & 15;
    const int lq   = lane >> 4;
    const int kb   = lq << 3;

    for (int term = 0; term < n_terms; ++term) {
        const float* Arow = Abase
            + (size_t)(z * n_terms + term) * (size_t)Mslice * (size_t)Kterm
            + (size_t)(m0 + sr) * (size_t)Kterm;
        const unsigned short* BrowH = Whi + ((size_t)term * N + n0 + sr) * (size_t)Kp;
        const unsigned short* BrowL = Wlo + ((size_t)term * N + n0 + sr) * (size_t)Kp;

        for (int k0 = 0; k0 < Kp; k0 += 32) {
            __syncthreads();
            // ---- stage A: fp32 -> (bn+relu) -> hi/lo bf16, 16 elems ----
            {
                float xv[16];
                if (k0 + 32 <= Kterm) {
#pragma unroll
                    for (int i = 0; i < 4; ++i) {
                        float4 f = *(const float4*)(Arow + k0 + sk + (i << 2));
                        if (bnS != nullptr) {
                            float4 s = *(const float4*)(bnS + k0 + sk + (i << 2));
                            float4 c = *(const float4*)(bnB + k0 + sk + (i << 2));
                            f.x = fmaxf(fmaf(f.x, s.x, c.x), 0.f);
                            f.y = fmaxf(fmaf(f.y, s.y, c.y), 0.f);
                            f.z = fmaxf(fmaf(f.z, s.z, c.z), 0.f);
                            f.w = fmaxf(fmaf(f.w, s.w, c.w), 0.f);
                        }
                        xv[4*i]   = f.x; xv[4*i+1] = f.y;
                        xv[4*i+2] = f.z; xv[4*i+3] = f.w;
                    }
                } else {
#pragma unroll
                    for (int j = 0; j < 16; ++j) {
                        int k = k0 + sk + j;
                        float x = (k < Kterm) ? Arow[k] : 0.f;
                        if (bnS != nullptr && k < Kterm)
                            x = fmaxf(fmaf(x, bnS[k], bnB[k]), 0.f);
                        xv[j] = x;
                    }
                }
                unsigned hp[8], lp[8];
#pragma unroll
                for (int i = 0; i < 8; ++i) {
                    unsigned short h0 = bfh(xv[2*i]),   h1 = bfh(xv[2*i+1]);
                    unsigned short l0 = bfh(xv[2*i]   - bf2f(h0));
                    unsigned short l1 = bfh(xv[2*i+1] - bf2f(h1));
                    hp[i] = (unsigned)h0 | ((unsigned)h1 << 16);
                    lp[i] = (unsigned)l0 | ((unsigned)l1 << 16);
                }
                uint4* dh = (uint4*)&Ah[sr * SSTR + sk];
                uint4* dl = (uint4*)&Al[sr * SSTR + sk];
                dh[0] = make_uint4(hp[0], hp[1], hp[2], hp[3]);
                dh[1] = make_uint4(hp[4], hp[5], hp[6], hp[7]);
                dl[0] = make_uint4(lp[0], lp[1], lp[2], lp[3]);
                dl[1] = make_uint4(lp[4], lp[5], lp[6], lp[7]);
            }
            // ---- stage B: hi/lo bf16 copies (pre-padded to Kp) ----
            {
                uint4* dh = (uint4*)&Bh[sr * SSTR + sk];
                uint4* dl = (uint4*)&Bl[sr * SSTR + sk];
                dh[0] = *(const uint4*)(BrowH + k0 + sk);
                dh[1] = *(const uint4*)(BrowH + k0 + sk + 8);
                dl[0] = *(const uint4*)(BrowL + k0 + sk);
                dl[1] = *(const uint4*)(BrowL + k0 + sk + 8);
            }
            __syncthreads();
            // ---- compute: 16 tile-pairs x 3 MFMAs ----
            bf16x8 ah[4], al[4], bh[4], bl[4];
#pragma unroll
            for (int t = 0; t < 4; ++t) {
                const int ra = (wm + (t << 4) + lidx) * SSTR + kb;
                ah[t] = *(const bf16x8*)&Ah[ra];
                al[t] = *(const bf16x8*)&Al[ra];
            }
#pragma unroll
            for (int t = 0; t < 4; ++t) {
                const int rb = (wn + (t << 4) + lidx) * SSTR + kb;
                bh[t] = *(const bf16x8*)&Bh[rb];
                bl[t] = *(const bf16x8*)&Bl[rb];
            }
#pragma unroll
            for (int mt = 0; mt < 4; ++mt)
#pragma unroll
                for (int nt = 0; nt < 4; ++nt) {
                    acc[mt][nt] = __builtin_amdgcn_mfma_f32_16x16x32_bf16(
                        ah[mt], bh[nt], acc[mt][nt], 0, 0, 0);
                    acc[mt][nt] = __builtin_amdgcn_mfma_f32_16x16x32_bf16(
                        al[mt], bh[nt], acc[mt][nt], 0, 0, 0);
                    acc[mt][nt] = __builtin_amdgcn_mfma_f32_16x16x32_bf16(
                        ah[mt], bl[nt], acc[mt][nt], 0, 0, 0);
                }
        }
    }

    // ---- epilogue: fp32 C + BN stats ----
    const int rbase = lq << 2;
#pragma unroll
    for (int nt = 0; nt < 4; ++nt) {
        const int col = n0 + wn + (nt << 4) + lidx;
        float s = 0.f, q = 0.f;
#pragma unroll
        for (int mt = 0; mt < 4; ++mt) {
#pragma unroll
            for (int r = 0; r < 4; ++r) {
                float x = acc[mt][nt][r];
                s += x; q += x * x;
                const int row = m0 + wm + (mt << 4) + rbase + r;
                Cout[((size_t)z * Mslice + row) * (size_t)N + col] = x;
            }
        }
        if (stats != nullptr) {
            s += __shfl_xor(s, 16, 64); s += __shfl_xor(s, 32, 64);
            q += __shfl_xor(q, 16, 64); q += __shfl_xor(q, 32, 64);
            if (lq == 0) {
                atomicAdd(&colsum[wn + (nt << 4) + lidx], s);
                atomicAdd(&colsq [wn + (nt << 4) + lidx], q);
            }
        }
    }
    if (stats != nullptr) {
        __syncthreads();
        if (tid < 128) {
            atomicAdd(&stats[n0 + tid],       colsum[tid]);
            atomicAdd(&stats[512 + n0 + tid], colsq[tid]);
        }
    }
}

// ============================ small kernels ================================
__global__ void k_init(float* __restrict__ zbase, unsigned long long* __restrict__ amin)
{
    int t = blockIdx.x * 256 + threadIdx.x;
    if (t < 6720) zbase[t] = 0.f;
    if (t < 1024) amin[t] = ~0ULL;
}

// fp32 repack to [k][i*512+o] from (O,I,Kc) (also codebook with Kc=1)
__global__ void k_repack(const float* __restrict__ w, float* __restrict__ wt,
                         int Kc, int total)
{
    int idx = blockIdx.x * 256 + threadIdx.x;
    if (idx >= total) return;
    int k = idx >> 18;
    int rem = idx & 262143;
    int i = rem >> 9, o = rem & 511;
    wt[idx] = w[(((o << 9) + i) * Kc + k)];
}

// decoder bf16 repack to [k][o][i]; src (I,O,Kc)
__global__ void k_repack_bf(const float* __restrict__ w, unsigned short* __restrict__ wt,
                            int Kc, int I, int O, int total)
{
    int idx = blockIdx.x * 256 + threadIdx.x;
    if (idx >= total) return;
    int i = idx % I;
    int o = (idx / I) % O;
    int k = idx / (I * O);
    wt[idx] = bfh(w[((size_t)i * O + o) * Kc + k]);
}

// split repack from enc weight (O=512,I=512,Kc) -> hi/lo [k][o][i]
__global__ void k_repack_sp(const float* __restrict__ w,
                            unsigned short* __restrict__ whi,
                            unsigned short* __restrict__ wlo,
                            int Kc, int total)
{
    int idx = blockIdx.x * 256 + threadIdx.x;
    if (idx >= total) return;
    int i = idx & 511;
    int o = (idx >> 9) & 511;
    int k = idx >> 18;
    float v = w[(((o << 9) + i) * Kc) + k];
    unsigned short h = bfh(v);
    whi[idx] = h;
    wlo[idx] = bfh(v - bf2f(h));
}

// split repack weff [term][i(135)][o(512)] -> hi/lo [term][o][ipad(160)]
__global__ void k_repack_sp_weff(const float* __restrict__ weff,
                                 unsigned short* __restrict__ whi,
                                 unsigned short* __restrict__ wlo,
                                 int total)
{
    int idx = blockIdx.x * 256 + threadIdx.x;
    if (idx >= total) return;
    int i = idx % 160;
    int o = (idx / 160) & 511;
    int t = idx / 81920;
    float v = (i < 135) ? weff[((size_t)t * 135 + i) * 512 + o] : 0.f;
    unsigned short h = bfh(v);
    whi[idx] = h;
    wlo[idx] = bfh(v - bf2f(h));
}

__global__ void k_codesq(const float* __restrict__ cb, float* __restrict__ outq)
{
    int c = blockIdx.x; int l = threadIdx.x;
    float s = 0.f;
    for (int i = l; i < 512; i += 64) { float v = cb[c * 512 + i]; s += v * v; }
    for (int off = 32; off; off >>= 1) s += __shfl_down(s, off, 64);
    if (l == 0) outq[c] = s;
}

__global__ void k_bn_fin(const float* __restrict__ stats,
                         const float* __restrict__ g, const float* __restrict__ b,
                         float* __restrict__ sc, float* __restrict__ sh, float inv_n)
{
    int c = blockIdx.x * blockDim.x + threadIdx.x;
    if (c >= 512) return;
    float m = stats[c] * inv_n;
    float v = stats[512 + c] * inv_n - m * m;
    float a = (float)((double)g[c] / sqrt((double)v + 1e-5));
    sc[c] = a;
    sh[c] = b[c] - m * a;
}

__global__ void k_vq_gather(const unsigned long long* __restrict__ amin,
                            const float* __restrict__ codebook,
                            const float* __restrict__ e3pre,
                            const float* __restrict__ sc, const float* __restrict__ sh,
                            float* __restrict__ quant, float* __restrict__ loss,
                            unsigned int* __restrict__ hist)
{
    int b = blockIdx.x; int t = threadIdx.x;   // 256 threads
    unsigned int idx = (unsigned int)(amin[b] & 0xFFFFFFFFull) & 511u;
    float part = 0.f;
    for (int i = t; i < 512; i += 256) {
        float q = codebook[(size_t)idx * 512 + i];
        quant[(size_t)b * 512 + i] = q;
        float x = e3pre[(size_t)b * 512 + i];
        float f = fmaxf(fmaf(x, sc[i], sh[i]), 0.f);
        float d = q - f;
        part += d * d;
    }
    for (int off = 32; off; off >>= 1) part += __shfl_down(part, off, 64);
    __shared__ float red[4];
    if ((t & 63) == 0) red[t >> 6] = part;
    __syncthreads();
    if (t == 0) {
        atomicAdd(loss, red[0] + red[1] + red[2] + red[3]);
        atomicAdd(&hist[idx], 1u);
    }
}

__global__ void k_scalars(const unsigned int* __restrict__ hist,
                          const float* __restrict__ loss, float* __restrict__ out)
{
    int t = threadIdx.x;   // 512
    float p = (float)hist[t] * (1.0f / 1024.0f);
    float e = p * logf(p + 1e-10f);
    for (int off = 32; off; off >>= 1) e += __shfl_down(e, off, 64);
    __shared__ float red[8];
    if ((t & 63) == 0) red[t >> 6] = e;
    __syncthreads();
    if (t == 0) {
        float s = 0.f;
        for (int i = 0; i < 8; ++i) s += red[i];
        out[4147200] = 1.25f * loss[0] * (1.0f / 524288.0f);
        out[4147201] = expf(-s);
    }
}

extern "C" void kernel_launch(void* const* d_in, const int* in_sizes, int n_in,
                              void* d_out, int out_size, void* d_ws, size_t ws_size,
                              hipStream_t stream)
{
    const float* in_seqs = (const float*)d_in[0];
    const float* W_in  = (const float*)d_in[1];
    // d_in[2] = b_in: dropped (BN shift-invariance)
    const float* w_e1  = (const float*)d_in[3];
    const float* g_e1  = (const float*)d_in[4];
    const float* be1   = (const float*)d_in[5];
    const float* w_e2  = (const float*)d_in[6];
    const float* g_e2  = (const float*)d_in[7];
    const float* be2   = (const float*)d_in[8];
    const float* w_e3  = (const float*)d_in[9];
    const float* g_e3  = (const float*)d_in[10];
    const float* be3   = (const float*)d_in[11];
    const float* codebook = (const float*)d_in[12];
    const float* W_q   = (const float*)d_in[13];
    const float* b_q   = (const float*)d_in[14];
    const float* w_d1  = (const float*)d_in[15];
    const float* g_d1  = (const float*)d_in[16];
    const float* bd1   = (const float*)d_in[17];
    const float* w_d2  = (const float*)d_in[18];
    const float* g_d2  = (const float*)d_in[19];
    const float* bd2   = (const float*)d_in[20];
    const float* w_d3  = (const float*)d_in[21];
    const float* g_d3  = (const float*)d_in[22];
    const float* bd3   = (const float*)d_in[23];
    const float* W_out = (const float*)d_in[24];
    const float* b_out = (const float*)d_in[25];
    float* out = (float*)d_out;

    // ---- workspace layout (floats) ----
    float* W = (float*)d_ws;
    unsigned long long* amin = (unsigned long long*)W;     // 2048 f
    float* stats  = W + 2048;                              // 6144
    float* lossp  = W + 8192;                              // 64
    unsigned int* hist = (unsigned int*)(W + 8256);        // 512
    float* scsh   = W + 8768;                              // 6144
    float* codesq = W + 14912;                             // 512
    float* wt_e1  = W + 15424;                             // 5*262144 fp32
    float* weff   = wt_e1 + 5 * 262144;                    // 345600 fp32
    float* codeT  = weff + 345600;                         // 262144 fp32
    const size_t SLICE = 1024u * 512u;
    float* e1    = codeT + 262144;                         // 6 slices (reused d2)
    float* e2    = e1 + 6 * SLICE;                         // 2 slices (reused d1)
    float* e3    = e2 + 2 * SLICE;
    float* quant = e3 + SLICE;
    float* d0v   = quant + SLICE;
    float* d3v   = d0v + SLICE;                            // 30 slices

    // split-encoder weights overlay d3v (dead until decoder d3 runs)
    unsigned short* sp = (unsigned short*)d3v;
    unsigned short* whi_e1 = sp;                 // 5*512*160 = 409600
    unsigned short* wlo_e1 = sp + 409600;
    unsigned short* whi_e2 = sp + 819200;        // 3*512*512 = 786432
    unsigned short* wlo_e2 = sp + 1605632;
    unsigned short* whi_e3 = sp + 2392064;       // 2*512*512 = 524288
    unsigned short* wlo_e3 = sp + 2916352;       // ends 3440640 sh = 1720320 f

    // decoder bf16 weights overlay wt_e1+weff (dead after weff split-repack)
    unsigned short* db   = (unsigned short*)wt_e1;
    unsigned short* wqb   = db;                  // 262144
    unsigned short* wd1b  = db + 262144;         // 524288
    unsigned short* wd2b  = db + 786432;         // 786432
    unsigned short* wd3b  = db + 1572864;        // 1310720
    unsigned short* woutb = db + 2883584;        // 69120 -> ends 2952704 sh

    float* st_e1 = stats + 0 * 1024; float* sc_e1 = scsh + 0 * 1024; float* sh_e1 = sc_e1 + 512;
    float* st_e2 = stats + 1 * 1024; float* sc_e2 = scsh + 1 * 1024; float* sh_e2 = sc_e2 + 512;
    float* st_e3 = stats + 2 * 1024; float* sc_e3 = scsh + 2 * 1024; float* sh_e3 = sc_e3 + 512;
    float* st_d1 = stats + 3 * 1024; float* sc_d1 = scsh + 3 * 1024; float* sh_d1 = sc_d1 + 512;
    float* st_d2 = stats + 4 * 1024; float* sc_d2 = scsh + 4 * 1024; float* sh_d2 = sc_d2 + 512;
    float* st_d3 = stats + 5 * 1024; float* sc_d3 = scsh + 5 * 1024; float* sh_d3 = sc_d3 + 512;

    float* d1v = e2;
    float* d2v = e1;

    dim3 blk(256);
    k_init<<<dim3(32), blk, 0, stream>>>(stats, amin);

    // fp32 repacks: wt_e1 (for weff), codebook
    k_repack<<<dim3(5 * 1024), blk, 0, stream>>>(w_e1, wt_e1, 5, 5 * 262144);
    k_repack<<<dim3(1024),     blk, 0, stream>>>(codebook, codeT, 1, 262144);
    k_codesq<<<dim3(512), dim3(64), 0, stream>>>(codebook, codesq);

    // weff[k] = W_in (135x512) @ wt_e1[k]  (fp32, dec-mode indexing)
    k_gemm<<<dim3(8, 3, 5), blk, 0, stream>>>(W_in, wt_e1, weff, nullptr,
        nullptr, nullptr, nullptr, nullptr, nullptr, nullptr, 135, 512, 512, 1, 0, 5);

    // split repacks (into d3v overlay)
    k_repack_sp_weff<<<dim3(1600), blk, 0, stream>>>(weff, whi_e1, wlo_e1, 409600);
    k_repack_sp<<<dim3(3 * 1024), blk, 0, stream>>>(w_e2, whi_e2, wlo_e2, 3, 3 * 262144);
    k_repack_sp<<<dim3(2 * 1024), blk, 0, stream>>>(w_e3, whi_e3, wlo_e3, 2, 2 * 262144);

    // decoder bf16 repacks (overlay wt_e1+weff, both now dead)
    k_repack_bf<<<dim3(1024),     blk, 0, stream>>>(W_q,   wqb,   1, 512, 512, 262144);
    k_repack_bf<<<dim3(2 * 1024), blk, 0, stream>>>(w_d1,  wd1b,  2, 512, 512, 524288);
    k_repack_bf<<<dim3(3 * 1024), blk, 0, stream>>>(w_d2,  wd2b,  3, 512, 512, 786432);
    k_repack_bf<<<dim3(5 * 1024), blk, 0, stream>>>(w_d3,  wd3b,  5, 512, 512, 1310720);
    k_repack_bf<<<dim3(270),      blk, 0, stream>>>(W_out, woutb, 1, 512, 135, 69120);

    // ---- encoder: split-bf16 MFMA ----
    k_mfma_sp<<<dim3(4, 8, 6), blk, 0, stream>>>(in_seqs, whi_e1, wlo_e1, e1,
        nullptr, nullptr, st_e1, 1024, 135, 160, 512, 5);
    k_bn_fin<<<dim3(2), blk, 0, stream>>>(st_e1, g_e1, be1, sc_e1, sh_e1, 1.f / 6144.f);

    k_mfma_sp<<<dim3(4, 8, 2), blk, 0, stream>>>(e1, whi_e2, wlo_e2, e2,
        sc_e1, sh_e1, st_e2, 1024, 512, 512, 512, 3);
    k_bn_fin<<<dim3(2), blk, 0, stream>>>(st_e2, g_e2, be2, sc_e2, sh_e2, 1.f / 2048.f);

    k_mfma_sp<<<dim3(4, 8, 1), blk, 0, stream>>>(e2, whi_e3, wlo_e3, e3,
        sc_e2, sh_e2, st_e3, 1024, 512, 512, 512, 2);
    k_bn_fin<<<dim3(2), blk, 0, stream>>>(st_e3, g_e3, be3, sc_e3, sh_e3, 1.f / 1024.f);

    // ---- VQ: fp32 dist GEMM + argmin (bit-identical to rounds 3/4) ----
    k_gemm<<<dim3(8, 16, 1), blk, 0, stream>>>(e3, codeT, nullptr, nullptr,
        sc_e3, sh_e3, nullptr, amin, codesq, nullptr, 1024, 512, 512, 1, 1, 1);
    k_vq_gather<<<dim3(1024), blk, 0, stream>>>(amin, codebook, e3, sc_e3, sh_e3,
                                                quant, lossp, hist);

    // ---- decoder: single-bf16 MFMA (unchanged) ----
    k_mfma<<<dim3(4, 8, 1), blk, 0, stream>>>(quant, wqb, d0v, b_q,
        nullptr, nullptr, nullptr, nullptr, 1024, 512, 512, 1);

    k_mfma<<<dim3(4, 8, 2), blk, 0, stream>>>(d0v, wd1b, d1v, nullptr,
        nullptr, nullptr, st_d1, nullptr, 1024, 512, 512, 2);
    k_bn_fin<<<dim3(2), blk, 0, stream>>>(st_d1, g_d1, bd1, sc_d1, sh_d1, 1.f / 2048.f);

    k_mfma<<<dim3(4, 8, 6), blk, 0, stream>>>(d1v, wd2b, d2v, nullptr,
        sc_d1, sh_d1, st_d2, nullptr, 1024, 512, 512, 3);
    k_bn_fin<<<dim3(2), blk, 0, stream>>>(st_d2, g_d2, bd2, sc_d2, sh_d2, 1.f / 6144.f);

    k_mfma<<<dim3(4, 8, 30), blk, 0, stream>>>(d2v, wd3b, d3v, nullptr,
        sc_d2, sh_d2, st_d3, nullptr, 1024, 512, 512, 5);
    k_bn_fin<<<dim3(2), blk, 0, stream>>>(st_d3, g_d3, bd3, sc_d3, sh_d3, 1.f / 30720.f);

    // recon = bnrelu(d3) @ W_out + b_out, (b,t,p)-permuted write
    k_mfma<<<dim3(2, 240, 1), blk, 0, stream>>>(d3v, woutb, nullptr, b_out,
        sc_d3, sh_d3, nullptr, out, 30720, 512, 135, 1);

    k_scalars<<<dim3(1), dim3(512), 0, stream>>>(hist, lossp, out);
}

// Round 6
// 614.384 us; speedup vs baseline: 1.6657x; 1.2179x over previous
//
#include <hip/hip_runtime.h>
#include <math.h>

// ---------------------------------------------------------------------------
// VQ-VAE forward (round 6).
//  - All per-element BN/ReLU/bf16-split conversion moved OUT of GEMM hot
//    loops into memory-bound passes; GEMM staging is pure uint4 copy.
//  - Decoder activations stored bf16 (halved traffic); encoder activations
//    stored as post-BN hi/lo bf16 planes (split-bf16 accuracy preserved,
//    so VQ argmin math is identical to round 5's).
//  - VQ dist GEMM + argmin stays pure fp32 (unchanged since round 3).
// ---------------------------------------------------------------------------

#define TM 64
#define TN 64
#define BK 32
#define LSTR 68

typedef __attribute__((ext_vector_type(8))) short bf16x8;
typedef __attribute__((ext_vector_type(4))) float f32x4;

__device__ __forceinline__ unsigned pk_bf16(float a, float b) {
    unsigned ua = __float_as_uint(a), ub = __float_as_uint(b);
    ua += 0x7fffu + ((ua >> 16) & 1u);          // RNE
    ub += 0x7fffu + ((ub >> 16) & 1u);
    return (ua >> 16) | (ub & 0xffff0000u);
}
__device__ __forceinline__ unsigned short bfh(float x) {
    unsigned u = __float_as_uint(x);
    u += 0x7fffu + ((u >> 16) & 1u);
    return (unsigned short)(u >> 16);
}
__device__ __forceinline__ float bf2f(unsigned short h) {
    return __uint_as_float(((unsigned)h) << 16);
}

// ======================= fp32 GEMM (weff + VQ dist) ========================
__global__ __launch_bounds__(256)
void k_gemm(const float* __restrict__ Abase,
            const float* __restrict__ Wt,
            float* __restrict__ Cout,
            const float* __restrict__ bias,
            const float* __restrict__ bnS, const float* __restrict__ bnB,
            float* __restrict__ stats,
            unsigned long long* __restrict__ amin,
            const float* __restrict__ codesq,
            int Mslice, int K, int N,
            int n_terms, int enc_mode, int decK)
{
    __shared__ __align__(16) float As[BK][LSTR];
    __shared__ __align__(16) float Bs[BK][LSTR];
    __shared__ float colsum[TN];
    __shared__ float colsq[TN];

    const int tid = threadIdx.x;
    const int z  = blockIdx.z;
    const int n0 = blockIdx.x * TN;
    const int m0 = blockIdx.y * TM;
    const int ty = tid >> 4;
    const int tx = tid & 15;

    if (stats != nullptr && tid < TN) { colsum[tid] = 0.f; colsq[tid] = 0.f; }

    float acc[4][4];
#pragma unroll
    for (int i = 0; i < 4; ++i)
#pragma unroll
        for (int j = 0; j < 4; ++j) acc[i][j] = 0.f;

    const int arow = tid >> 2;
    const int ac4  = (tid & 3) << 2;
    const int brow = tid >> 3;
    const int bc4  = (tid & 7) << 2;

    int mrow = m0 + arow;
    if (mrow > Mslice - 1) mrow = Mslice - 1;

    const bool alignedK = ((K & 31) == 0);

    for (int term = 0; term < n_terms; ++term) {
        int a_slice, wk;
        if (enc_mode) { a_slice = z * n_terms + term; wk = term; }
        else          { a_slice = z / decK;           wk = z % decK; }
        const float* Ap = Abase + (size_t)a_slice * (size_t)Mslice * (size_t)K;
        const float* Wp = Wt    + (size_t)wk * (size_t)K * (size_t)N;
        const float* Arow_p = Ap + (size_t)mrow * (size_t)K;

        for (int k0 = 0; k0 < K; k0 += BK) {
            __syncthreads();
            if (alignedK) {
                float4 a0 = *(const float4*)(Arow_p + k0 + ac4);
                float4 a1 = *(const float4*)(Arow_p + k0 + ac4 + 16);
                if (bnS != nullptr) {
                    float4 s0 = *(const float4*)(bnS + k0 + ac4);
                    float4 c0 = *(const float4*)(bnB + k0 + ac4);
                    float4 s1 = *(const float4*)(bnS + k0 + ac4 + 16);
                    float4 c1 = *(const float4*)(bnB + k0 + ac4 + 16);
                    a0.x = fmaxf(fmaf(a0.x, s0.x, c0.x), 0.f);
                    a0.y = fmaxf(fmaf(a0.y, s0.y, c0.y), 0.f);
                    a0.z = fmaxf(fmaf(a0.z, s0.z, c0.z), 0.f);
                    a0.w = fmaxf(fmaf(a0.w, s0.w, c0.w), 0.f);
                    a1.x = fmaxf(fmaf(a1.x, s1.x, c1.x), 0.f);
                    a1.y = fmaxf(fmaf(a1.y, s1.y, c1.y), 0.f);
                    a1.z = fmaxf(fmaf(a1.z, s1.z, c1.z), 0.f);
                    a1.w = fmaxf(fmaf(a1.w, s1.w, c1.w), 0.f);
                }
                As[ac4+0][arow] = a0.x;  As[ac4+1][arow] = a0.y;
                As[ac4+2][arow] = a0.z;  As[ac4+3][arow] = a0.w;
                As[ac4+16][arow] = a1.x; As[ac4+17][arow] = a1.y;
                As[ac4+18][arow] = a1.z; As[ac4+19][arow] = a1.w;
            } else {
#pragma unroll
                for (int j = 0; j < 4; ++j) {
                    int k = k0 + ac4 + j;
                    As[ac4+j][arow] = (k < K) ? Arow_p[k] : 0.f;
                    int k2 = k + 16;
                    As[ac4+16+j][arow] = (k2 < K) ? Arow_p[k2] : 0.f;
                }
            }
            {
                int kB = k0 + brow;
                float4 b0 = make_float4(0.f, 0.f, 0.f, 0.f);
                float4 b1 = make_float4(0.f, 0.f, 0.f, 0.f);
                if (kB < K) {
                    const float* wrow = Wp + (size_t)kB * N + n0;
                    b0 = *(const float4*)(wrow + bc4);
                    b1 = *(const float4*)(wrow + bc4 + 32);
                }
                *(float4*)&Bs[brow][bc4]      = b0;
                *(float4*)&Bs[brow][bc4 + 32] = b1;
            }
            __syncthreads();
#pragma unroll
            for (int kk = 0; kk < BK; ++kk) {
                float4 av = *(const float4*)&As[kk][ty << 2];
                float4 bv = *(const float4*)&Bs[kk][tx << 2];
                acc[0][0] = fmaf(av.x, bv.x, acc[0][0]);
                acc[0][1] = fmaf(av.x, bv.y, acc[0][1]);
                acc[0][2] = fmaf(av.x, bv.z, acc[0][2]);
                acc[0][3] = fmaf(av.x, bv.w, acc[0][3]);
                acc[1][0] = fmaf(av.y, bv.x, acc[1][0]);
                acc[1][1] = fmaf(av.y, bv.y, acc[1][1]);
                acc[1][2] = fmaf(av.y, bv.z, acc[1][2]);
                acc[1][3] = fmaf(av.y, bv.w, acc[1][3]);
                acc[2][0] = fmaf(av.z, bv.x, acc[2][0]);
                acc[2][1] = fmaf(av.z, bv.y, acc[2][1]);
                acc[2][2] = fmaf(av.z, bv.z, acc[2][2]);
                acc[2][3] = fmaf(av.z, bv.w, acc[2][3]);
                acc[3][0] = fmaf(av.w, bv.x, acc[3][0]);
                acc[3][1] = fmaf(av.w, bv.y, acc[3][1]);
                acc[3][2] = fmaf(av.w, bv.z, acc[3][2]);
                acc[3][3] = fmaf(av.w, bv.w, acc[3][3]);
            }
        }
    }

    if (amin != nullptr) {
        float4 cq = *(const float4*)(codesq + n0 + (tx << 2));
#pragma unroll
        for (int i = 0; i < 4; ++i) {
            int m = m0 + (ty << 2) + i;
            if (m >= Mslice) continue;
            float d0 = cq.x - 2.f * acc[i][0];
            float d1 = cq.y - 2.f * acc[i][1];
            float d2 = cq.z - 2.f * acc[i][2];
            float d3 = cq.w - 2.f * acc[i][3];
            float best = d0; int bj = 0;
            if (d1 < best) { best = d1; bj = 1; }
            if (d2 < best) { best = d2; bj = 2; }
            if (d3 < best) { best = d3; bj = 3; }
            unsigned u = __float_as_uint(best);
            u = (u & 0x80000000u) ? ~u : (u | 0x80000000u);
            unsigned long long key =
                ((unsigned long long)u << 32) | (unsigned)(n0 + (tx << 2) + bj);
            atomicMin(&amin[m], key);
        }
        return;
    }

#pragma unroll
    for (int i = 0; i < 4; ++i) {
        int m = m0 + (ty << 2) + i;
        if (m >= Mslice) continue;
        float4 v = make_float4(acc[i][0], acc[i][1], acc[i][2], acc[i][3]);
        if (bias != nullptr) {
            float4 bb = *(const float4*)(bias + n0 + (tx << 2));
            v.x += bb.x; v.y += bb.y; v.z += bb.z; v.w += bb.w;
        }
        *(float4*)&Cout[((size_t)z * Mslice + m) * N + n0 + (tx << 2)] = v;
    }

    if (stats != nullptr) {
#pragma unroll
        for (int j = 0; j < 4; ++j) {
            float s = 0.f, q = 0.f;
#pragma unroll
            for (int i = 0; i < 4; ++i) {
                int m = m0 + (ty << 2) + i;
                if (m < Mslice) { float x = acc[i][j]; s += x; q += x * x; }
            }
            atomicAdd(&colsum[(tx << 2) + j], s);
            atomicAdd(&colsq [(tx << 2) + j], q);
        }
        __syncthreads();
        if (tid < TN) {
            atomicAdd(&stats[n0 + tid],       colsum[tid]);
            atomicAdd(&stats[512 + n0 + tid], colsq[tid]);
        }
    }
}

// =================== bf16 MFMA GEMM (decoder, copy staging) ================
// A is bf16 (post-BN ready, or raw with optional BN folded at staging).
// Block 128x128, 4 waves of 64x64, mfma 16x16x32, K chunk 64.
#define ASTR 72

__global__ __launch_bounds__(256)
void k_mfma_b(const unsigned short* __restrict__ Abase,
              const unsigned short* __restrict__ Bt,
              unsigned short* __restrict__ Cb,
              float* __restrict__ operm,
              const float* __restrict__ bias,
              const float* __restrict__ bnS, const float* __restrict__ bnB,
              float* __restrict__ stats,
              int Mslice, int K, int N, int decK)
{
    __shared__ __align__(16) unsigned short As[128 * ASTR];
    __shared__ __align__(16) unsigned short Bs[128 * ASTR];
    __shared__ float colsum[128], colsq[128];

    const int tid  = threadIdx.x;
    const int lane = tid & 63;
    const int wave = tid >> 6;
    const int wm = (wave >> 1) << 6;
    const int wn = (wave & 1) << 6;
    const int z  = blockIdx.z;
    const int n0 = blockIdx.x << 7;
    const int m0 = blockIdx.y << 7;

    if (stats != nullptr && tid < 128) { colsum[tid] = 0.f; colsq[tid] = 0.f; }

    const int a_slice = z / decK, wk = z - a_slice * decK;
    const unsigned short* Ap = Abase + (size_t)a_slice * (size_t)Mslice * (size_t)K;
    const unsigned short* Bp = Bt + (size_t)wk * (size_t)N * (size_t)K;

    const int sr = tid >> 1;           // 0..127
    const int sk = (tid & 1) << 5;     // 0 or 32 elems

    const unsigned short* Arow = Ap + (size_t)(m0 + sr) * K + sk;
    const unsigned short* Brow = Bp + (size_t)(n0 + sr) * K + sk;
    const bool bvalid = (n0 + sr) < N;

    f32x4 acc[4][4];
#pragma unroll
    for (int i = 0; i < 4; ++i)
#pragma unroll
        for (int j = 0; j < 4; ++j) acc[i][j] = (f32x4){0.f, 0.f, 0.f, 0.f};

    const int lidx = lane & 15;
    const int lq   = lane >> 4;

    for (int k0 = 0; k0 < K; k0 += 64) {
        __syncthreads();
        // ---- stage A: pure copy (32 bf16/thread), optional BN on bf16 ----
        {
            uint4 raw[4];
#pragma unroll
            for (int i = 0; i < 4; ++i)
                raw[i] = *(const uint4*)(Arow + k0 + (i << 3));
            if (bnS != nullptr) {
#pragma unroll
                for (int i = 0; i < 4; ++i) {
                    unsigned* u4 = (unsigned*)&raw[i];
#pragma unroll
                    for (int j = 0; j < 4; ++j) {
                        const int k = k0 + sk + (i << 3) + (j << 1);
                        unsigned u = u4[j];
                        float x0 = __uint_as_float(u << 16);
                        float x1 = __uint_as_float(u & 0xffff0000u);
                        x0 = fmaxf(fmaf(x0, bnS[k],     bnB[k]),     0.f);
                        x1 = fmaxf(fmaf(x1, bnS[k + 1], bnB[k + 1]), 0.f);
                        u4[j] = pk_bf16(x0, x1);
                    }
                }
            }
            uint4* dst = (uint4*)&As[sr * ASTR + sk];
#pragma unroll
            for (int i = 0; i < 4; ++i) dst[i] = raw[i];
        }
        // ---- stage B: pure copy ----
        {
            uint4* dst = (uint4*)&Bs[sr * ASTR + sk];
            if (bvalid) {
#pragma unroll
                for (int i = 0; i < 4; ++i)
                    dst[i] = *(const uint4*)(Brow + k0 + (i << 3));
            } else {
#pragma unroll
                for (int i = 0; i < 4; ++i)
                    dst[i] = make_uint4(0u, 0u, 0u, 0u);
            }
        }
        __syncthreads();
#pragma unroll
        for (int ks = 0; ks < 2; ++ks) {
            const int kb = (ks << 5) + (lq << 3);
            bf16x8 af[4], bfv[4];
#pragma unroll
            for (int t = 0; t < 4; ++t)
                af[t] = *(const bf16x8*)&As[(wm + (t << 4) + lidx) * ASTR + kb];
#pragma unroll
            for (int t = 0; t < 4; ++t)
                bfv[t] = *(const bf16x8*)&Bs[(wn + (t << 4) + lidx) * ASTR + kb];
#pragma unroll
            for (int mt = 0; mt < 4; ++mt)
#pragma unroll
                for (int nt = 0; nt < 4; ++nt)
                    acc[mt][nt] = __builtin_amdgcn_mfma_f32_16x16x32_bf16(
                        af[mt], bfv[nt], acc[mt][nt], 0, 0, 0);
        }
    }

    const int rbase = lq << 2;
#pragma unroll
    for (int nt = 0; nt < 4; ++nt) {
        const int col = n0 + wn + (nt << 4) + lidx;
        const float badd = (bias != nullptr && col < N) ? bias[col] : 0.f;
        float s = 0.f, q = 0.f;
#pragma unroll
        for (int mt = 0; mt < 4; ++mt) {
#pragma unroll
            for (int r = 0; r < 4; ++r) {
                float x = acc[mt][nt][r];
                s += x; q += x * x;
                const int row = m0 + wm + (mt << 4) + rbase + r;
                if (operm != nullptr) {
                    if (col < N) {
                        const int t = row >> 10, b = row & 1023;
                        operm[(size_t)b * 4050 + t * 135 + col] = x + badd;
                    }
                } else {
                    Cb[((size_t)z * Mslice + row) * (size_t)N + col] = bfh(x + badd);
                }
            }
        }
        if (stats != nullptr) {
            s += __shfl_xor(s, 16, 64); s += __shfl_xor(s, 32, 64);
            q += __shfl_xor(q, 16, 64); q += __shfl_xor(q, 32, 64);
            if (lq == 0) {
                atomicAdd(&colsum[wn + (nt << 4) + lidx], s);
                atomicAdd(&colsq [wn + (nt << 4) + lidx], q);
            }
        }
    }
    if (stats != nullptr) {
        __syncthreads();
        if (tid < 128) {
            atomicAdd(&stats[n0 + tid],       colsum[tid]);
            atomicAdd(&stats[512 + n0 + tid], colsq[tid]);
        }
    }
}

// ============ split-bf16 MFMA GEMM (encoder, pre-split copy staging) =======
#define SSTR 40

__global__ __launch_bounds__(256)
void k_mfma_sp2(const unsigned short* __restrict__ Ahg,
                const unsigned short* __restrict__ Alg,
                const unsigned short* __restrict__ Whi,
                const unsigned short* __restrict__ Wlo,
                float* __restrict__ Cout, float* __restrict__ stats,
                int Mslice, int Kp, int N, int n_terms)
{
    __shared__ __align__(16) unsigned short Ah[128 * SSTR];
    __shared__ __align__(16) unsigned short Al[128 * SSTR];
    __shared__ __align__(16) unsigned short Bh[128 * SSTR];
    __shared__ __align__(16) unsigned short Bl[128 * SSTR];
    __shared__ float colsum[128], colsq[128];

    const int tid  = threadIdx.x;
    const int lane = tid & 63;
    const int wave = tid >> 6;
    const int wm = (wave >> 1) << 6;
    const int wn = (wave & 1) << 6;
    const int z  = blockIdx.z;
    const int n0 = blockIdx.x << 7;
    const int m0 = blockIdx.y << 7;

    if (stats != nullptr && tid < 128) { colsum[tid] = 0.f; colsq[tid] = 0.f; }

    const int sr = tid >> 1;           // 0..127
    const int sk = (tid & 1) << 4;     // 0 or 16 elems

    f32x4 acc[4][4];
#pragma unroll
    for (int i = 0; i < 4; ++i)
#pragma unroll
        for (int j = 0; j < 4; ++j) acc[i][j] = (f32x4){0.f, 0.f, 0.f, 0.f};

    const int lidx = lane & 15;
    const int lq   = lane >> 4;
    const int kb   = lq << 3;

    for (int term = 0; term < n_terms; ++term) {
        const size_t abase = ((size_t)(z * n_terms + term) * Mslice + m0 + sr) * Kp + sk;
        const unsigned short* ArH = Ahg + abase;
        const unsigned short* ArL = Alg + abase;
        const size_t bbase = ((size_t)term * N + n0 + sr) * Kp + sk;
        const unsigned short* BrH = Whi + bbase;
        const unsigned short* BrL = Wlo + bbase;

        for (int k0 = 0; k0 < Kp; k0 += 32) {
            __syncthreads();
            {
                uint4* dah = (uint4*)&Ah[sr * SSTR + sk];
                uint4* dal = (uint4*)&Al[sr * SSTR + sk];
                uint4* dbh = (uint4*)&Bh[sr * SSTR + sk];
                uint4* dbl = (uint4*)&Bl[sr * SSTR + sk];
                dah[0] = *(const uint4*)(ArH + k0);
                dah[1] = *(const uint4*)(ArH + k0 + 8);
                dal[0] = *(const uint4*)(ArL + k0);
                dal[1] = *(const uint4*)(ArL + k0 + 8);
                dbh[0] = *(const uint4*)(BrH + k0);
                dbh[1] = *(const uint4*)(BrH + k0 + 8);
                dbl[0] = *(const uint4*)(BrL + k0);
                dbl[1] = *(const uint4*)(BrL + k0 + 8);
            }
            __syncthreads();
            bf16x8 ah[4], al[4], bh[4], bl[4];
#pragma unroll
            for (int t = 0; t < 4; ++t) {
                const int ra = (wm + (t << 4) + lidx) * SSTR + kb;
                ah[t] = *(const bf16x8*)&Ah[ra];
                al[t] = *(const bf16x8*)&Al[ra];
            }
#pragma unroll
            for (int t = 0; t < 4; ++t) {
                const int rb = (wn + (t << 4) + lidx) * SSTR + kb;
                bh[t] = *(const bf16x8*)&Bh[rb];
                bl[t] = *(const bf16x8*)&Bl[rb];
            }
#pragma unroll
            for (int mt = 0; mt < 4; ++mt)
#pragma unroll
                for (int nt = 0; nt < 4; ++nt) {
                    acc[mt][nt] = __builtin_amdgcn_mfma_f32_16x16x32_bf16(
                        ah[mt], bh[nt], acc[mt][nt], 0, 0, 0);
                    acc[mt][nt] = __builtin_amdgcn_mfma_f32_16x16x32_bf16(
                        al[mt], bh[nt], acc[mt][nt], 0, 0, 0);
                    acc[mt][nt] = __builtin_amdgcn_mfma_f32_16x16x32_bf16(
                        ah[mt], bl[nt], acc[mt][nt], 0, 0, 0);
                }
        }
    }

    const int rbase = lq << 2;
#pragma unroll
    for (int nt = 0; nt < 4; ++nt) {
        const int col = n0 + wn + (nt << 4) + lidx;
        float s = 0.f, q = 0.f;
#pragma unroll
        for (int mt = 0; mt < 4; ++mt) {
#pragma unroll
            for (int r = 0; r < 4; ++r) {
                float x = acc[mt][nt][r];
                s += x; q += x * x;
                const int row = m0 + wm + (mt << 4) + rbase + r;
                Cout[((size_t)z * Mslice + row) * (size_t)N + col] = x;
            }
        }
        if (stats != nullptr) {
            s += __shfl_xor(s, 16, 64); s += __shfl_xor(s, 32, 64);
            q += __shfl_xor(q, 16, 64); q += __shfl_xor(q, 32, 64);
            if (lq == 0) {
                atomicAdd(&colsum[wn + (nt << 4) + lidx], s);
                atomicAdd(&colsq [wn + (nt << 4) + lidx], q);
            }
        }
    }
    if (stats != nullptr) {
        __syncthreads();
        if (tid < 128) {
            atomicAdd(&stats[n0 + tid],       colsum[tid]);
            atomicAdd(&stats[512 + n0 + tid], colsq[tid]);
        }
    }
}

// ============================ small kernels ================================
__global__ void k_init(float* __restrict__ zbase, unsigned long long* __restrict__ amin)
{
    int t = blockIdx.x * 256 + threadIdx.x;
    if (t < 6720) zbase[t] = 0.f;
    if (t < 1024) amin[t] = ~0ULL;
}

__global__ void k_repack(const float* __restrict__ w, float* __restrict__ wt,
                         int Kc, int total)
{
    int idx = blockIdx.x * 256 + threadIdx.x;
    if (idx >= total) return;
    int k = idx >> 18;
    int rem = idx & 262143;
    int i = rem >> 9, o = rem & 511;
    wt[idx] = w[(((o << 9) + i) * Kc + k)];
}

__global__ void k_repack_bf(const float* __restrict__ w, unsigned short* __restrict__ wt,
                            int Kc, int I, int O, int total)
{
    int idx = blockIdx.x * 256 + threadIdx.x;
    if (idx >= total) return;
    int i = idx % I;
    int o = (idx / I) % O;
    int k = idx / (I * O);
    wt[idx] = bfh(w[((size_t)i * O + o) * Kc + k]);
}

__global__ void k_repack_sp(const float* __restrict__ w,
                            unsigned short* __restrict__ whi,
                            unsigned short* __restrict__ wlo,
                            int Kc, int total)
{
    int idx = blockIdx.x * 256 + threadIdx.x;
    if (idx >= total) return;
    int i = idx & 511;
    int o = (idx >> 9) & 511;
    int k = idx >> 18;
    float v = w[(((o << 9) + i) * Kc) + k];
    unsigned short h = bfh(v);
    whi[idx] = h;
    wlo[idx] = bfh(v - bf2f(h));
}

__global__ void k_repack_sp_weff(const float* __restrict__ weff,
                                 unsigned short* __restrict__ whi,
                                 unsigned short* __restrict__ wlo,
                                 int total)
{
    int idx = blockIdx.x * 256 + threadIdx.x;
    if (idx >= total) return;
    int i = idx % 160;
    int o = (idx / 160) & 511;
    int t = idx / 81920;
    float v = (i < 135) ? weff[((size_t)t * 135 + i) * 512 + o] : 0.f;
    unsigned short h = bfh(v);
    whi[idx] = h;
    wlo[idx] = bfh(v - bf2f(h));
}

// in_seqs fp32 [30720][135] -> hi/lo bf16 [30720][160] (zero-padded)
__global__ void k_split_in(const float* __restrict__ x,
                           unsigned short* __restrict__ hq,
                           unsigned short* __restrict__ lq_, int total)
{
    int idx = blockIdx.x * 256 + threadIdx.x;
    if (idx >= total) return;
    int i = idx % 160;
    int r = idx / 160;
    float v = (i < 135) ? x[(size_t)r * 135 + i] : 0.f;
    unsigned short h = bfh(v);
    hq[idx] = h;
    lq_[idx] = bfh(v - bf2f(h));
}

// fp32 -> post-BN-ReLU hi/lo bf16 (k = idx%512)
__global__ void k_bnsplit(const float* __restrict__ x,
                          const float* __restrict__ sc, const float* __restrict__ sh,
                          unsigned short* __restrict__ hq, unsigned short* __restrict__ lq_,
                          int total4)
{
    int idx = blockIdx.x * 256 + threadIdx.x;
    if (idx >= total4) return;
    const int base = idx << 2;
    float4 f = *(const float4*)(x + base);
    const int k = base & 511;
    float4 s = *(const float4*)(sc + k);
    float4 c = *(const float4*)(sh + k);
    float y0 = fmaxf(fmaf(f.x, s.x, c.x), 0.f);
    float y1 = fmaxf(fmaf(f.y, s.y, c.y), 0.f);
    float y2 = fmaxf(fmaf(f.z, s.z, c.z), 0.f);
    float y3 = fmaxf(fmaf(f.w, s.w, c.w), 0.f);
    unsigned short h0 = bfh(y0), h1 = bfh(y1), h2 = bfh(y2), h3 = bfh(y3);
    unsigned short l0 = bfh(y0 - bf2f(h0)), l1 = bfh(y1 - bf2f(h1));
    unsigned short l2 = bfh(y2 - bf2f(h2)), l3 = bfh(y3 - bf2f(h3));
    *(uint2*)&hq[base]  = make_uint2((unsigned)h0 | ((unsigned)h1 << 16),
                                     (unsigned)h2 | ((unsigned)h3 << 16));
    *(uint2*)&lq_[base] = make_uint2((unsigned)l0 | ((unsigned)l1 << 16),
                                     (unsigned)l2 | ((unsigned)l3 << 16));
}

// bf16 -> post-BN-ReLU bf16 (k = elem%512), 8 elems/thread
__global__ void k_bnapply(const unsigned short* __restrict__ x,
                          const float* __restrict__ sc, const float* __restrict__ sh,
                          unsigned short* __restrict__ y, int total8)
{
    int idx = blockIdx.x * 256 + threadIdx.x;
    if (idx >= total8) return;
    const int base = idx << 3;
    uint4 raw = *(const uint4*)(x + base);
    const int k = base & 511;
    float4 s0 = *(const float4*)(sc + k);
    float4 c0 = *(const float4*)(sh + k);
    float4 s1 = *(const float4*)(sc + k + 4);
    float4 c1 = *(const float4*)(sh + k + 4);
    unsigned* u = (unsigned*)&raw;
    float x0 = __uint_as_float(u[0] << 16),        x1 = __uint_as_float(u[0] & 0xffff0000u);
    float x2 = __uint_as_float(u[1] << 16),        x3 = __uint_as_float(u[1] & 0xffff0000u);
    float x4 = __uint_as_float(u[2] << 16),        x5 = __uint_as_float(u[2] & 0xffff0000u);
    float x6 = __uint_as_float(u[3] << 16),        x7 = __uint_as_float(u[3] & 0xffff0000u);
    x0 = fmaxf(fmaf(x0, s0.x, c0.x), 0.f); x1 = fmaxf(fmaf(x1, s0.y, c0.y), 0.f);
    x2 = fmaxf(fmaf(x2, s0.z, c0.z), 0.f); x3 = fmaxf(fmaf(x3, s0.w, c0.w), 0.f);
    x4 = fmaxf(fmaf(x4, s1.x, c1.x), 0.f); x5 = fmaxf(fmaf(x5, s1.y, c1.y), 0.f);
    x6 = fmaxf(fmaf(x6, s1.z, c1.z), 0.f); x7 = fmaxf(fmaf(x7, s1.w, c1.w), 0.f);
    *(uint4*)&y[base] = make_uint4(pk_bf16(x0, x1), pk_bf16(x2, x3),
                                   pk_bf16(x4, x5), pk_bf16(x6, x7));
}

__global__ void k_codesq(const float* __restrict__ cb, float* __restrict__ outq)
{
    int c = blockIdx.x; int l = threadIdx.x;
    float s = 0.f;
    for (int i = l; i < 512; i += 64) { float v = cb[c * 512 + i]; s += v * v; }
    for (int off = 32; off; off >>= 1) s += __shfl_down(s, off, 64);
    if (l == 0) outq[c] = s;
}

__global__ void k_bn_fin(const float* __restrict__ stats,
                         const float* __restrict__ g, const float* __restrict__ b,
                         float* __restrict__ sc, float* __restrict__ sh, float inv_n)
{
    int c = blockIdx.x * blockDim.x + threadIdx.x;
    if (c >= 512) return;
    float m = stats[c] * inv_n;
    float v = stats[512 + c] * inv_n - m * m;
    float a = (float)((double)g[c] / sqrt((double)v + 1e-5));
    sc[c] = a;
    sh[c] = b[c] - m * a;
}

__global__ void k_vq_gather(const unsigned long long* __restrict__ amin,
                            const float* __restrict__ codebook,
                            const float* __restrict__ e3pre,
                            const float* __restrict__ sc, const float* __restrict__ sh,
                            unsigned short* __restrict__ quant_bf,
                            float* __restrict__ loss,
                            unsigned int* __restrict__ hist)
{
    int b = blockIdx.x; int t = threadIdx.x;   // 256 threads
    unsigned int idx = (unsigned int)(amin[b] & 0xFFFFFFFFull) & 511u;
    float part = 0.f;
    for (int i = t; i < 512; i += 256) {
        float q = codebook[(size_t)idx * 512 + i];
        quant_bf[(size_t)b * 512 + i] = bfh(q);
        float x = e3pre[(size_t)b * 512 + i];
        float f = fmaxf(fmaf(x, sc[i], sh[i]), 0.f);
        float d = q - f;
        part += d * d;
    }
    for (int off = 32; off; off >>= 1) part += __shfl_down(part, off, 64);
    __shared__ float red[4];
    if ((t & 63) == 0) red[t >> 6] = part;
    __syncthreads();
    if (t == 0) {
        atomicAdd(loss, red[0] + red[1] + red[2] + red[3]);
        atomicAdd(&hist[idx], 1u);
    }
}

__global__ void k_scalars(const unsigned int* __restrict__ hist,
                          const float* __restrict__ loss, float* __restrict__ out)
{
    int t = threadIdx.x;   // 512
    float p = (float)hist[t] * (1.0f / 1024.0f);
    float e = p * logf(p + 1e-10f);
    for (int off = 32; off; off >>= 1) e += __shfl_down(e, off, 64);
    __shared__ float red[8];
    if ((t & 63) == 0) red[t >> 6] = e;
    __syncthreads();
    if (t == 0) {
        float s = 0.f;
        for (int i = 0; i < 8; ++i) s += red[i];
        out[4147200] = 1.25f * loss[0] * (1.0f / 524288.0f);
        out[4147201] = expf(-s);
    }
}

extern "C" void kernel_launch(void* const* d_in, const int* in_sizes, int n_in,
                              void* d_out, int out_size, void* d_ws, size_t ws_size,
                              hipStream_t stream)
{
    const float* in_seqs = (const float*)d_in[0];
    const float* W_in  = (const float*)d_in[1];
    const float* w_e1  = (const float*)d_in[3];
    const float* g_e1  = (const float*)d_in[4];
    const float* be1   = (const float*)d_in[5];
    const float* w_e2  = (const float*)d_in[6];
    const float* g_e2  = (const float*)d_in[7];
    const float* be2   = (const float*)d_in[8];
    const float* w_e3  = (const float*)d_in[9];
    const float* g_e3  = (const float*)d_in[10];
    const float* be3   = (const float*)d_in[11];
    const float* codebook = (const float*)d_in[12];
    const float* W_q   = (const float*)d_in[13];
    const float* b_q   = (const float*)d_in[14];
    const float* w_d1  = (const float*)d_in[15];
    const float* g_d1  = (const float*)d_in[16];
    const float* bd1   = (const float*)d_in[17];
    const float* w_d2  = (const float*)d_in[18];
    const float* g_d2  = (const float*)d_in[19];
    const float* bd2   = (const float*)d_in[20];
    const float* w_d3  = (const float*)d_in[21];
    const float* g_d3  = (const float*)d_in[22];
    const float* bd3   = (const float*)d_in[23];
    const float* W_out = (const float*)d_in[24];
    const float* b_out = (const float*)d_in[25];
    float* out = (float*)d_out;

    // ---- workspace layout (float offsets) ----
    float* W = (float*)d_ws;
    unsigned long long* amin = (unsigned long long*)W;            // 2048 f
    float* stats  = W + 2048;                                     // 6144
    float* lossp  = W + 8192;                                     // 64
    unsigned int* hist = (unsigned int*)(W + 8256);               // 512
    float* scsh   = W + 8768;                                     // 6144
    float* codesq = W + 14912;                                    // 512
    float* wt_e1  = W + 15424;                                    // 1310720 f
    float* weff   = W + 1326144;                                  // 345600 f
    float* codeT  = W + 1671744;                                  // 262144 f
    // encoder split weights
    unsigned short* esw = (unsigned short*)(W + 1933888);         // 3440640 ush
    unsigned short* whi_e1 = esw;
    unsigned short* wlo_e1 = esw + 409600;
    unsigned short* whi_e2 = esw + 819200;
    unsigned short* wlo_e2 = esw + 1605632;
    unsigned short* whi_e3 = esw + 2392064;
    unsigned short* wlo_e3 = esw + 2916352;
    // R1: in_h/in_l early; d3pre later (7864320 f)
    unsigned short* in_h  = (unsigned short*)(W + 3654208);       // 4915200 ush
    unsigned short* in_l  = in_h + 4915200;
    unsigned short* d3pre = (unsigned short*)(W + 3654208);       // 15728640 ush
    // R2: e1 fp32 + e1 hi/lo (6291456 f)
    float* e1f = W + 11518528;                                    // 3145728 f
    unsigned short* e1h = (unsigned short*)(W + 14664256);        // 3145728 ush
    unsigned short* e1l = e1h + 3145728;
    // R3: e2 fp32 + e2 hi/lo early; d2pre/d2bf later (3145728 f)
    float* e2f = W + 17809984;                                    // 1048576 f
    unsigned short* e2h = (unsigned short*)(W + 18858560);        // 1048576 ush
    unsigned short* e2l = e2h + 1048576;
    unsigned short* d2pre = (unsigned short*)(W + 17809984);      // 3145728 ush
    unsigned short* d2bf  = d2pre + 3145728;                      // 3145728 ush
    // R4: small buffers (1572864 f)
    float* e3f = W + 20955712;                                    // 524288 f
    unsigned short* quant_bf = (unsigned short*)(W + 21480000);   // 524288 ush
    unsigned short* d0bf     = (unsigned short*)(W + 21742144);   // 524288 ush
    unsigned short* d1pre    = (unsigned short*)(W + 22004288);   // 1048576 ush
    // end: 22528576 f = 90.1 MB

    // decoder bf16 weights overlay wt_e1+weff (dead after weff split repack)
    unsigned short* db    = (unsigned short*)wt_e1;
    unsigned short* wqb   = db;
    unsigned short* wd1b  = db + 262144;
    unsigned short* wd2b  = db + 786432;
    unsigned short* wd3b  = db + 1572864;
    unsigned short* woutb = db + 2883584;

    float* st_e1 = stats + 0 * 1024; float* sc_e1 = scsh + 0 * 1024; float* sh_e1 = sc_e1 + 512;
    float* st_e2 = stats + 1 * 1024; float* sc_e2 = scsh + 1 * 1024; float* sh_e2 = sc_e2 + 512;
    float* st_e3 = stats + 2 * 1024; float* sc_e3 = scsh + 2 * 1024; float* sh_e3 = sc_e3 + 512;
    float* st_d1 = stats + 3 * 1024; float* sc_d1 = scsh + 3 * 1024; float* sh_d1 = sc_d1 + 512;
    float* st_d2 = stats + 4 * 1024; float* sc_d2 = scsh + 4 * 1024; float* sh_d2 = sc_d2 + 512;
    float* st_d3 = stats + 5 * 1024; float* sc_d3 = scsh + 5 * 1024; float* sh_d3 = sc_d3 + 512;

    dim3 blk(256);
    k_init<<<dim3(32), blk, 0, stream>>>(stats, amin);

    // repacks
    k_repack<<<dim3(5 * 1024), blk, 0, stream>>>(w_e1, wt_e1, 5, 5 * 262144);
    k_repack<<<dim3(1024),     blk, 0, stream>>>(codebook, codeT, 1, 262144);
    k_codesq<<<dim3(512), dim3(64), 0, stream>>>(codebook, codesq);

    // weff[k] = W_in @ wt_e1[k]  (fp32)
    k_gemm<<<dim3(8, 3, 5), blk, 0, stream>>>(W_in, wt_e1, weff, nullptr,
        nullptr, nullptr, nullptr, nullptr, nullptr, 135, 512, 512, 1, 0, 5);

    k_repack_sp_weff<<<dim3(1600), blk, 0, stream>>>(weff, whi_e1, wlo_e1, 409600);
    k_repack_sp<<<dim3(3 * 1024), blk, 0, stream>>>(w_e2, whi_e2, wlo_e2, 3, 3 * 262144);
    k_repack_sp<<<dim3(2 * 1024), blk, 0, stream>>>(w_e3, whi_e3, wlo_e3, 2, 2 * 262144);

    // decoder bf16 repacks (overlay now-dead wt_e1/weff)
    k_repack_bf<<<dim3(1024),     blk, 0, stream>>>(W_q,   wqb,   1, 512, 512, 262144);
    k_repack_bf<<<dim3(2 * 1024), blk, 0, stream>>>(w_d1,  wd1b,  2, 512, 512, 524288);
    k_repack_bf<<<dim3(3 * 1024), blk, 0, stream>>>(w_d2,  wd2b,  3, 512, 512, 786432);
    k_repack_bf<<<dim3(5 * 1024), blk, 0, stream>>>(w_d3,  wd3b,  5, 512, 512, 1310720);
    k_repack_bf<<<dim3(270),      blk, 0, stream>>>(W_out, woutb, 1, 512, 135, 69120);

    // input pre-split
    k_split_in<<<dim3(19200), blk, 0, stream>>>(in_seqs, in_h, in_l, 4915200);

    // ---- encoder (copy-staged split-bf16 MFMA) ----
    k_mfma_sp2<<<dim3(4, 8, 6), blk, 0, stream>>>(in_h, in_l, whi_e1, wlo_e1,
        e1f, st_e1, 1024, 160, 512, 5);
    k_bn_fin<<<dim3(2), blk, 0, stream>>>(st_e1, g_e1, be1, sc_e1, sh_e1, 1.f / 6144.f);
    k_bnsplit<<<dim3(3072), blk, 0, stream>>>(e1f, sc_e1, sh_e1, e1h, e1l, 786432);

    k_mfma_sp2<<<dim3(4, 8, 2), blk, 0, stream>>>(e1h, e1l, whi_e2, wlo_e2,
        e2f, st_e2, 1024, 512, 512, 3);
    k_bn_fin<<<dim3(2), blk, 0, stream>>>(st_e2, g_e2, be2, sc_e2, sh_e2, 1.f / 2048.f);
    k_bnsplit<<<dim3(1024), blk, 0, stream>>>(e2f, sc_e2, sh_e2, e2h, e2l, 262144);

    k_mfma_sp2<<<dim3(4, 8, 1), blk, 0, stream>>>(e2h, e2l, whi_e3, wlo_e3,
        e3f, st_e3, 1024, 512, 512, 2);
    k_bn_fin<<<dim3(2), blk, 0, stream>>>(st_e3, g_e3, be3, sc_e3, sh_e3, 1.f / 1024.f);

    // ---- VQ: fp32 dist GEMM + argmin (unchanged) ----
    k_gemm<<<dim3(8, 16, 1), blk, 0, stream>>>(e3f, codeT, nullptr, nullptr,
        sc_e3, sh_e3, nullptr, amin, codesq, 1024, 512, 512, 1, 1, 1);
    k_vq_gather<<<dim3(1024), blk, 0, stream>>>(amin, codebook, e3f, sc_e3, sh_e3,
                                                quant_bf, lossp, hist);

    // ---- decoder (copy-staged bf16 MFMA) ----
    // d0 = quant @ W_q + b_q  -> bf16
    k_mfma_b<<<dim3(4, 8, 1), blk, 0, stream>>>(quant_bf, wqb, d0bf, nullptr,
        b_q, nullptr, nullptr, nullptr, 1024, 512, 512, 1);

    // d1pre (pre-BN) -> bf16 + stats
    k_mfma_b<<<dim3(4, 8, 2), blk, 0, stream>>>(d0bf, wd1b, d1pre, nullptr,
        nullptr, nullptr, nullptr, st_d1, 1024, 512, 512, 2);
    k_bn_fin<<<dim3(2), blk, 0, stream>>>(st_d1, g_d1, bd1, sc_d1, sh_d1, 1.f / 2048.f);

    // d2pre: BN(d1) folded at staging (A re-read only 4x)
    k_mfma_b<<<dim3(4, 8, 6), blk, 0, stream>>>(d1pre, wd2b, d2pre, nullptr,
        nullptr, sc_d1, sh_d1, st_d2, 1024, 512, 512, 3);
    k_bn_fin<<<dim3(2), blk, 0, stream>>>(st_d2, g_d2, bd2, sc_d2, sh_d2, 1.f / 6144.f);

    // BN-apply pass for d2 (read 20x by d3 -> convert once)
    k_bnapply<<<dim3(1536), blk, 0, stream>>>(d2pre, sc_d2, sh_d2, d2bf, 393216);

    // d3pre -> bf16 + stats
    k_mfma_b<<<dim3(4, 8, 30), blk, 0, stream>>>(d2bf, wd3b, d3pre, nullptr,
        nullptr, nullptr, nullptr, st_d3, 1024, 512, 512, 5);
    k_bn_fin<<<dim3(2), blk, 0, stream>>>(st_d3, g_d3, bd3, sc_d3, sh_d3, 1.f / 30720.f);

    // recon: BN(d3) folded at staging (A re-read only 2x), permuted fp32 out
    k_mfma_b<<<dim3(2, 240, 1), blk, 0, stream>>>(d3pre, woutb, nullptr, out,
        b_out, sc_d3, sh_d3, nullptr, 30720, 512, 135, 1);

    k_scalars<<<dim3(1), dim3(512), 0, stream>>>(hist, lossp, out);
}

// Round 9
// 525.696 us; speedup vs baseline: 1.9468x; 1.1687x over previous
//
#include <hip/hip_runtime.h>
#include <math.h>

// ---------------------------------------------------------------------------
// VQ-VAE forward (round 9 = round 7 source, third submission; rounds 7 and 8
// both died with broker-side "MI355X container failed twice" — the kernel
// never ran. If this also fails, next round bisects the new kernels.)
//  - Round-6 structure kept (pure-copy GEMM staging, bf16 decoder acts,
//    pre-split encoder acts, fp32 VQ argmin).
//  - 64x64-tile kernels (k_sp64 / k_b64) for the occupancy-starved
//    M=1024 layers (e1,e2,e3,d0,d1,d2): 4x block count, ~20KB LDS.
//    d3 (960 blocks) and out-proj (480) keep the 128x128 kernel.
// ---------------------------------------------------------------------------

#define TM 64
#define TN 64
#define BK 32
#define LSTR 68

typedef __attribute__((ext_vector_type(8))) short bf16x8;
typedef __attribute__((ext_vector_type(4))) float f32x4;

__device__ __forceinline__ unsigned pk_bf16(float a, float b) {
    unsigned ua = __float_as_uint(a), ub = __float_as_uint(b);
    ua += 0x7fffu + ((ua >> 16) & 1u);          // RNE
    ub += 0x7fffu + ((ub >> 16) & 1u);
    return (ua >> 16) | (ub & 0xffff0000u);
}
__device__ __forceinline__ unsigned short bfh(float x) {
    unsigned u = __float_as_uint(x);
    u += 0x7fffu + ((u >> 16) & 1u);
    return (unsigned short)(u >> 16);
}
__device__ __forceinline__ float bf2f(unsigned short h) {
    return __uint_as_float(((unsigned)h) << 16);
}

// ======================= fp32 GEMM (weff + VQ dist) ========================
__global__ __launch_bounds__(256)
void k_gemm(const float* __restrict__ Abase,
            const float* __restrict__ Wt,
            float* __restrict__ Cout,
            const float* __restrict__ bias,
            const float* __restrict__ bnS, const float* __restrict__ bnB,
            float* __restrict__ stats,
            unsigned long long* __restrict__ amin,
            const float* __restrict__ codesq,
            int Mslice, int K, int N,
            int n_terms, int enc_mode, int decK)
{
    __shared__ __align__(16) float As[BK][LSTR];
    __shared__ __align__(16) float Bs[BK][LSTR];
    __shared__ float colsum[TN];
    __shared__ float colsq[TN];

    const int tid = threadIdx.x;
    const int z  = blockIdx.z;
    const int n0 = blockIdx.x * TN;
    const int m0 = blockIdx.y * TM;
    const int ty = tid >> 4;
    const int tx = tid & 15;

    if (stats != nullptr && tid < TN) { colsum[tid] = 0.f; colsq[tid] = 0.f; }

    float acc[4][4];
#pragma unroll
    for (int i = 0; i < 4; ++i)
#pragma unroll
        for (int j = 0; j < 4; ++j) acc[i][j] = 0.f;

    const int arow = tid >> 2;
    const int ac4  = (tid & 3) << 2;
    const int brow = tid >> 3;
    const int bc4  = (tid & 7) << 2;

    int mrow = m0 + arow;
    if (mrow > Mslice - 1) mrow = Mslice - 1;

    const bool alignedK = ((K & 31) == 0);

    for (int term = 0; term < n_terms; ++term) {
        int a_slice, wk;
        if (enc_mode) { a_slice = z * n_terms + term; wk = term; }
        else          { a_slice = z / decK;           wk = z % decK; }
        const float* Ap = Abase + (size_t)a_slice * (size_t)Mslice * (size_t)K;
        const float* Wp = Wt    + (size_t)wk * (size_t)K * (size_t)N;
        const float* Arow_p = Ap + (size_t)mrow * (size_t)K;

        for (int k0 = 0; k0 < K; k0 += BK) {
            __syncthreads();
            if (alignedK) {
                float4 a0 = *(const float4*)(Arow_p + k0 + ac4);
                float4 a1 = *(const float4*)(Arow_p + k0 + ac4 + 16);
                if (bnS != nullptr) {
                    float4 s0 = *(const float4*)(bnS + k0 + ac4);
                    float4 c0 = *(const float4*)(bnB + k0 + ac4);
                    float4 s1 = *(const float4*)(bnS + k0 + ac4 + 16);
                    float4 c1 = *(const float4*)(bnB + k0 + ac4 + 16);
                    a0.x = fmaxf(fmaf(a0.x, s0.x, c0.x), 0.f);
                    a0.y = fmaxf(fmaf(a0.y, s0.y, c0.y), 0.f);
                    a0.z = fmaxf(fmaf(a0.z, s0.z, c0.z), 0.f);
                    a0.w = fmaxf(fmaf(a0.w, s0.w, c0.w), 0.f);
                    a1.x = fmaxf(fmaf(a1.x, s1.x, c1.x), 0.f);
                    a1.y = fmaxf(fmaf(a1.y, s1.y, c1.y), 0.f);
                    a1.z = fmaxf(fmaf(a1.z, s1.z, c1.z), 0.f);
                    a1.w = fmaxf(fmaf(a1.w, s1.w, c1.w), 0.f);
                }
                As[ac4+0][arow] = a0.x;  As[ac4+1][arow] = a0.y;
                As[ac4+2][arow] = a0.z;  As[ac4+3][arow] = a0.w;
                As[ac4+16][arow] = a1.x; As[ac4+17][arow] = a1.y;
                As[ac4+18][arow] = a1.z; As[ac4+19][arow] = a1.w;
            } else {
#pragma unroll
                for (int j = 0; j < 4; ++j) {
                    int k = k0 + ac4 + j;
                    As[ac4+j][arow] = (k < K) ? Arow_p[k] : 0.f;
                    int k2 = k + 16;
                    As[ac4+16+j][arow] = (k2 < K) ? Arow_p[k2] : 0.f;
                }
            }
            {
                int kB = k0 + brow;
                float4 b0 = make_float4(0.f, 0.f, 0.f, 0.f);
                float4 b1 = make_float4(0.f, 0.f, 0.f, 0.f);
                if (kB < K) {
                    const float* wrow = Wp + (size_t)kB * N + n0;
                    b0 = *(const float4*)(wrow + bc4);
                    b1 = *(const float4*)(wrow + bc4 + 32);
                }
                *(float4*)&Bs[brow][bc4]      = b0;
                *(float4*)&Bs[brow][bc4 + 32] = b1;
            }
            __syncthreads();
#pragma unroll
            for (int kk = 0; kk < BK; ++kk) {
                float4 av = *(const float4*)&As[kk][ty << 2];
                float4 bv = *(const float4*)&Bs[kk][tx << 2];
                acc[0][0] = fmaf(av.x, bv.x, acc[0][0]);
                acc[0][1] = fmaf(av.x, bv.y, acc[0][1]);
                acc[0][2] = fmaf(av.x, bv.z, acc[0][2]);
                acc[0][3] = fmaf(av.x, bv.w, acc[0][3]);
                acc[1][0] = fmaf(av.y, bv.x, acc[1][0]);
                acc[1][1] = fmaf(av.y, bv.y, acc[1][1]);
                acc[1][2] = fmaf(av.y, bv.z, acc[1][2]);
                acc[1][3] = fmaf(av.y, bv.w, acc[1][3]);
                acc[2][0] = fmaf(av.z, bv.x, acc[2][0]);
                acc[2][1] = fmaf(av.z, bv.y, acc[2][1]);
                acc[2][2] = fmaf(av.z, bv.z, acc[2][2]);
                acc[2][3] = fmaf(av.z, bv.w, acc[2][3]);
                acc[3][0] = fmaf(av.w, bv.x, acc[3][0]);
                acc[3][1] = fmaf(av.w, bv.y, acc[3][1]);
                acc[3][2] = fmaf(av.w, bv.z, acc[3][2]);
                acc[3][3] = fmaf(av.w, bv.w, acc[3][3]);
            }
        }
    }

    if (amin != nullptr) {
        float4 cq = *(const float4*)(codesq + n0 + (tx << 2));
#pragma unroll
        for (int i = 0; i < 4; ++i) {
            int m = m0 + (ty << 2) + i;
            if (m >= Mslice) continue;
            float d0 = cq.x - 2.f * acc[i][0];
            float d1 = cq.y - 2.f * acc[i][1];
            float d2 = cq.z - 2.f * acc[i][2];
            float d3 = cq.w - 2.f * acc[i][3];
            float best = d0; int bj = 0;
            if (d1 < best) { best = d1; bj = 1; }
            if (d2 < best) { best = d2; bj = 2; }
            if (d3 < best) { best = d3; bj = 3; }
            unsigned u = __float_as_uint(best);
            u = (u & 0x80000000u) ? ~u : (u | 0x80000000u);
            unsigned long long key =
                ((unsigned long long)u << 32) | (unsigned)(n0 + (tx << 2) + bj);
            atomicMin(&amin[m], key);
        }
        return;
    }

#pragma unroll
    for (int i = 0; i < 4; ++i) {
        int m = m0 + (ty << 2) + i;
        if (m >= Mslice) continue;
        float4 v = make_float4(acc[i][0], acc[i][1], acc[i][2], acc[i][3]);
        if (bias != nullptr) {
            float4 bb = *(const float4*)(bias + n0 + (tx << 2));
            v.x += bb.x; v.y += bb.y; v.z += bb.z; v.w += bb.w;
        }
        *(float4*)&Cout[((size_t)z * Mslice + m) * N + n0 + (tx << 2)] = v;
    }

    if (stats != nullptr) {
#pragma unroll
        for (int j = 0; j < 4; ++j) {
            float s = 0.f, q = 0.f;
#pragma unroll
            for (int i = 0; i < 4; ++i) {
                int m = m0 + (ty << 2) + i;
                if (m < Mslice) { float x = acc[i][j]; s += x; q += x * x; }
            }
            atomicAdd(&colsum[(tx << 2) + j], s);
            atomicAdd(&colsq [(tx << 2) + j], q);
        }
        __syncthreads();
        if (tid < TN) {
            atomicAdd(&stats[n0 + tid],       colsum[tid]);
            atomicAdd(&stats[512 + n0 + tid], colsq[tid]);
        }
    }
}

// ============== bf16 MFMA GEMM, 128x128 tile (d3 + out-proj) ===============
#define ASTR 72

__global__ __launch_bounds__(256)
void k_mfma_b(const unsigned short* __restrict__ Abase,
              const unsigned short* __restrict__ Bt,
              unsigned short* __restrict__ Cb,
              float* __restrict__ operm,
              const float* __restrict__ bias,
              const float* __restrict__ bnS, const float* __restrict__ bnB,
              float* __restrict__ stats,
              int Mslice, int K, int N, int decK)
{
    __shared__ __align__(16) unsigned short As[128 * ASTR];
    __shared__ __align__(16) unsigned short Bs[128 * ASTR];
    __shared__ float colsum[128], colsq[128];

    const int tid  = threadIdx.x;
    const int lane = tid & 63;
    const int wave = tid >> 6;
    const int wm = (wave >> 1) << 6;
    const int wn = (wave & 1) << 6;
    const int z  = blockIdx.z;
    const int n0 = blockIdx.x << 7;
    const int m0 = blockIdx.y << 7;

    if (stats != nullptr && tid < 128) { colsum[tid] = 0.f; colsq[tid] = 0.f; }

    const int a_slice = z / decK, wk = z - a_slice * decK;
    const unsigned short* Ap = Abase + (size_t)a_slice * (size_t)Mslice * (size_t)K;
    const unsigned short* Bp = Bt + (size_t)wk * (size_t)N * (size_t)K;

    const int sr = tid >> 1;           // 0..127
    const int sk = (tid & 1) << 5;     // 0 or 32 elems

    const unsigned short* Arow = Ap + (size_t)(m0 + sr) * K + sk;
    const unsigned short* Brow = Bp + (size_t)(n0 + sr) * K + sk;
    const bool bvalid = (n0 + sr) < N;

    f32x4 acc[4][4];
#pragma unroll
    for (int i = 0; i < 4; ++i)
#pragma unroll
        for (int j = 0; j < 4; ++j) acc[i][j] = (f32x4){0.f, 0.f, 0.f, 0.f};

    const int lidx = lane & 15;
    const int lq   = lane >> 4;

    for (int k0 = 0; k0 < K; k0 += 64) {
        __syncthreads();
        {
            uint4 raw[4];
#pragma unroll
            for (int i = 0; i < 4; ++i)
                raw[i] = *(const uint4*)(Arow + k0 + (i << 3));
            if (bnS != nullptr) {
#pragma unroll
                for (int i = 0; i < 4; ++i) {
                    unsigned* u4 = (unsigned*)&raw[i];
#pragma unroll
                    for (int j = 0; j < 4; ++j) {
                        const int k = k0 + sk + (i << 3) + (j << 1);
                        unsigned u = u4[j];
                        float x0 = __uint_as_float(u << 16);
                        float x1 = __uint_as_float(u & 0xffff0000u);
                        x0 = fmaxf(fmaf(x0, bnS[k],     bnB[k]),     0.f);
                        x1 = fmaxf(fmaf(x1, bnS[k + 1], bnB[k + 1]), 0.f);
                        u4[j] = pk_bf16(x0, x1);
                    }
                }
            }
            uint4* dst = (uint4*)&As[sr * ASTR + sk];
#pragma unroll
            for (int i = 0; i < 4; ++i) dst[i] = raw[i];
        }
        {
            uint4* dst = (uint4*)&Bs[sr * ASTR + sk];
            if (bvalid) {
#pragma unroll
                for (int i = 0; i < 4; ++i)
                    dst[i] = *(const uint4*)(Brow + k0 + (i << 3));
            } else {
#pragma unroll
                for (int i = 0; i < 4; ++i)
                    dst[i] = make_uint4(0u, 0u, 0u, 0u);
            }
        }
        __syncthreads();
#pragma unroll
        for (int ks = 0; ks < 2; ++ks) {
            const int kb = (ks << 5) + (lq << 3);
            bf16x8 af[4], bfv[4];
#pragma unroll
            for (int t = 0; t < 4; ++t)
                af[t] = *(const bf16x8*)&As[(wm + (t << 4) + lidx) * ASTR + kb];
#pragma unroll
            for (int t = 0; t < 4; ++t)
                bfv[t] = *(const bf16x8*)&Bs[(wn + (t << 4) + lidx) * ASTR + kb];
#pragma unroll
            for (int mt = 0; mt < 4; ++mt)
#pragma unroll
                for (int nt = 0; nt < 4; ++nt)
                    acc[mt][nt] = __builtin_amdgcn_mfma_f32_16x16x32_bf16(
                        af[mt], bfv[nt], acc[mt][nt], 0, 0, 0);
        }
    }

    const int rbase = lq << 2;
#pragma unroll
    for (int nt = 0; nt < 4; ++nt) {
        const int col = n0 + wn + (nt << 4) + lidx;
        const float badd = (bias != nullptr && col < N) ? bias[col] : 0.f;
        float s = 0.f, q = 0.f;
#pragma unroll
        for (int mt = 0; mt < 4; ++mt) {
#pragma unroll
            for (int r = 0; r < 4; ++r) {
                float x = acc[mt][nt][r];
                s += x; q += x * x;
                const int row = m0 + wm + (mt << 4) + rbase + r;
                if (operm != nullptr) {
                    if (col < N) {
                        const int t = row >> 10, b = row & 1023;
                        operm[(size_t)b * 4050 + t * 135 + col] = x + badd;
                    }
                } else {
                    Cb[((size_t)z * Mslice + row) * (size_t)N + col] = bfh(x + badd);
                }
            }
        }
        if (stats != nullptr) {
            s += __shfl_xor(s, 16, 64); s += __shfl_xor(s, 32, 64);
            q += __shfl_xor(q, 16, 64); q += __shfl_xor(q, 32, 64);
            if (lq == 0) {
                atomicAdd(&colsum[wn + (nt << 4) + lidx], s);
                atomicAdd(&colsq [wn + (nt << 4) + lidx], q);
            }
        }
    }
    if (stats != nullptr) {
        __syncthreads();
        if (tid < 128) {
            atomicAdd(&stats[n0 + tid],       colsum[tid]);
            atomicAdd(&stats[512 + n0 + tid], colsq[tid]);
        }
    }
}

// ============== bf16 MFMA GEMM, 64x64 tile (d0, d1, d2) ====================
#define BSTR 72

__global__ __launch_bounds__(256)
void k_b64(const unsigned short* __restrict__ Abase,
           const unsigned short* __restrict__ Bt,
           unsigned short* __restrict__ Cb,
           const float* __restrict__ bias,
           const float* __restrict__ bnS, const float* __restrict__ bnB,
           float* __restrict__ stats,
           int Mslice, int K, int N, int decK)
{
    __shared__ __align__(16) unsigned short As[64 * BSTR];
    __shared__ __align__(16) unsigned short Bs[64 * BSTR];
    __shared__ float colsum[64], colsq[64];

    const int tid  = threadIdx.x;
    const int lane = tid & 63;
    const int wave = tid >> 6;
    const int wm = (wave >> 1) << 5;
    const int wn = (wave & 1) << 5;
    const int z  = blockIdx.z;
    const int n0 = blockIdx.x << 6;
    const int m0 = blockIdx.y << 6;

    if (stats != nullptr && tid < 64) { colsum[tid] = 0.f; colsq[tid] = 0.f; }

    const int a_slice = z / decK, wk = z - a_slice * decK;
    const unsigned short* Ap = Abase + (size_t)a_slice * (size_t)Mslice * (size_t)K;
    const unsigned short* Bp = Bt + (size_t)wk * (size_t)N * (size_t)K;

    const int sr = tid >> 2;           // 0..63
    const int sk = (tid & 3) << 4;     // 0,16,32,48 elems

    const unsigned short* Arow = Ap + (size_t)(m0 + sr) * K + sk;
    const unsigned short* Brow = Bp + (size_t)(n0 + sr) * K + sk;

    f32x4 acc[2][2];
#pragma unroll
    for (int i = 0; i < 2; ++i)
#pragma unroll
        for (int j = 0; j < 2; ++j) acc[i][j] = (f32x4){0.f, 0.f, 0.f, 0.f};

    const int lidx = lane & 15;
    const int lq   = lane >> 4;

    for (int k0 = 0; k0 < K; k0 += 64) {
        __syncthreads();
        {
            uint4 raw[2];
            raw[0] = *(const uint4*)(Arow + k0);
            raw[1] = *(const uint4*)(Arow + k0 + 8);
            if (bnS != nullptr) {
#pragma unroll
                for (int i = 0; i < 2; ++i) {
                    unsigned* u4 = (unsigned*)&raw[i];
#pragma unroll
                    for (int j = 0; j < 4; ++j) {
                        const int k = k0 + sk + (i << 3) + (j << 1);
                        unsigned u = u4[j];
                        float x0 = __uint_as_float(u << 16);
                        float x1 = __uint_as_float(u & 0xffff0000u);
                        x0 = fmaxf(fmaf(x0, bnS[k],     bnB[k]),     0.f);
                        x1 = fmaxf(fmaf(x1, bnS[k + 1], bnB[k + 1]), 0.f);
                        u4[j] = pk_bf16(x0, x1);
                    }
                }
            }
            uint4* dst = (uint4*)&As[sr * BSTR + sk];
            dst[0] = raw[0]; dst[1] = raw[1];
        }
        {
            uint4* dst = (uint4*)&Bs[sr * BSTR + sk];
            dst[0] = *(const uint4*)(Brow + k0);
            dst[1] = *(const uint4*)(Brow + k0 + 8);
        }
        __syncthreads();
#pragma unroll
        for (int ks = 0; ks < 2; ++ks) {
            const int kb = (ks << 5) + (lq << 3);
            bf16x8 af[2], bfv[2];
#pragma unroll
            for (int t = 0; t < 2; ++t)
                af[t] = *(const bf16x8*)&As[(wm + (t << 4) + lidx) * BSTR + kb];
#pragma unroll
            for (int t = 0; t < 2; ++t)
                bfv[t] = *(const bf16x8*)&Bs[(wn + (t << 4) + lidx) * BSTR + kb];
#pragma unroll
            for (int mt = 0; mt < 2; ++mt)
#pragma unroll
                for (int nt = 0; nt < 2; ++nt)
                    acc[mt][nt] = __builtin_amdgcn_mfma_f32_16x16x32_bf16(
                        af[mt], bfv[nt], acc[mt][nt], 0, 0, 0);
        }
    }

    const int rbase = lq << 2;
#pragma unroll
    for (int nt = 0; nt < 2; ++nt) {
        const int col = n0 + wn + (nt << 4) + lidx;
        const float badd = (bias != nullptr) ? bias[col] : 0.f;
        float s = 0.f, q = 0.f;
#pragma unroll
        for (int mt = 0; mt < 2; ++mt) {
#pragma unroll
            for (int r = 0; r < 4; ++r) {
                float x = acc[mt][nt][r];
                s += x; q += x * x;
                const int row = m0 + wm + (mt << 4) + rbase + r;
                Cb[((size_t)z * Mslice + row) * (size_t)N + col] = bfh(x + badd);
            }
        }
        if (stats != nullptr) {
            s += __shfl_xor(s, 16, 64); s += __shfl_xor(s, 32, 64);
            q += __shfl_xor(q, 16, 64); q += __shfl_xor(q, 32, 64);
            if (lq == 0) {
                atomicAdd(&colsum[wn + (nt << 4) + lidx], s);
                atomicAdd(&colsq [wn + (nt << 4) + lidx], q);
            }
        }
    }
    if (stats != nullptr) {
        __syncthreads();
        if (tid < 64) {
            atomicAdd(&stats[n0 + tid],       colsum[tid]);
            atomicAdd(&stats[512 + n0 + tid], colsq[tid]);
        }
    }
}

// ============ split-bf16 MFMA GEMM, 64x64 tile (encoder convs) =============
#define S64 40

__global__ __launch_bounds__(256)
void k_sp64(const unsigned short* __restrict__ Ahg,
            const unsigned short* __restrict__ Alg,
            const unsigned short* __restrict__ Whi,
            const unsigned short* __restrict__ Wlo,
            float* __restrict__ Cout, float* __restrict__ stats,
            int Mslice, int Kp, int N, int n_terms)
{
    __shared__ __align__(16) unsigned short Ah[64 * S64];
    __shared__ __align__(16) unsigned short Al[64 * S64];
    __shared__ __align__(16) unsigned short Bh[64 * S64];
    __shared__ __align__(16) unsigned short Bl[64 * S64];
    __shared__ float colsum[64], colsq[64];

    const int tid  = threadIdx.x;
    const int lane = tid & 63;
    const int wave = tid >> 6;
    const int wm = (wave >> 1) << 5;
    const int wn = (wave & 1) << 5;
    const int z  = blockIdx.z;
    const int n0 = blockIdx.x << 6;
    const int m0 = blockIdx.y << 6;

    if (stats != nullptr && tid < 64) { colsum[tid] = 0.f; colsq[tid] = 0.f; }

    const int sr = tid >> 2;           // 0..63
    const int sk = (tid & 3) << 3;     // 0,8,16,24 elems

    f32x4 acc[2][2];
#pragma unroll
    for (int i = 0; i < 2; ++i)
#pragma unroll
        for (int j = 0; j < 2; ++j) acc[i][j] = (f32x4){0.f, 0.f, 0.f, 0.f};

    const int lidx = lane & 15;
    const int lq   = lane >> 4;
    const int kb   = lq << 3;

    for (int term = 0; term < n_terms; ++term) {
        const size_t abase = ((size_t)(z * n_terms + term) * Mslice + m0 + sr) * Kp + sk;
        const unsigned short* ArH = Ahg + abase;
        const unsigned short* ArL = Alg + abase;
        const size_t bbase = ((size_t)term * N + n0 + sr) * Kp + sk;
        const unsigned short* BrH = Whi + bbase;
        const unsigned short* BrL = Wlo + bbase;

        for (int k0 = 0; k0 < Kp; k0 += 32) {
            __syncthreads();
            *(uint4*)&Ah[sr * S64 + sk] = *(const uint4*)(ArH + k0);
            *(uint4*)&Al[sr * S64 + sk] = *(const uint4*)(ArL + k0);
            *(uint4*)&Bh[sr * S64 + sk] = *(const uint4*)(BrH + k0);
            *(uint4*)&Bl[sr * S64 + sk] = *(const uint4*)(BrL + k0);
            __syncthreads();
            bf16x8 ah[2], al[2], bh[2], bl[2];
#pragma unroll
            for (int t = 0; t < 2; ++t) {
                const int ra = (wm + (t << 4) + lidx) * S64 + kb;
                ah[t] = *(const bf16x8*)&Ah[ra];
                al[t] = *(const bf16x8*)&Al[ra];
            }
#pragma unroll
            for (int t = 0; t < 2; ++t) {
                const int rb = (wn + (t << 4) + lidx) * S64 + kb;
                bh[t] = *(const bf16x8*)&Bh[rb];
                bl[t] = *(const bf16x8*)&Bl[rb];
            }
#pragma unroll
            for (int mt = 0; mt < 2; ++mt)
#pragma unroll
                for (int nt = 0; nt < 2; ++nt) {
                    acc[mt][nt] = __builtin_amdgcn_mfma_f32_16x16x32_bf16(
                        ah[mt], bh[nt], acc[mt][nt], 0, 0, 0);
                    acc[mt][nt] = __builtin_amdgcn_mfma_f32_16x16x32_bf16(
                        al[mt], bh[nt], acc[mt][nt], 0, 0, 0);
                    acc[mt][nt] = __builtin_amdgcn_mfma_f32_16x16x32_bf16(
                        ah[mt], bl[nt], acc[mt][nt], 0, 0, 0);
                }
        }
    }

    const int rbase = lq << 2;
#pragma unroll
    for (int nt = 0; nt < 2; ++nt) {
        const int col = n0 + wn + (nt << 4) + lidx;
        float s = 0.f, q = 0.f;
#pragma unroll
        for (int mt = 0; mt < 2; ++mt) {
#pragma unroll
            for (int r = 0; r < 4; ++r) {
                float x = acc[mt][nt][r];
                s += x; q += x * x;
                const int row = m0 + wm + (mt << 4) + rbase + r;
                Cout[((size_t)z * Mslice + row) * (size_t)N + col] = x;
            }
        }
        if (stats != nullptr) {
            s += __shfl_xor(s, 16, 64); s += __shfl_xor(s, 32, 64);
            q += __shfl_xor(q, 16, 64); q += __shfl_xor(q, 32, 64);
            if (lq == 0) {
                atomicAdd(&colsum[wn + (nt << 4) + lidx], s);
                atomicAdd(&colsq [wn + (nt << 4) + lidx], q);
            }
        }
    }
    if (stats != nullptr) {
        __syncthreads();
        if (tid < 64) {
            atomicAdd(&stats[n0 + tid],       colsum[tid]);
            atomicAdd(&stats[512 + n0 + tid], colsq[tid]);
        }
    }
}

// ============================ small kernels ================================
__global__ void k_init(float* __restrict__ zbase, unsigned long long* __restrict__ amin)
{
    int t = blockIdx.x * 256 + threadIdx.x;
    if (t < 6720) zbase[t] = 0.f;
    if (t < 1024) amin[t] = ~0ULL;
}

__global__ void k_repack(const float* __restrict__ w, float* __restrict__ wt,
                         int Kc, int total)
{
    int idx = blockIdx.x * 256 + threadIdx.x;
    if (idx >= total) return;
    int k = idx >> 18;
    int rem = idx & 262143;
    int i = rem >> 9, o = rem & 511;
    wt[idx] = w[(((o << 9) + i) * Kc + k)];
}

__global__ void k_repack_bf(const float* __restrict__ w, unsigned short* __restrict__ wt,
                            int Kc, int I, int O, int total)
{
    int idx = blockIdx.x * 256 + threadIdx.x;
    if (idx >= total) return;
    int i = idx % I;
    int o = (idx / I) % O;
    int k = idx / (I * O);
    wt[idx] = bfh(w[((size_t)i * O + o) * Kc + k]);
}

__global__ void k_repack_sp(const float* __restrict__ w,
                            unsigned short* __restrict__ whi,
                            unsigned short* __restrict__ wlo,
                            int Kc, int total)
{
    int idx = blockIdx.x * 256 + threadIdx.x;
    if (idx >= total) return;
    int i = idx & 511;
    int o = (idx >> 9) & 511;
    int k = idx >> 18;
    float v = w[(((o << 9) + i) * Kc) + k];
    unsigned short h = bfh(v);
    whi[idx] = h;
    wlo[idx] = bfh(v - bf2f(h));
}

__global__ void k_repack_sp_weff(const float* __restrict__ weff,
                                 unsigned short* __restrict__ whi,
                                 unsigned short* __restrict__ wlo,
                                 int total)
{
    int idx = blockIdx.x * 256 + threadIdx.x;
    if (idx >= total) return;
    int i = idx % 160;
    int o = (idx / 160) & 511;
    int t = idx / 81920;
    float v = (i < 135) ? weff[((size_t)t * 135 + i) * 512 + o] : 0.f;
    unsigned short h = bfh(v);
    whi[idx] = h;
    wlo[idx] = bfh(v - bf2f(h));
}

__global__ void k_split_in(const float* __restrict__ x,
                           unsigned short* __restrict__ hq,
                           unsigned short* __restrict__ lq_, int total)
{
    int idx = blockIdx.x * 256 + threadIdx.x;
    if (idx >= total) return;
    int i = idx % 160;
    int r = idx / 160;
    float v = (i < 135) ? x[(size_t)r * 135 + i] : 0.f;
    unsigned short h = bfh(v);
    hq[idx] = h;
    lq_[idx] = bfh(v - bf2f(h));
}

__global__ void k_bnsplit(const float* __restrict__ x,
                          const float* __restrict__ sc, const float* __restrict__ sh,
                          unsigned short* __restrict__ hq, unsigned short* __restrict__ lq_,
                          int total4)
{
    int idx = blockIdx.x * 256 + threadIdx.x;
    if (idx >= total4) return;
    const int base = idx << 2;
    float4 f = *(const float4*)(x + base);
    const int k = base & 511;
    float4 s = *(const float4*)(sc + k);
    float4 c = *(const float4*)(sh + k);
    float y0 = fmaxf(fmaf(f.x, s.x, c.x), 0.f);
    float y1 = fmaxf(fmaf(f.y, s.y, c.y), 0.f);
    float y2 = fmaxf(fmaf(f.z, s.z, c.z), 0.f);
    float y3 = fmaxf(fmaf(f.w, s.w, c.w), 0.f);
    unsigned short h0 = bfh(y0), h1 = bfh(y1), h2 = bfh(y2), h3 = bfh(y3);
    unsigned short l0 = bfh(y0 - bf2f(h0)), l1 = bfh(y1 - bf2f(h1));
    unsigned short l2 = bfh(y2 - bf2f(h2)), l3 = bfh(y3 - bf2f(h3));
    *(uint2*)&hq[base]  = make_uint2((unsigned)h0 | ((unsigned)h1 << 16),
                                     (unsigned)h2 | ((unsigned)h3 << 16));
    *(uint2*)&lq_[base] = make_uint2((unsigned)l0 | ((unsigned)l1 << 16),
                                     (unsigned)l2 | ((unsigned)l3 << 16));
}

__global__ void k_bnapply(const unsigned short* __restrict__ x,
                          const float* __restrict__ sc, const float* __restrict__ sh,
                          unsigned short* __restrict__ y, int total8)
{
    int idx = blockIdx.x * 256 + threadIdx.x;
    if (idx >= total8) return;
    const int base = idx << 3;
    uint4 raw = *(const uint4*)(x + base);
    const int k = base & 511;
    float4 s0 = *(const float4*)(sc + k);
    float4 c0 = *(const float4*)(sh + k);
    float4 s1 = *(const float4*)(sc + k + 4);
    float4 c1 = *(const float4*)(sh + k + 4);
    unsigned* u = (unsigned*)&raw;
    float x0 = __uint_as_float(u[0] << 16),        x1 = __uint_as_float(u[0] & 0xffff0000u);
    float x2 = __uint_as_float(u[1] << 16),        x3 = __uint_as_float(u[1] & 0xffff0000u);
    float x4 = __uint_as_float(u[2] << 16),        x5 = __uint_as_float(u[2] & 0xffff0000u);
    float x6 = __uint_as_float(u[3] << 16),        x7 = __uint_as_float(u[3] & 0xffff0000u);
    x0 = fmaxf(fmaf(x0, s0.x, c0.x), 0.f); x1 = fmaxf(fmaf(x1, s0.y, c0.y), 0.f);
    x2 = fmaxf(fmaf(x2, s0.z, c0.z), 0.f); x3 = fmaxf(fmaf(x3, s0.w, c0.w), 0.f);
    x4 = fmaxf(fmaf(x4, s1.x, c1.x), 0.f); x5 = fmaxf(fmaf(x5, s1.y, c1.y), 0.f);
    x6 = fmaxf(fmaf(x6, s1.z, c1.z), 0.f); x7 = fmaxf(fmaf(x7, s1.w, c1.w), 0.f);
    *(uint4*)&y[base] = make_uint4(pk_bf16(x0, x1), pk_bf16(x2, x3),
                                   pk_bf16(x4, x5), pk_bf16(x6, x7));
}

__global__ void k_codesq(const float* __restrict__ cb, float* __restrict__ outq)
{
    int c = blockIdx.x; int l = threadIdx.x;
    float s = 0.f;
    for (int i = l; i < 512; i += 64) { float v = cb[c * 512 + i]; s += v * v; }
    for (int off = 32; off; off >>= 1) s += __shfl_down(s, off, 64);
    if (l == 0) outq[c] = s;
}

__global__ void k_bn_fin(const float* __restrict__ stats,
                         const float* __restrict__ g, const float* __restrict__ b,
                         float* __restrict__ sc, float* __restrict__ sh, float inv_n)
{
    int c = blockIdx.x * blockDim.x + threadIdx.x;
    if (c >= 512) return;
    float m = stats[c] * inv_n;
    float v = stats[512 + c] * inv_n - m * m;
    float a = (float)((double)g[c] / sqrt((double)v + 1e-5));
    sc[c] = a;
    sh[c] = b[c] - m * a;
}

__global__ void k_vq_gather(const unsigned long long* __restrict__ amin,
                            const float* __restrict__ codebook,
                            const float* __restrict__ e3pre,
                            const float* __restrict__ sc, const float* __restrict__ sh,
                            unsigned short* __restrict__ quant_bf,
                            float* __restrict__ loss,
                            unsigned int* __restrict__ hist)
{
    int b = blockIdx.x; int t = threadIdx.x;   // 256 threads
    unsigned int idx = (unsigned int)(amin[b] & 0xFFFFFFFFull) & 511u;
    float part = 0.f;
    for (int i = t; i < 512; i += 256) {
        float q = codebook[(size_t)idx * 512 + i];
        quant_bf[(size_t)b * 512 + i] = bfh(q);
        float x = e3pre[(size_t)b * 512 + i];
        float f = fmaxf(fmaf(x, sc[i], sh[i]), 0.f);
        float d = q - f;
        part += d * d;
    }
    for (int off = 32; off; off >>= 1) part += __shfl_down(part, off, 64);
    __shared__ float red[4];
    if ((t & 63) == 0) red[t >> 6] = part;
    __syncthreads();
    if (t == 0) {
        atomicAdd(loss, red[0] + red[1] + red[2] + red[3]);
        atomicAdd(&hist[idx], 1u);
    }
}

__global__ void k_scalars(const unsigned int* __restrict__ hist,
                          const float* __restrict__ loss, float* __restrict__ out)
{
    int t = threadIdx.x;   // 512
    float p = (float)hist[t] * (1.0f / 1024.0f);
    float e = p * logf(p + 1e-10f);
    for (int off = 32; off; off >>= 1) e += __shfl_down(e, off, 64);
    __shared__ float red[8];
    if ((t & 63) == 0) red[t >> 6] = e;
    __syncthreads();
    if (t == 0) {
        float s = 0.f;
        for (int i = 0; i < 8; ++i) s += red[i];
        out[4147200] = 1.25f * loss[0] * (1.0f / 524288.0f);
        out[4147201] = expf(-s);
    }
}

extern "C" void kernel_launch(void* const* d_in, const int* in_sizes, int n_in,
                              void* d_out, int out_size, void* d_ws, size_t ws_size,
                              hipStream_t stream)
{
    const float* in_seqs = (const float*)d_in[0];
    const float* W_in  = (const float*)d_in[1];
    const float* w_e1  = (const float*)d_in[3];
    const float* g_e1  = (const float*)d_in[4];
    const float* be1   = (const float*)d_in[5];
    const float* w_e2  = (const float*)d_in[6];
    const float* g_e2  = (const float*)d_in[7];
    const float* be2   = (const float*)d_in[8];
    const float* w_e3  = (const float*)d_in[9];
    const float* g_e3  = (const float*)d_in[10];
    const float* be3   = (const float*)d_in[11];
    const float* codebook = (const float*)d_in[12];
    const float* W_q   = (const float*)d_in[13];
    const float* b_q   = (const float*)d_in[14];
    const float* w_d1  = (const float*)d_in[15];
    const float* g_d1  = (const float*)d_in[16];
    const float* bd1   = (const float*)d_in[17];
    const float* w_d2  = (const float*)d_in[18];
    const float* g_d2  = (const float*)d_in[19];
    const float* bd2   = (const float*)d_in[20];
    const float* w_d3  = (const float*)d_in[21];
    const float* g_d3  = (const float*)d_in[22];
    const float* bd3   = (const float*)d_in[23];
    const float* W_out = (const float*)d_in[24];
    const float* b_out = (const float*)d_in[25];
    float* out = (float*)d_out;

    // ---- workspace layout (float offsets) — same as round 6 ----
    float* W = (float*)d_ws;
    unsigned long long* amin = (unsigned long long*)W;            // 2048 f
    float* stats  = W + 2048;                                     // 6144
    float* lossp  = W + 8192;                                     // 64
    unsigned int* hist = (unsigned int*)(W + 8256);               // 512
    float* scsh   = W + 8768;                                     // 6144
    float* codesq = W + 14912;                                    // 512
    float* wt_e1  = W + 15424;                                    // 1310720 f
    float* weff   = W + 1326144;                                  // 345600 f
    float* codeT  = W + 1671744;                                  // 262144 f
    unsigned short* esw = (unsigned short*)(W + 1933888);         // 3440640 ush
    unsigned short* whi_e1 = esw;
    unsigned short* wlo_e1 = esw + 409600;
    unsigned short* whi_e2 = esw + 819200;
    unsigned short* wlo_e2 = esw + 1605632;
    unsigned short* whi_e3 = esw + 2392064;
    unsigned short* wlo_e3 = esw + 2916352;
    unsigned short* in_h  = (unsigned short*)(W + 3654208);       // 4915200 ush
    unsigned short* in_l  = in_h + 4915200;
    unsigned short* d3pre = (unsigned short*)(W + 3654208);       // 15728640 ush
    float* e1f = W + 11518528;                                    // 3145728 f
    unsigned short* e1h = (unsigned short*)(W + 14664256);        // 3145728 ush
    unsigned short* e1l = e1h + 3145728;
    float* e2f = W + 17809984;                                    // 1048576 f
    unsigned short* e2h = (unsigned short*)(W + 18858560);        // 1048576 ush
    unsigned short* e2l = e2h + 1048576;
    unsigned short* d2pre = (unsigned short*)(W + 17809984);      // 3145728 ush
    unsigned short* d2bf  = d2pre + 3145728;                      // 3145728 ush
    float* e3f = W + 20955712;                                    // 524288 f
    unsigned short* quant_bf = (unsigned short*)(W + 21480000);   // 524288 ush
    unsigned short* d0bf     = (unsigned short*)(W + 21742144);   // 524288 ush
    unsigned short* d1pre    = (unsigned short*)(W + 22004288);   // 1048576 ush

    unsigned short* db    = (unsigned short*)wt_e1;
    unsigned short* wqb   = db;
    unsigned short* wd1b  = db + 262144;
    unsigned short* wd2b  = db + 786432;
    unsigned short* wd3b  = db + 1572864;
    unsigned short* woutb = db + 2883584;

    float* st_e1 = stats + 0 * 1024; float* sc_e1 = scsh + 0 * 1024; float* sh_e1 = sc_e1 + 512;
    float* st_e2 = stats + 1 * 1024; float* sc_e2 = scsh + 1 * 1024; float* sh_e2 = sc_e2 + 512;
    float* st_e3 = stats + 2 * 1024; float* sc_e3 = scsh + 2 * 1024; float* sh_e3 = sc_e3 + 512;
    float* st_d1 = stats + 3 * 1024; float* sc_d1 = scsh + 3 * 1024; float* sh_d1 = sc_d1 + 512;
    float* st_d2 = stats + 4 * 1024; float* sc_d2 = scsh + 4 * 1024; float* sh_d2 = sc_d2 + 512;
    float* st_d3 = stats + 5 * 1024; float* sc_d3 = scsh + 5 * 1024; float* sh_d3 = sc_d3 + 512;

    dim3 blk(256);
    k_init<<<dim3(32), blk, 0, stream>>>(stats, amin);

    k_repack<<<dim3(5 * 1024), blk, 0, stream>>>(w_e1, wt_e1, 5, 5 * 262144);
    k_repack<<<dim3(1024),     blk, 0, stream>>>(codebook, codeT, 1, 262144);
    k_codesq<<<dim3(512), dim3(64), 0, stream>>>(codebook, codesq);

    k_gemm<<<dim3(8, 3, 5), blk, 0, stream>>>(W_in, wt_e1, weff, nullptr,
        nullptr, nullptr, nullptr, nullptr, nullptr, 135, 512, 512, 1, 0, 5);

    k_repack_sp_weff<<<dim3(1600), blk, 0, stream>>>(weff, whi_e1, wlo_e1, 409600);
    k_repack_sp<<<dim3(3 * 1024), blk, 0, stream>>>(w_e2, whi_e2, wlo_e2, 3, 3 * 262144);
    k_repack_sp<<<dim3(2 * 1024), blk, 0, stream>>>(w_e3, whi_e3, wlo_e3, 2, 2 * 262144);

    k_repack_bf<<<dim3(1024),     blk, 0, stream>>>(W_q,   wqb,   1, 512, 512, 262144);
    k_repack_bf<<<dim3(2 * 1024), blk, 0, stream>>>(w_d1,  wd1b,  2, 512, 512, 524288);
    k_repack_bf<<<dim3(3 * 1024), blk, 0, stream>>>(w_d2,  wd2b,  3, 512, 512, 786432);
    k_repack_bf<<<dim3(5 * 1024), blk, 0, stream>>>(w_d3,  wd3b,  5, 512, 512, 1310720);
    k_repack_bf<<<dim3(270),      blk, 0, stream>>>(W_out, woutb, 1, 512, 135, 69120);

    k_split_in<<<dim3(19200), blk, 0, stream>>>(in_seqs, in_h, in_l, 4915200);

    // ---- encoder: 64x64-tile split-bf16 MFMA ----
    k_sp64<<<dim3(8, 16, 6), blk, 0, stream>>>(in_h, in_l, whi_e1, wlo_e1,
        e1f, st_e1, 1024, 160, 512, 5);
    k_bn_fin<<<dim3(2), blk, 0, stream>>>(st_e1, g_e1, be1, sc_e1, sh_e1, 1.f / 6144.f);
    k_bnsplit<<<dim3(3072), blk, 0, stream>>>(e1f, sc_e1, sh_e1, e1h, e1l, 786432);

    k_sp64<<<dim3(8, 16, 2), blk, 0, stream>>>(e1h, e1l, whi_e2, wlo_e2,
        e2f, st_e2, 1024, 512, 512, 3);
    k_bn_fin<<<dim3(2), blk, 0, stream>>>(st_e2, g_e2, be2, sc_e2, sh_e2, 1.f / 2048.f);
    k_bnsplit<<<dim3(1024), blk, 0, stream>>>(e2f, sc_e2, sh_e2, e2h, e2l, 262144);

    k_sp64<<<dim3(8, 16, 1), blk, 0, stream>>>(e2h, e2l, whi_e3, wlo_e3,
        e3f, st_e3, 1024, 512, 512, 2);
    k_bn_fin<<<dim3(2), blk, 0, stream>>>(st_e3, g_e3, be3, sc_e3, sh_e3, 1.f / 1024.f);

    // ---- VQ: fp32 dist GEMM + argmin (unchanged) ----
    k_gemm<<<dim3(8, 16, 1), blk, 0, stream>>>(e3f, codeT, nullptr, nullptr,
        sc_e3, sh_e3, nullptr, amin, codesq, 1024, 512, 512, 1, 1, 1);
    k_vq_gather<<<dim3(1024), blk, 0, stream>>>(amin, codebook, e3f, sc_e3, sh_e3,
                                                quant_bf, lossp, hist);

    // ---- decoder: 64x64-tile bf16 MFMA for d0/d1/d2 ----
    k_b64<<<dim3(8, 16, 1), blk, 0, stream>>>(quant_bf, wqb, d0bf,
        b_q, nullptr, nullptr, nullptr, 1024, 512, 512, 1);

    k_b64<<<dim3(8, 16, 2), blk, 0, stream>>>(d0bf, wd1b, d1pre,
        nullptr, nullptr, nullptr, st_d1, 1024, 512, 512, 2);
    k_bn_fin<<<dim3(2), blk, 0, stream>>>(st_d1, g_d1, bd1, sc_d1, sh_d1, 1.f / 2048.f);

    k_b64<<<dim3(8, 16, 6), blk, 0, stream>>>(d1pre, wd2b, d2pre,
        nullptr, sc_d1, sh_d1, st_d2, 1024, 512, 512, 3);
    k_bn_fin<<<dim3(2), blk, 0, stream>>>(st_d2, g_d2, bd2, sc_d2, sh_d2, 1.f / 6144.f);

    k_bnapply<<<dim3(1536), blk, 0, stream>>>(d2pre, sc_d2, sh_d2, d2bf, 393216);

    // d3 + proj keep 128x128 tiles (plenty of blocks)
    k_mfma_b<<<dim3(4, 8, 30), blk, 0, stream>>>(d2bf, wd3b, d3pre, nullptr,
        nullptr, nullptr, nullptr, st_d3, 1024, 512, 512, 5);
    k_bn_fin<<<dim3(2), blk, 0, stream>>>(st_d3, g_d3, bd3, sc_d3, sh_d3, 1.f / 30720.f);

    k_mfma_b<<<dim3(2, 240, 1), blk, 0, stream>>>(d3pre, woutb, nullptr, out,
        b_out, sc_d3, sh_d3, nullptr, 30720, 512, 135, 1);

    k_scalars<<<dim3(1), dim3(512), 0, stream>>>(hist, lossp, out);
}

// Round 11
// 496.198 us; speedup vs baseline: 2.0625x; 1.0594x over previous
//
#include <hip/hip_runtime.h>
#include <math.h>

// ---------------------------------------------------------------------------
// VQ-VAE forward (round 11 = round 10 resubmitted; round-10 bench died with
// the same broker-side "container failed twice" that hit rounds 7/8 before
// the identical source passed in round 9 — treating as infra flake).
//  - Round-9 structure (64x64-tile MFMA kernels, pure-copy staging, bf16
//    decoder acts, pre-split encoder acts, fp32 VQ argmin).
//  - Register-prefetch software pipelining in k_mfma_b/k_b64/k_sp64
//    (load chunk k+1 into VGPRs between the barriers -> global latency
//    overlaps MFMA of chunk k). Numerics identical.
//  - k_prep merges 9 independent prep kernels into one dispatch.
// ---------------------------------------------------------------------------

#define TM 64
#define TN 64
#define BK 32
#define LSTR 68

typedef __attribute__((ext_vector_type(8))) short bf16x8;
typedef __attribute__((ext_vector_type(4))) float f32x4;

__device__ __forceinline__ unsigned pk_bf16(float a, float b) {
    unsigned ua = __float_as_uint(a), ub = __float_as_uint(b);
    ua += 0x7fffu + ((ua >> 16) & 1u);          // RNE
    ub += 0x7fffu + ((ub >> 16) & 1u);
    return (ua >> 16) | (ub & 0xffff0000u);
}
__device__ __forceinline__ unsigned short bfh(float x) {
    unsigned u = __float_as_uint(x);
    u += 0x7fffu + ((u >> 16) & 1u);
    return (unsigned short)(u >> 16);
}
__device__ __forceinline__ float bf2f(unsigned short h) {
    return __uint_as_float(((unsigned)h) << 16);
}

// BN+ReLU on packed bf16 pairs; kbase = absolute k of raw[0] low half
template <int NV>
__device__ __forceinline__ void bn_on_raw(uint4* raw, int kbase,
                                          const float* __restrict__ bnS,
                                          const float* __restrict__ bnB) {
#pragma unroll
    for (int i = 0; i < NV; ++i) {
        unsigned* u4 = (unsigned*)&raw[i];
#pragma unroll
        for (int j = 0; j < 4; ++j) {
            const int k = kbase + (i << 3) + (j << 1);
            unsigned u = u4[j];
            float x0 = __uint_as_float(u << 16);
            float x1 = __uint_as_float(u & 0xffff0000u);
            x0 = fmaxf(fmaf(x0, bnS[k],     bnB[k]),     0.f);
            x1 = fmaxf(fmaf(x1, bnS[k + 1], bnB[k + 1]), 0.f);
            u4[j] = pk_bf16(x0, x1);
        }
    }
}

// ======================= fp32 GEMM (weff + VQ dist) ========================
__global__ __launch_bounds__(256)
void k_gemm(const float* __restrict__ Abase,
            const float* __restrict__ Wt,
            float* __restrict__ Cout,
            const float* __restrict__ bias,
            const float* __restrict__ bnS, const float* __restrict__ bnB,
            float* __restrict__ stats,
            unsigned long long* __restrict__ amin,
            const float* __restrict__ codesq,
            int Mslice, int K, int N,
            int n_terms, int enc_mode, int decK)
{
    __shared__ __align__(16) float As[BK][LSTR];
    __shared__ __align__(16) float Bs[BK][LSTR];
    __shared__ float colsum[TN];
    __shared__ float colsq[TN];

    const int tid = threadIdx.x;
    const int z  = blockIdx.z;
    const int n0 = blockIdx.x * TN;
    const int m0 = blockIdx.y * TM;
    const int ty = tid >> 4;
    const int tx = tid & 15;

    if (stats != nullptr && tid < TN) { colsum[tid] = 0.f; colsq[tid] = 0.f; }

    float acc[4][4];
#pragma unroll
    for (int i = 0; i < 4; ++i)
#pragma unroll
        for (int j = 0; j < 4; ++j) acc[i][j] = 0.f;

    const int arow = tid >> 2;
    const int ac4  = (tid & 3) << 2;
    const int brow = tid >> 3;
    const int bc4  = (tid & 7) << 2;

    int mrow = m0 + arow;
    if (mrow > Mslice - 1) mrow = Mslice - 1;

    const bool alignedK = ((K & 31) == 0);

    for (int term = 0; term < n_terms; ++term) {
        int a_slice, wk;
        if (enc_mode) { a_slice = z * n_terms + term; wk = term; }
        else          { a_slice = z / decK;           wk = z % decK; }
        const float* Ap = Abase + (size_t)a_slice * (size_t)Mslice * (size_t)K;
        const float* Wp = Wt    + (size_t)wk * (size_t)K * (size_t)N;
        const float* Arow_p = Ap + (size_t)mrow * (size_t)K;

        for (int k0 = 0; k0 < K; k0 += BK) {
            __syncthreads();
            if (alignedK) {
                float4 a0 = *(const float4*)(Arow_p + k0 + ac4);
                float4 a1 = *(const float4*)(Arow_p + k0 + ac4 + 16);
                if (bnS != nullptr) {
                    float4 s0 = *(const float4*)(bnS + k0 + ac4);
                    float4 c0 = *(const float4*)(bnB + k0 + ac4);
                    float4 s1 = *(const float4*)(bnS + k0 + ac4 + 16);
                    float4 c1 = *(const float4*)(bnB + k0 + ac4 + 16);
                    a0.x = fmaxf(fmaf(a0.x, s0.x, c0.x), 0.f);
                    a0.y = fmaxf(fmaf(a0.y, s0.y, c0.y), 0.f);
                    a0.z = fmaxf(fmaf(a0.z, s0.z, c0.z), 0.f);
                    a0.w = fmaxf(fmaf(a0.w, s0.w, c0.w), 0.f);
                    a1.x = fmaxf(fmaf(a1.x, s1.x, c1.x), 0.f);
                    a1.y = fmaxf(fmaf(a1.y, s1.y, c1.y), 0.f);
                    a1.z = fmaxf(fmaf(a1.z, s1.z, c1.z), 0.f);
                    a1.w = fmaxf(fmaf(a1.w, s1.w, c1.w), 0.f);
                }
                As[ac4+0][arow] = a0.x;  As[ac4+1][arow] = a0.y;
                As[ac4+2][arow] = a0.z;  As[ac4+3][arow] = a0.w;
                As[ac4+16][arow] = a1.x; As[ac4+17][arow] = a1.y;
                As[ac4+18][arow] = a1.z; As[ac4+19][arow] = a1.w;
            } else {
#pragma unroll
                for (int j = 0; j < 4; ++j) {
                    int k = k0 + ac4 + j;
                    As[ac4+j][arow] = (k < K) ? Arow_p[k] : 0.f;
                    int k2 = k + 16;
                    As[ac4+16+j][arow] = (k2 < K) ? Arow_p[k2] : 0.f;
                }
            }
            {
                int kB = k0 + brow;
                float4 b0 = make_float4(0.f, 0.f, 0.f, 0.f);
                float4 b1 = make_float4(0.f, 0.f, 0.f, 0.f);
                if (kB < K) {
                    const float* wrow = Wp + (size_t)kB * N + n0;
                    b0 = *(const float4*)(wrow + bc4);
                    b1 = *(const float4*)(wrow + bc4 + 32);
                }
                *(float4*)&Bs[brow][bc4]      = b0;
                *(float4*)&Bs[brow][bc4 + 32] = b1;
            }
            __syncthreads();
#pragma unroll
            for (int kk = 0; kk < BK; ++kk) {
                float4 av = *(const float4*)&As[kk][ty << 2];
                float4 bv = *(const float4*)&Bs[kk][tx << 2];
                acc[0][0] = fmaf(av.x, bv.x, acc[0][0]);
                acc[0][1] = fmaf(av.x, bv.y, acc[0][1]);
                acc[0][2] = fmaf(av.x, bv.z, acc[0][2]);
                acc[0][3] = fmaf(av.x, bv.w, acc[0][3]);
                acc[1][0] = fmaf(av.y, bv.x, acc[1][0]);
                acc[1][1] = fmaf(av.y, bv.y, acc[1][1]);
                acc[1][2] = fmaf(av.y, bv.z, acc[1][2]);
                acc[1][3] = fmaf(av.y, bv.w, acc[1][3]);
                acc[2][0] = fmaf(av.z, bv.x, acc[2][0]);
                acc[2][1] = fmaf(av.z, bv.y, acc[2][1]);
                acc[2][2] = fmaf(av.z, bv.z, acc[2][2]);
                acc[2][3] = fmaf(av.z, bv.w, acc[2][3]);
                acc[3][0] = fmaf(av.w, bv.x, acc[3][0]);
                acc[3][1] = fmaf(av.w, bv.y, acc[3][1]);
                acc[3][2] = fmaf(av.w, bv.z, acc[3][2]);
                acc[3][3] = fmaf(av.w, bv.w, acc[3][3]);
            }
        }
    }

    if (amin != nullptr) {
        float4 cq = *(const float4*)(codesq + n0 + (tx << 2));
#pragma unroll
        for (int i = 0; i < 4; ++i) {
            int m = m0 + (ty << 2) + i;
            if (m >= Mslice) continue;
            float d0 = cq.x - 2.f * acc[i][0];
            float d1 = cq.y - 2.f * acc[i][1];
            float d2 = cq.z - 2.f * acc[i][2];
            float d3 = cq.w - 2.f * acc[i][3];
            float best = d0; int bj = 0;
            if (d1 < best) { best = d1; bj = 1; }
            if (d2 < best) { best = d2; bj = 2; }
            if (d3 < best) { best = d3; bj = 3; }
            unsigned u = __float_as_uint(best);
            u = (u & 0x80000000u) ? ~u : (u | 0x80000000u);
            unsigned long long key =
                ((unsigned long long)u << 32) | (unsigned)(n0 + (tx << 2) + bj);
            atomicMin(&amin[m], key);
        }
        return;
    }

#pragma unroll
    for (int i = 0; i < 4; ++i) {
        int m = m0 + (ty << 2) + i;
        if (m >= Mslice) continue;
        float4 v = make_float4(acc[i][0], acc[i][1], acc[i][2], acc[i][3]);
        if (bias != nullptr) {
            float4 bb = *(const float4*)(bias + n0 + (tx << 2));
            v.x += bb.x; v.y += bb.y; v.z += bb.z; v.w += bb.w;
        }
        *(float4*)&Cout[((size_t)z * Mslice + m) * N + n0 + (tx << 2)] = v;
    }

    if (stats != nullptr) {
#pragma unroll
        for (int j = 0; j < 4; ++j) {
            float s = 0.f, q = 0.f;
#pragma unroll
            for (int i = 0; i < 4; ++i) {
                int m = m0 + (ty << 2) + i;
                if (m < Mslice) { float x = acc[i][j]; s += x; q += x * x; }
            }
            atomicAdd(&colsum[(tx << 2) + j], s);
            atomicAdd(&colsq [(tx << 2) + j], q);
        }
        __syncthreads();
        if (tid < TN) {
            atomicAdd(&stats[n0 + tid],       colsum[tid]);
            atomicAdd(&stats[512 + n0 + tid], colsq[tid]);
        }
    }
}

// ===== bf16 MFMA GEMM, 128x128 tile, reg-prefetch (d3 + out-proj) ==========
#define ASTR 72

__global__ __launch_bounds__(256)
void k_mfma_b(const unsigned short* __restrict__ Abase,
              const unsigned short* __restrict__ Bt,
              unsigned short* __restrict__ Cb,
              float* __restrict__ operm,
              const float* __restrict__ bias,
              const float* __restrict__ bnS, const float* __restrict__ bnB,
              float* __restrict__ stats,
              int Mslice, int K, int N, int decK)
{
    __shared__ __align__(16) unsigned short As[128 * ASTR];
    __shared__ __align__(16) unsigned short Bs[128 * ASTR];
    __shared__ float colsum[128], colsq[128];

    const int tid  = threadIdx.x;
    const int lane = tid & 63;
    const int wave = tid >> 6;
    const int wm = (wave >> 1) << 6;
    const int wn = (wave & 1) << 6;
    const int z  = blockIdx.z;
    const int n0 = blockIdx.x << 7;
    const int m0 = blockIdx.y << 7;

    if (stats != nullptr && tid < 128) { colsum[tid] = 0.f; colsq[tid] = 0.f; }

    const int a_slice = z / decK, wk = z - a_slice * decK;
    const unsigned short* Ap = Abase + (size_t)a_slice * (size_t)Mslice * (size_t)K;
    const unsigned short* Bp = Bt + (size_t)wk * (size_t)N * (size_t)K;

    const int sr = tid >> 1;           // 0..127
    const int sk = (tid & 1) << 5;     // 0 or 32 elems

    const unsigned short* Arow = Ap + (size_t)(m0 + sr) * K + sk;
    const unsigned short* Brow = Bp + (size_t)(n0 + sr) * K + sk;
    const bool bvalid = (n0 + sr) < N;

    f32x4 acc[4][4];
#pragma unroll
    for (int i = 0; i < 4; ++i)
#pragma unroll
        for (int j = 0; j < 4; ++j) acc[i][j] = (f32x4){0.f, 0.f, 0.f, 0.f};

    const int lidx = lane & 15;
    const int lq   = lane >> 4;

    // ---- prefetch chunk 0 into registers ----
    uint4 pa[4], pb[4];
#pragma unroll
    for (int i = 0; i < 4; ++i) pa[i] = *(const uint4*)(Arow + (i << 3));
    if (bnS != nullptr) bn_on_raw<4>(pa, sk, bnS, bnB);
    if (bvalid) {
#pragma unroll
        for (int i = 0; i < 4; ++i) pb[i] = *(const uint4*)(Brow + (i << 3));
    } else {
#pragma unroll
        for (int i = 0; i < 4; ++i) pb[i] = make_uint4(0u, 0u, 0u, 0u);
    }

    for (int k0 = 0; k0 < K; k0 += 64) {
        __syncthreads();
        {
            uint4* dA = (uint4*)&As[sr * ASTR + sk];
            uint4* dB = (uint4*)&Bs[sr * ASTR + sk];
#pragma unroll
            for (int i = 0; i < 4; ++i) { dA[i] = pa[i]; dB[i] = pb[i]; }
        }
        const int k0n = k0 + 64;
        if (k0n < K) {
#pragma unroll
            for (int i = 0; i < 4; ++i) pa[i] = *(const uint4*)(Arow + k0n + (i << 3));
            if (bnS != nullptr) bn_on_raw<4>(pa, k0n + sk, bnS, bnB);
            if (bvalid) {
#pragma unroll
                for (int i = 0; i < 4; ++i) pb[i] = *(const uint4*)(Brow + k0n + (i << 3));
            }
        }
        __syncthreads();
#pragma unroll
        for (int ks = 0; ks < 2; ++ks) {
            const int kb = (ks << 5) + (lq << 3);
            bf16x8 af[4], bfv[4];
#pragma unroll
            for (int t = 0; t < 4; ++t)
                af[t] = *(const bf16x8*)&As[(wm + (t << 4) + lidx) * ASTR + kb];
#pragma unroll
            for (int t = 0; t < 4; ++t)
                bfv[t] = *(const bf16x8*)&Bs[(wn + (t << 4) + lidx) * ASTR + kb];
#pragma unroll
            for (int mt = 0; mt < 4; ++mt)
#pragma unroll
                for (int nt = 0; nt < 4; ++nt)
                    acc[mt][nt] = __builtin_amdgcn_mfma_f32_16x16x32_bf16(
                        af[mt], bfv[nt], acc[mt][nt], 0, 0, 0);
        }
    }

    const int rbase = lq << 2;
#pragma unroll
    for (int nt = 0; nt < 4; ++nt) {
        const int col = n0 + wn + (nt << 4) + lidx;
        const float badd = (bias != nullptr && col < N) ? bias[col] : 0.f;
        float s = 0.f, q = 0.f;
#pragma unroll
        for (int mt = 0; mt < 4; ++mt) {
#pragma unroll
            for (int r = 0; r < 4; ++r) {
                float x = acc[mt][nt][r];
                s += x; q += x * x;
                const int row = m0 + wm + (mt << 4) + rbase + r;
                if (operm != nullptr) {
                    if (col < N) {
                        const int t = row >> 10, b = row & 1023;
                        operm[(size_t)b * 4050 + t * 135 + col] = x + badd;
                    }
                } else {
                    Cb[((size_t)z * Mslice + row) * (size_t)N + col] = bfh(x + badd);
                }
            }
        }
        if (stats != nullptr) {
            s += __shfl_xor(s, 16, 64); s += __shfl_xor(s, 32, 64);
            q += __shfl_xor(q, 16, 64); q += __shfl_xor(q, 32, 64);
            if (lq == 0) {
                atomicAdd(&colsum[wn + (nt << 4) + lidx], s);
                atomicAdd(&colsq [wn + (nt << 4) + lidx], q);
            }
        }
    }
    if (stats != nullptr) {
        __syncthreads();
        if (tid < 128) {
            atomicAdd(&stats[n0 + tid],       colsum[tid]);
            atomicAdd(&stats[512 + n0 + tid], colsq[tid]);
        }
    }
}

// ===== bf16 MFMA GEMM, 64x64 tile, reg-prefetch (d0, d1, d2) ===============
#define BSTR 72

__global__ __launch_bounds__(256)
void k_b64(const unsigned short* __restrict__ Abase,
           const unsigned short* __restrict__ Bt,
           unsigned short* __restrict__ Cb,
           const float* __restrict__ bias,
           const float* __restrict__ bnS, const float* __restrict__ bnB,
           float* __restrict__ stats,
           int Mslice, int K, int N, int decK)
{
    __shared__ __align__(16) unsigned short As[64 * BSTR];
    __shared__ __align__(16) unsigned short Bs[64 * BSTR];
    __shared__ float colsum[64], colsq[64];

    const int tid  = threadIdx.x;
    const int lane = tid & 63;
    const int wave = tid >> 6;
    const int wm = (wave >> 1) << 5;
    const int wn = (wave & 1) << 5;
    const int z  = blockIdx.z;
    const int n0 = blockIdx.x << 6;
    const int m0 = blockIdx.y << 6;

    if (stats != nullptr && tid < 64) { colsum[tid] = 0.f; colsq[tid] = 0.f; }

    const int a_slice = z / decK, wk = z - a_slice * decK;
    const unsigned short* Ap = Abase + (size_t)a_slice * (size_t)Mslice * (size_t)K;
    const unsigned short* Bp = Bt + (size_t)wk * (size_t)N * (size_t)K;

    const int sr = tid >> 2;           // 0..63
    const int sk = (tid & 3) << 4;     // 0,16,32,48 elems

    const unsigned short* Arow = Ap + (size_t)(m0 + sr) * K + sk;
    const unsigned short* Brow = Bp + (size_t)(n0 + sr) * K + sk;

    f32x4 acc[2][2];
#pragma unroll
    for (int i = 0; i < 2; ++i)
#pragma unroll
        for (int j = 0; j < 2; ++j) acc[i][j] = (f32x4){0.f, 0.f, 0.f, 0.f};

    const int lidx = lane & 15;
    const int lq   = lane >> 4;

    // ---- prefetch chunk 0 ----
    uint4 pa[2], pb[2];
    pa[0] = *(const uint4*)(Arow);
    pa[1] = *(const uint4*)(Arow + 8);
    if (bnS != nullptr) bn_on_raw<2>(pa, sk, bnS, bnB);
    pb[0] = *(const uint4*)(Brow);
    pb[1] = *(const uint4*)(Brow + 8);

    for (int k0 = 0; k0 < K; k0 += 64) {
        __syncthreads();
        {
            uint4* dA = (uint4*)&As[sr * BSTR + sk];
            uint4* dB = (uint4*)&Bs[sr * BSTR + sk];
            dA[0] = pa[0]; dA[1] = pa[1];
            dB[0] = pb[0]; dB[1] = pb[1];
        }
        const int k0n = k0 + 64;
        if (k0n < K) {
            pa[0] = *(const uint4*)(Arow + k0n);
            pa[1] = *(const uint4*)(Arow + k0n + 8);
            if (bnS != nullptr) bn_on_raw<2>(pa, k0n + sk, bnS, bnB);
            pb[0] = *(const uint4*)(Brow + k0n);
            pb[1] = *(const uint4*)(Brow + k0n + 8);
        }
        __syncthreads();
#pragma unroll
        for (int ks = 0; ks < 2; ++ks) {
            const int kb = (ks << 5) + (lq << 3);
            bf16x8 af[2], bfv[2];
#pragma unroll
            for (int t = 0; t < 2; ++t)
                af[t] = *(const bf16x8*)&As[(wm + (t << 4) + lidx) * BSTR + kb];
#pragma unroll
            for (int t = 0; t < 2; ++t)
                bfv[t] = *(const bf16x8*)&Bs[(wn + (t << 4) + lidx) * BSTR + kb];
#pragma unroll
            for (int mt = 0; mt < 2; ++mt)
#pragma unroll
                for (int nt = 0; nt < 2; ++nt)
                    acc[mt][nt] = __builtin_amdgcn_mfma_f32_16x16x32_bf16(
                        af[mt], bfv[nt], acc[mt][nt], 0, 0, 0);
        }
    }

    const int rbase = lq << 2;
#pragma unroll
    for (int nt = 0; nt < 2; ++nt) {
        const int col = n0 + wn + (nt << 4) + lidx;
        const float badd = (bias != nullptr) ? bias[col] : 0.f;
        float s = 0.f, q = 0.f;
#pragma unroll
        for (int mt = 0; mt < 2; ++mt) {
#pragma unroll
            for (int r = 0; r < 4; ++r) {
                float x = acc[mt][nt][r];
                s += x; q += x * x;
                const int row = m0 + wm + (mt << 4) + rbase + r;
                Cb[((size_t)z * Mslice + row) * (size_t)N + col] = bfh(x + badd);
            }
        }
        if (stats != nullptr) {
            s += __shfl_xor(s, 16, 64); s += __shfl_xor(s, 32, 64);
            q += __shfl_xor(q, 16, 64); q += __shfl_xor(q, 32, 64);
            if (lq == 0) {
                atomicAdd(&colsum[wn + (nt << 4) + lidx], s);
                atomicAdd(&colsq [wn + (nt << 4) + lidx], q);
            }
        }
    }
    if (stats != nullptr) {
        __syncthreads();
        if (tid < 64) {
            atomicAdd(&stats[n0 + tid],       colsum[tid]);
            atomicAdd(&stats[512 + n0 + tid], colsq[tid]);
        }
    }
}

// ===== split-bf16 MFMA GEMM, 64x64 tile, reg-prefetch (encoder convs) ======
#define S64 40

__global__ __launch_bounds__(256)
void k_sp64(const unsigned short* __restrict__ Ahg,
            const unsigned short* __restrict__ Alg,
            const unsigned short* __restrict__ Whi,
            const unsigned short* __restrict__ Wlo,
            float* __restrict__ Cout, float* __restrict__ stats,
            int Mslice, int Kp, int N, int n_terms)
{
    __shared__ __align__(16) unsigned short Ah[64 * S64];
    __shared__ __align__(16) unsigned short Al[64 * S64];
    __shared__ __align__(16) unsigned short Bh[64 * S64];
    __shared__ __align__(16) unsigned short Bl[64 * S64];
    __shared__ float colsum[64], colsq[64];

    const int tid  = threadIdx.x;
    const int lane = tid & 63;
    const int wave = tid >> 6;
    const int wm = (wave >> 1) << 5;
    const int wn = (wave & 1) << 5;
    const int z  = blockIdx.z;
    const int n0 = blockIdx.x << 6;
    const int m0 = blockIdx.y << 6;

    if (stats != nullptr && tid < 64) { colsum[tid] = 0.f; colsq[tid] = 0.f; }

    const int sr = tid >> 2;           // 0..63
    const int sk = (tid & 3) << 3;     // 0,8,16,24 elems

    f32x4 acc[2][2];
#pragma unroll
    for (int i = 0; i < 2; ++i)
#pragma unroll
        for (int j = 0; j < 2; ++j) acc[i][j] = (f32x4){0.f, 0.f, 0.f, 0.f};

    const int lidx = lane & 15;
    const int lq   = lane >> 4;
    const int kb   = lq << 3;

    const int cpk = Kp >> 5;
    const int tot = n_terms * cpk;

    // ---- prefetch chunk 0 (term 0, k0 0) ----
    uint4 rah, ral, rbh, rblv;
    {
        const size_t ab = ((size_t)(z * n_terms) * Mslice + m0 + sr) * (size_t)Kp + sk;
        rah = *(const uint4*)(Ahg + ab);
        ral = *(const uint4*)(Alg + ab);
        const size_t bb = ((size_t)(n0 + sr)) * (size_t)Kp + sk;
        rbh = *(const uint4*)(Whi + bb);
        rblv = *(const uint4*)(Wlo + bb);
    }
    int lt = 0, lk = 32;
    if (lk >= Kp) { lk = 0; lt = 1; }

    for (int c = 0; c < tot; ++c) {
        __syncthreads();
        *(uint4*)&Ah[sr * S64 + sk] = rah;
        *(uint4*)&Al[sr * S64 + sk] = ral;
        *(uint4*)&Bh[sr * S64 + sk] = rbh;
        *(uint4*)&Bl[sr * S64 + sk] = rblv;
        if (c + 1 < tot) {
            const size_t ab = ((size_t)(z * n_terms + lt) * Mslice + m0 + sr) * (size_t)Kp + lk + sk;
            rah = *(const uint4*)(Ahg + ab);
            ral = *(const uint4*)(Alg + ab);
            const size_t bb = ((size_t)lt * N + n0 + sr) * (size_t)Kp + lk + sk;
            rbh = *(const uint4*)(Whi + bb);
            rblv = *(const uint4*)(Wlo + bb);
            lk += 32; if (lk >= Kp) { lk = 0; ++lt; }
        }
        __syncthreads();
        bf16x8 ah[2], al[2], bh[2], bl[2];
#pragma unroll
        for (int t = 0; t < 2; ++t) {
            const int ra = (wm + (t << 4) + lidx) * S64 + kb;
            ah[t] = *(const bf16x8*)&Ah[ra];
            al[t] = *(const bf16x8*)&Al[ra];
        }
#pragma unroll
        for (int t = 0; t < 2; ++t) {
            const int rb = (wn + (t << 4) + lidx) * S64 + kb;
            bh[t] = *(const bf16x8*)&Bh[rb];
            bl[t] = *(const bf16x8*)&Bl[rb];
        }
#pragma unroll
        for (int mt = 0; mt < 2; ++mt)
#pragma unroll
            for (int nt = 0; nt < 2; ++nt) {
                acc[mt][nt] = __builtin_amdgcn_mfma_f32_16x16x32_bf16(
                    ah[mt], bh[nt], acc[mt][nt], 0, 0, 0);
                acc[mt][nt] = __builtin_amdgcn_mfma_f32_16x16x32_bf16(
                    al[mt], bh[nt], acc[mt][nt], 0, 0, 0);
                acc[mt][nt] = __builtin_amdgcn_mfma_f32_16x16x32_bf16(
                    ah[mt], bl[nt], acc[mt][nt], 0, 0, 0);
            }
    }

    const int rbase = lq << 2;
#pragma unroll
    for (int nt = 0; nt < 2; ++nt) {
        const int col = n0 + wn + (nt << 4) + lidx;
        float s = 0.f, q = 0.f;
#pragma unroll
        for (int mt = 0; mt < 2; ++mt) {
#pragma unroll
            for (int r = 0; r < 4; ++r) {
                float x = acc[mt][nt][r];
                s += x; q += x * x;
                const int row = m0 + wm + (mt << 4) + rbase + r;
                Cout[((size_t)z * Mslice + row) * (size_t)N + col] = x;
            }
        }
        if (stats != nullptr) {
            s += __shfl_xor(s, 16, 64); s += __shfl_xor(s, 32, 64);
            q += __shfl_xor(q, 16, 64); q += __shfl_xor(q, 32, 64);
            if (lq == 0) {
                atomicAdd(&colsum[wn + (nt << 4) + lidx], s);
                atomicAdd(&colsq [wn + (nt << 4) + lidx], q);
            }
        }
    }
    if (stats != nullptr) {
        __syncthreads();
        if (tid < 64) {
            atomicAdd(&stats[n0 + tid],       colsum[tid]);
            atomicAdd(&stats[512 + n0 + tid], colsq[tid]);
        }
    }
}

// ================= merged prep kernel (9 independent preps) ================
// sections (block ranges):
//  s0 init:32  s1 codeT:1024  s2 codesq:512  s3 spE2:3072  s4 spE3:2048
//  s5 wq:1024  s6 wd1:2048  s7 wd2:3072  s8 wd3:5120  s9 wout:270
//  s10 split_in:19200   total 37422
__global__ void k_prep(float* __restrict__ zbase, unsigned long long* __restrict__ amin,
                       const float* __restrict__ codebook, float* __restrict__ codeT,
                       float* __restrict__ codesq,
                       const float* __restrict__ w_e2, unsigned short* __restrict__ whi_e2,
                       unsigned short* __restrict__ wlo_e2,
                       const float* __restrict__ w_e3, unsigned short* __restrict__ whi_e3,
                       unsigned short* __restrict__ wlo_e3,
                       const float* __restrict__ W_q,  unsigned short* __restrict__ wqb,
                       const float* __restrict__ w_d1, unsigned short* __restrict__ wd1b,
                       const float* __restrict__ w_d2, unsigned short* __restrict__ wd2b,
                       const float* __restrict__ w_d3, unsigned short* __restrict__ wd3b,
                       const float* __restrict__ W_out, unsigned short* __restrict__ woutb,
                       const float* __restrict__ in_seqs,
                       unsigned short* __restrict__ in_h, unsigned short* __restrict__ in_l)
{
    __shared__ float red[4];
    const int bid = blockIdx.x;
    const int tid = threadIdx.x;

    if (bid < 32) {                                    // s0: init
        int t = bid * 256 + tid;
        if (t < 6720) zbase[t] = 0.f;
        if (t < 1024) amin[t] = ~0ULL;
        return;
    }
    if (bid < 1056) {                                  // s1: codeT repack (Kc=1)
        int idx = (bid - 32) * 256 + tid;
        int i = (idx >> 9) & 511, o = idx & 511;
        codeT[idx] = codebook[(o << 9) + i];
        return;
    }
    if (bid < 1568) {                                  // s2: codesq
        int c = bid - 1056;
        float s = 0.f;
        for (int i = tid; i < 512; i += 256) { float v = codebook[c * 512 + i]; s += v * v; }
        for (int off = 32; off; off >>= 1) s += __shfl_down(s, off, 64);
        if ((tid & 63) == 0) red[tid >> 6] = s;
        __syncthreads();
        if (tid == 0) codesq[c] = red[0] + red[1] + red[2] + red[3];
        return;
    }
    if (bid < 4640) {                                  // s3: split e2 (Kc=3)
        int idx = (bid - 1568) * 256 + tid;
        int i = idx & 511, o = (idx >> 9) & 511, k = idx >> 18;
        float v = w_e2[(((o << 9) + i) * 3) + k];
        unsigned short h = bfh(v);
        whi_e2[idx] = h; wlo_e2[idx] = bfh(v - bf2f(h));
        return;
    }
    if (bid < 6688) {                                  // s4: split e3 (Kc=2)
        int idx = (bid - 4640) * 256 + tid;
        int i = idx & 511, o = (idx >> 9) & 511, k = idx >> 18;
        float v = w_e3[(((o << 9) + i) * 2) + k];
        unsigned short h = bfh(v);
        whi_e3[idx] = h; wlo_e3[idx] = bfh(v - bf2f(h));
        return;
    }
    if (bid < 7712) {                                  // s5: W_q bf (Kc=1,I=O=512)
        int idx = (bid - 6688) * 256 + tid;
        int i = idx & 511, o = (idx >> 9) & 511;
        wqb[idx] = bfh(W_q[((size_t)i << 9) + o]);
        return;
    }
    if (bid < 9760) {                                  // s6: w_d1 bf (Kc=2)
        int idx = (bid - 7712) * 256 + tid;
        int i = idx & 511, o = (idx >> 9) & 511, k = idx >> 18;
        wd1b[idx] = bfh(w_d1[(((size_t)i << 9) + o) * 2 + k]);
        return;
    }
    if (bid < 12832) {                                 // s7: w_d2 bf (Kc=3)
        int idx = (bid - 9760) * 256 + tid;
        int i = idx & 511, o = (idx >> 9) & 511, k = idx >> 18;
        wd2b[idx] = bfh(w_d2[(((size_t)i << 9) + o) * 3 + k]);
        return;
    }
    if (bid < 17952) {                                 // s8: w_d3 bf (Kc=5)
        int idx = (bid - 12832) * 256 + tid;
        int i = idx & 511, o = (idx >> 9) & 511, k = idx >> 18;
        wd3b[idx] = bfh(w_d3[(((size_t)i << 9) + o) * 5 + k]);
        return;
    }
    if (bid < 18222) {                                 // s9: W_out bf (Kc=1,I=512,O=135)
        int idx = (bid - 17952) * 256 + tid;
        if (idx >= 69120) return;
        int i = idx % 512, o = idx / 512;              // [o][i], o<135
        woutb[idx] = bfh(W_out[((size_t)i * 135) + o]);
        return;
    }
    {                                                  // s10: split_in
        int idx = (bid - 18222) * 256 + tid;
        if (idx >= 4915200) return;
        int i = idx % 160, r = idx / 160;
        float v = (i < 135) ? in_seqs[(size_t)r * 135 + i] : 0.f;
        unsigned short h = bfh(v);
        in_h[idx] = h; in_l[idx] = bfh(v - bf2f(h));
    }
}

// ============================ small kernels ================================
__global__ void k_repack(const float* __restrict__ w, float* __restrict__ wt,
                         int Kc, int total)
{
    int idx = blockIdx.x * 256 + threadIdx.x;
    if (idx >= total) return;
    int k = idx >> 18;
    int rem = idx & 262143;
    int i = rem >> 9, o = rem & 511;
    wt[idx] = w[(((o << 9) + i) * Kc + k)];
}

__global__ void k_repack_sp_weff(const float* __restrict__ weff,
                                 unsigned short* __restrict__ whi,
                                 unsigned short* __restrict__ wlo,
                                 int total)
{
    int idx = blockIdx.x * 256 + threadIdx.x;
    if (idx >= total) return;
    int i = idx % 160;
    int o = (idx / 160) & 511;
    int t = idx / 81920;
    float v = (i < 135) ? weff[((size_t)t * 135 + i) * 512 + o] : 0.f;
    unsigned short h = bfh(v);
    whi[idx] = h;
    wlo[idx] = bfh(v - bf2f(h));
}

__global__ void k_bnsplit(const float* __restrict__ x,
                          const float* __restrict__ sc, const float* __restrict__ sh,
                          unsigned short* __restrict__ hq, unsigned short* __restrict__ lq_,
                          int total4)
{
    int idx = blockIdx.x * 256 + threadIdx.x;
    if (idx >= total4) return;
    const int base = idx << 2;
    float4 f = *(const float4*)(x + base);
    const int k = base & 511;
    float4 s = *(const float4*)(sc + k);
    float4 c = *(const float4*)(sh + k);
    float y0 = fmaxf(fmaf(f.x, s.x, c.x), 0.f);
    float y1 = fmaxf(fmaf(f.y, s.y, c.y), 0.f);
    float y2 = fmaxf(fmaf(f.z, s.z, c.z), 0.f);
    float y3 = fmaxf(fmaf(f.w, s.w, c.w), 0.f);
    unsigned short h0 = bfh(y0), h1 = bfh(y1), h2 = bfh(y2), h3 = bfh(y3);
    unsigned short l0 = bfh(y0 - bf2f(h0)), l1 = bfh(y1 - bf2f(h1));
    unsigned short l2 = bfh(y2 - bf2f(h2)), l3 = bfh(y3 - bf2f(h3));
    *(uint2*)&hq[base]  = make_uint2((unsigned)h0 | ((unsigned)h1 << 16),
                                     (unsigned)h2 | ((unsigned)h3 << 16));
    *(uint2*)&lq_[base] = make_uint2((unsigned)l0 | ((unsigned)l1 << 16),
                                     (unsigned)l2 | ((unsigned)l3 << 16));
}

__global__ void k_bnapply(const unsigned short* __restrict__ x,
                          const float* __restrict__ sc, const float* __restrict__ sh,
                          unsigned short* __restrict__ y, int total8)
{
    int idx = blockIdx.x * 256 + threadIdx.x;
    if (idx >= total8) return;
    const int base = idx << 3;
    uint4 raw = *(const uint4*)(x + base);
    const int k = base & 511;
    float4 s0 = *(const float4*)(sc + k);
    float4 c0 = *(const float4*)(sh + k);
    float4 s1 = *(const float4*)(sc + k + 4);
    float4 c1 = *(const float4*)(sh + k + 4);
    unsigned* u = (unsigned*)&raw;
    float x0 = __uint_as_float(u[0] << 16),        x1 = __uint_as_float(u[0] & 0xffff0000u);
    float x2 = __uint_as_float(u[1] << 16),        x3 = __uint_as_float(u[1] & 0xffff0000u);
    float x4 = __uint_as_float(u[2] << 16),        x5 = __uint_as_float(u[2] & 0xffff0000u);
    float x6 = __uint_as_float(u[3] << 16),        x7 = __uint_as_float(u[3] & 0xffff0000u);
    x0 = fmaxf(fmaf(x0, s0.x, c0.x), 0.f); x1 = fmaxf(fmaf(x1, s0.y, c0.y), 0.f);
    x2 = fmaxf(fmaf(x2, s0.z, c0.z), 0.f); x3 = fmaxf(fmaf(x3, s0.w, c0.w), 0.f);
    x4 = fmaxf(fmaf(x4, s1.x, c1.x), 0.f); x5 = fmaxf(fmaf(x5, s1.y, c1.y), 0.f);
    x6 = fmaxf(fmaf(x6, s1.z, c1.z), 0.f); x7 = fmaxf(fmaf(x7, s1.w, c1.w), 0.f);
    *(uint4*)&y[base] = make_uint4(pk_bf16(x0, x1), pk_bf16(x2, x3),
                                   pk_bf16(x4, x5), pk_bf16(x6, x7));
}

__global__ void k_bn_fin(const float* __restrict__ stats,
                         const float* __restrict__ g, const float* __restrict__ b,
                         float* __restrict__ sc, float* __restrict__ sh, float inv_n)
{
    int c = blockIdx.x * blockDim.x + threadIdx.x;
    if (c >= 512) return;
    float m = stats[c] * inv_n;
    float v = stats[512 + c] * inv_n - m * m;
    float a = (float)((double)g[c] / sqrt((double)v + 1e-5));
    sc[c] = a;
    sh[c] = b[c] - m * a;
}

__global__ void k_vq_gather(const unsigned long long* __restrict__ amin,
                            const float* __restrict__ codebook,
                            const float* __restrict__ e3pre,
                            const float* __restrict__ sc, const float* __restrict__ sh,
                            unsigned short* __restrict__ quant_bf,
                            float* __restrict__ loss,
                            unsigned int* __restrict__ hist)
{
    int b = blockIdx.x; int t = threadIdx.x;   // 256 threads
    unsigned int idx = (unsigned int)(amin[b] & 0xFFFFFFFFull) & 511u;
    float part = 0.f;
    for (int i = t; i < 512; i += 256) {
        float q = codebook[(size_t)idx * 512 + i];
        quant_bf[(size_t)b * 512 + i] = bfh(q);
        float x = e3pre[(size_t)b * 512 + i];
        float f = fmaxf(fmaf(x, sc[i], sh[i]), 0.f);
        float d = q - f;
        part += d * d;
    }
    for (int off = 32; off; off >>= 1) part += __shfl_down(part, off, 64);
    __shared__ float red[4];
    if ((t & 63) == 0) red[t >> 6] = part;
    __syncthreads();
    if (t == 0) {
        atomicAdd(loss, red[0] + red[1] + red[2] + red[3]);
        atomicAdd(&hist[idx], 1u);
    }
}

__global__ void k_scalars(const unsigned int* __restrict__ hist,
                          const float* __restrict__ loss, float* __restrict__ out)
{
    int t = threadIdx.x;   // 512
    float p = (float)hist[t] * (1.0f / 1024.0f);
    float e = p * logf(p + 1e-10f);
    for (int off = 32; off; off >>= 1) e += __shfl_down(e, off, 64);
    __shared__ float red[8];
    if ((t & 63) == 0) red[t >> 6] = e;
    __syncthreads();
    if (t == 0) {
        float s = 0.f;
        for (int i = 0; i < 8; ++i) s += red[i];
        out[4147200] = 1.25f * loss[0] * (1.0f / 524288.0f);
        out[4147201] = expf(-s);
    }
}

extern "C" void kernel_launch(void* const* d_in, const int* in_sizes, int n_in,
                              void* d_out, int out_size, void* d_ws, size_t ws_size,
                              hipStream_t stream)
{
    const float* in_seqs = (const float*)d_in[0];
    const float* W_in  = (const float*)d_in[1];
    const float* w_e1  = (const float*)d_in[3];
    const float* g_e1  = (const float*)d_in[4];
    const float* be1   = (const float*)d_in[5];
    const float* w_e2  = (const float*)d_in[6];
    const float* g_e2  = (const float*)d_in[7];
    const float* be2   = (const float*)d_in[8];
    const float* w_e3  = (const float*)d_in[9];
    const float* g_e3  = (const float*)d_in[10];
    const float* be3   = (const float*)d_in[11];
    const float* codebook = (const float*)d_in[12];
    const float* W_q   = (const float*)d_in[13];
    const float* b_q   = (const float*)d_in[14];
    const float* w_d1  = (const float*)d_in[15];
    const float* g_d1  = (const float*)d_in[16];
    const float* bd1   = (const float*)d_in[17];
    const float* w_d2  = (const float*)d_in[18];
    const float* g_d2  = (const float*)d_in[19];
    const float* bd2   = (const float*)d_in[20];
    const float* w_d3  = (const float*)d_in[21];
    const float* g_d3  = (const float*)d_in[22];
    const float* bd3   = (const float*)d_in[23];
    const float* W_out = (const float*)d_in[24];
    const float* b_out = (const float*)d_in[25];
    float* out = (float*)d_out;

    // ---- workspace layout (float offsets) — same as round 9 ----
    float* W = (float*)d_ws;
    unsigned long long* amin = (unsigned long long*)W;            // 2048 f
    float* stats  = W + 2048;                                     // 6144
    float* lossp  = W + 8192;                                     // 64
    unsigned int* hist = (unsigned int*)(W + 8256);               // 512
    float* scsh   = W + 8768;                                     // 6144
    float* codesq = W + 14912;                                    // 512
    float* wt_e1  = W + 15424;                                    // 1310720 f
    float* weff   = W + 1326144;                                  // 345600 f
    float* codeT  = W + 1671744;                                  // 262144 f
    unsigned short* esw = (unsigned short*)(W + 1933888);         // 3440640 ush
    unsigned short* whi_e1 = esw;
    unsigned short* wlo_e1 = esw + 409600;
    unsigned short* whi_e2 = esw + 819200;
    unsigned short* wlo_e2 = esw + 1605632;
    unsigned short* whi_e3 = esw + 2392064;
    unsigned short* wlo_e3 = esw + 2916352;
    unsigned short* in_h  = (unsigned short*)(W + 3654208);       // 4915200 ush
    unsigned short* in_l  = in_h + 4915200;
    unsigned short* d3pre = (unsigned short*)(W + 3654208);       // 15728640 ush
    float* e1f = W + 11518528;                                    // 3145728 f
    unsigned short* e1h = (unsigned short*)(W + 14664256);        // 3145728 ush
    unsigned short* e1l = e1h + 3145728;
    float* e2f = W + 17809984;                                    // 1048576 f
    unsigned short* e2h = (unsigned short*)(W + 18858560);        // 1048576 ush
    unsigned short* e2l = e2h + 1048576;
    unsigned short* d2pre = (unsigned short*)(W + 17809984);      // 3145728 ush
    unsigned short* d2bf  = d2pre + 3145728;                      // 3145728 ush
    float* e3f = W + 20955712;                                    // 524288 f
    unsigned short* quant_bf = (unsigned short*)(W + 21480000);   // 524288 ush
    unsigned short* d0bf     = (unsigned short*)(W + 21742144);   // 524288 ush
    unsigned short* d1pre    = (unsigned short*)(W + 22004288);   // 1048576 ush

    unsigned short* db    = (unsigned short*)wt_e1;
    unsigned short* wqb   = db;
    unsigned short* wd1b  = db + 262144;
    unsigned short* wd2b  = db + 786432;
    unsigned short* wd3b  = db + 1572864;
    unsigned short* woutb = db + 2883584;

    float* st_e1 = stats + 0 * 1024; float* sc_e1 = scsh + 0 * 1024; float* sh_e1 = sc_e1 + 512;
    float* st_e2 = stats + 1 * 1024; float* sc_e2 = scsh + 1 * 1024; float* sh_e2 = sc_e2 + 512;
    float* st_e3 = stats + 2 * 1024; float* sc_e3 = scsh + 2 * 1024; float* sh_e3 = sc_e3 + 512;
    float* st_d1 = stats + 3 * 1024; float* sc_d1 = scsh + 3 * 1024; float* sh_d1 = sc_d1 + 512;
    float* st_d2 = stats + 4 * 1024; float* sc_d2 = scsh + 4 * 1024; float* sh_d2 = sc_d2 + 512;
    float* st_d3 = stats + 5 * 1024; float* sc_d3 = scsh + 5 * 1024; float* sh_d3 = sc_d3 + 512;

    dim3 blk(256);

    // order: wt_e1 fp32 repack -> weff gemm -> sp_weff, THEN k_prep (which
    // fills decoder bf16 weights over the then-dead wt_e1 region).
    k_repack<<<dim3(5 * 1024), blk, 0, stream>>>(w_e1, wt_e1, 5, 5 * 262144);
    k_gemm<<<dim3(8, 3, 5), blk, 0, stream>>>(W_in, wt_e1, weff, nullptr,
        nullptr, nullptr, nullptr, nullptr, nullptr, 135, 512, 512, 1, 0, 5);
    k_repack_sp_weff<<<dim3(1600), blk, 0, stream>>>(weff, whi_e1, wlo_e1, 409600);

    k_prep<<<dim3(37422), blk, 0, stream>>>(stats, amin,
        codebook, codeT, codesq,
        w_e2, whi_e2, wlo_e2, w_e3, whi_e3, wlo_e3,
        W_q, wqb, w_d1, wd1b, w_d2, wd2b, w_d3, wd3b, W_out, woutb,
        in_seqs, in_h, in_l);

    // ---- encoder: 64x64-tile split-bf16 MFMA (reg-prefetch) ----
    k_sp64<<<dim3(8, 16, 6), blk, 0, stream>>>(in_h, in_l, whi_e1, wlo_e1,
        e1f, st_e1, 1024, 160, 512, 5);
    k_bn_fin<<<dim3(2), blk, 0, stream>>>(st_e1, g_e1, be1, sc_e1, sh_e1, 1.f / 6144.f);
    k_bnsplit<<<dim3(3072), blk, 0, stream>>>(e1f, sc_e1, sh_e1, e1h, e1l, 786432);

    k_sp64<<<dim3(8, 16, 2), blk, 0, stream>>>(e1h, e1l, whi_e2, wlo_e2,
        e2f, st_e2, 1024, 512, 512, 3);
    k_bn_fin<<<dim3(2), blk, 0, stream>>>(st_e2, g_e2, be2, sc_e2, sh_e2, 1.f / 2048.f);
    k_bnsplit<<<dim3(1024), blk, 0, stream>>>(e2f, sc_e2, sh_e2, e2h, e2l, 262144);

    k_sp64<<<dim3(8, 16, 1), blk, 0, stream>>>(e2h, e2l, whi_e3, wlo_e3,
        e3f, st_e3, 1024, 512, 512, 2);
    k_bn_fin<<<dim3(2), blk, 0, stream>>>(st_e3, g_e3, be3, sc_e3, sh_e3, 1.f / 1024.f);

    // ---- VQ: fp32 dist GEMM + argmin (unchanged) ----
    k_gemm<<<dim3(8, 16, 1), blk, 0, stream>>>(e3f, codeT, nullptr, nullptr,
        sc_e3, sh_e3, nullptr, amin, codesq, 1024, 512, 512, 1, 1, 1);
    k_vq_gather<<<dim3(1024), blk, 0, stream>>>(amin, codebook, e3f, sc_e3, sh_e3,
                                                quant_bf, lossp, hist);

    // ---- decoder: 64x64-tile bf16 MFMA (reg-prefetch) for d0/d1/d2 ----
    k_b64<<<dim3(8, 16, 1), blk, 0, stream>>>(quant_bf, wqb, d0bf,
        b_q, nullptr, nullptr, nullptr, 1024, 512, 512, 1);

    k_b64<<<dim3(8, 16, 2), blk, 0, stream>>>(d0bf, wd1b, d1pre,
        nullptr, nullptr, nullptr, st_d1, 1024, 512, 512, 2);
    k_bn_fin<<<dim3(2), blk, 0, stream>>>(st_d1, g_d1, bd1, sc_d1, sh_d1, 1.f / 2048.f);

    k_b64<<<dim3(8, 16, 6), blk, 0, stream>>>(d1pre, wd2b, d2pre,
        nullptr, sc_d1, sh_d1, st_d2, 1024, 512, 512, 3);
    k_bn_fin<<<dim3(2), blk, 0, stream>>>(st_d2, g_d2, bd2, sc_d2, sh_d2, 1.f / 6144.f);

    k_bnapply<<<dim3(1536), blk, 0, stream>>>(d2pre, sc_d2, sh_d2, d2bf, 393216);

    // d3 + proj keep 128x128 tiles (plenty of blocks), reg-prefetched
    k_mfma_b<<<dim3(4, 8, 30), blk, 0, stream>>>(d2bf, wd3b, d3pre, nullptr,
        nullptr, nullptr, nullptr, st_d3, 1024, 512, 512, 5);
    k_bn_fin<<<dim3(2), blk, 0, stream>>>(st_d3, g_d3, bd3, sc_d3, sh_d3, 1.f / 30720.f);

    k_mfma_b<<<dim3(2, 240, 1), blk, 0, stream>>>(d3pre, woutb, nullptr, out,
        b_out, sc_d3, sh_d3, nullptr, 30720, 512, 135, 1);

    k_scalars<<<dim3(1), dim3(512), 0, stream>>>(hist, lossp, out);
}